// Round 1
// baseline (2855.686 us; speedup 1.0000x reference)
//
#include <hip/hip_runtime.h>
#include <hip/hip_bf16.h>

namespace {

constexpr int Bn      = 256;
constexpr int NNODES  = 64;
constexpr int NGROUPS = 16;
constexpr int L       = 64;
constexpr int C       = 32;
constexpr int GH      = 128;
constexpr int E1      = 262144;
constexpr int E2      = 32768;
constexpr int NROWS   = Bn * NNODES;   // 16384
constexpr int GROWS   = Bn * NGROUPS;  // 4096

// ---------------- conv + max + relu -> feats [NROWS,192] ----------------
__global__ void k_conv_feats(
    const float* __restrict__ x,
    const float* __restrict__ w3,  const float* __restrict__ b3,
    const float* __restrict__ w5,  const float* __restrict__ b5,
    const float* __restrict__ w7,  const float* __restrict__ b7,
    const float* __restrict__ tw3, const float* __restrict__ tb3,
    const float* __restrict__ tw5, const float* __restrict__ tb5,
    const float* __restrict__ tw7, const float* __restrict__ tb7,
    float* __restrict__ feats)
{
    const int row = blockIdx.x;            // b*NNODES + n
    const int n = row & (NNODES - 1);
    __shared__ float xs[4 * L];
    const int t = threadIdx.x;             // 0..191
    for (int i = t; i < 4 * L; i += 192) xs[i] = x[row * (4 * L) + i];
    __syncthreads();
    const int cid = t >> 5, ch = t & 31;
    const float* wptr; const float* bptr; int k, pad, Lx, chin;
    switch (cid) {
        case 0: wptr = w3;  bptr = b3;  k = 3; pad = 1; Lx = 64; chin = 0; break;
        case 1: wptr = w5;  bptr = b5;  k = 5; pad = 2; Lx = 64; chin = 0; break;
        case 2: wptr = w7;  bptr = b7;  k = 7; pad = 3; Lx = 64; chin = 0; break;
        case 3: wptr = tw3; bptr = tb3; k = 3; pad = 1; Lx = 62; chin = 1; break;
        case 4: wptr = tw5; bptr = tb5; k = 5; pad = 2; Lx = 60; chin = 2; break;
        default:wptr = tw7; bptr = tb7; k = 7; pad = 3; Lx = 58; chin = 3; break;
    }
    float w[7];
    for (int i = 0; i < k; ++i) w[i] = wptr[(n * C + ch) * k + i];
    const float bias = bptr[n * C + ch];
    const float* xin = xs + chin * L;
    float m = -3.0e38f;
    for (int p = 0; p < Lx; ++p) {        // Lout == Lx (same padding)
        float s = 0.f;
        const int base = p - pad;
        for (int i = 0; i < k; ++i) {
            const int ix = base + i;
            const float xv = (ix >= 0 && ix < Lx) ? xin[ix] : 0.f;
            s = fmaf(w[i], xv, s);
        }
        m = fmaxf(m, s);
    }
    feats[row * 192 + cid * 32 + ch] = fmaxf(m + bias, 0.f);
}

// ---------------- per-node FF 192->128 + relu; 16 b-rows per block --------
__global__ void k_ff(const float* __restrict__ feats, const float* __restrict__ ffw,
                     const float* __restrict__ ffb, float* __restrict__ h0)
{
    const int nb = blockIdx.x >> 6;        // b-tile 0..15
    const int n  = blockIdx.x & 63;
    const int t  = threadIdx.x;            // 128
    __shared__ float fs[16 * 192];
    for (int r = 0; r < 16; ++r) {
        const int b = nb * 16 + r;
        for (int i = t; i < 192; i += 128)
            fs[r * 192 + i] = feats[((b << 6) | n) * 192 + i];
    }
    __syncthreads();
    const float* w = ffw + n * 192 * 128;
    const float bias = ffb[n * 128 + t];
    float acc[16];
    #pragma unroll
    for (int r = 0; r < 16; ++r) acc[r] = bias;
    for (int f = 0; f < 192; ++f) {
        const float wv = w[f * 128 + t];
        #pragma unroll
        for (int r = 0; r < 16; ++r) acc[r] = fmaf(fs[r * 192 + f], wv, acc[r]);
    }
    for (int r = 0; r < 16; ++r) {
        const int b = nb * 16 + r;
        h0[((b << 6) | n) * 128 + t] = fmaxf(acc[r], 0.f);
    }
}

// ---------------- shared-weight 128x128 GEMM; 16 rows per block -----------
__global__ void k_gemm128(const float* __restrict__ X, const float* __restrict__ W,
                          float* __restrict__ Y)
{
    const int r0 = blockIdx.x * 16;
    const int t = threadIdx.x;             // 128
    __shared__ float xs[16 * 128];
    for (int r = 0; r < 16; ++r) xs[r * 128 + t] = X[(r0 + r) * 128 + t];
    __syncthreads();
    float acc[16];
    #pragma unroll
    for (int r = 0; r < 16; ++r) acc[r] = 0.f;
    for (int f = 0; f < 128; ++f) {
        const float wv = W[f * 128 + t];
        #pragma unroll
        for (int r = 0; r < 16; ++r) acc[r] = fmaf(xs[r * 128 + f], wv, acc[r]);
    }
    for (int r = 0; r < 16; ++r) Y[(r0 + r) * 128 + t] = acc[r];
}

// ---------------- GCN helpers ---------------------------------------------
__global__ void k_deg_init(float* __restrict__ deg, int n) {
    const int i = blockIdx.x * blockDim.x + threadIdx.x;
    if (i < n) deg[i] = 1.0f;              // self loop
}
__global__ void k_deg_count(const int* __restrict__ dst, float* __restrict__ deg, int E) {
    const int e = blockIdx.x * blockDim.x + threadIdx.x;
    if (e < E) atomicAdd(&deg[dst[e]], 1.0f);
}
__global__ void k_dinv(float* __restrict__ deg, int n) {
    const int i = blockIdx.x * blockDim.x + threadIdx.x;
    if (i < n) deg[i] = rsqrtf(deg[i]);
}
// out[i,:] = hw[i,:]*dinv[i]^2 + bias  (self-loop message + bias)
__global__ void k_msg_init(const float* __restrict__ hw, const float* __restrict__ dinv,
                           const float* __restrict__ bias, float* __restrict__ out)
{
    const int i = blockIdx.x;
    const int t = threadIdx.x;             // 128
    const float di = dinv[i];
    out[i * 128 + t] = fmaf(hw[i * 128 + t], di * di, bias[t]);
}
// scatter: out[dst,:] += hw[src,:] * dinv[src]*dinv[dst]
__global__ void k_gcn_edges(const int* __restrict__ ei, const float* __restrict__ hw,
                            const float* __restrict__ dinv, float* __restrict__ out, int E)
{
    const int gid = blockIdx.x * blockDim.x + threadIdx.x;
    const int e = gid >> 5;                // 32 threads per edge
    if (e >= E) return;
    const int c = (gid & 31) * 4;
    const int s = ei[e];
    const int d = ei[E + e];
    const float norm = dinv[s] * dinv[d];
    const float4 v = *reinterpret_cast<const float4*>(hw + s * 128 + c);
    float* o = out + d * 128 + c;
    atomicAdd(o + 0, v.x * norm);
    atomicAdd(o + 1, v.y * norm);
    atomicAdd(o + 2, v.z * norm);
    atomicAdd(o + 3, v.w * norm);
}

// ---------------- per-group aggregate 512->128 -----------------------------
__global__ void k_agg(const float* __restrict__ h, const float* __restrict__ aggw,
                      const float* __restrict__ aggb, float* __restrict__ hg)
{
    const int bt = blockIdx.x >> 4;        // b-tile 0..15
    const int g  = blockIdx.x & 15;
    const int t  = threadIdx.x;            // 128
    __shared__ float fs[16 * 512];
    for (int r = 0; r < 16; ++r) {
        const int b = bt * 16 + r;
        // group g = nodes 4g..4g+3, contiguous rows of h
        const float* src = h + (b * 64 + g * 4) * 128;
        for (int i = t; i < 512; i += 128) fs[r * 512 + i] = src[i];
    }
    __syncthreads();
    const float* w = aggw + g * 512 * 128;
    const float bias = aggb[g * 128 + t];
    float acc[16];
    #pragma unroll
    for (int r = 0; r < 16; ++r) acc[r] = bias;
    for (int f = 0; f < 512; ++f) {
        const float wv = w[f * 128 + t];
        #pragma unroll
        for (int r = 0; r < 16; ++r) acc[r] = fmaf(fs[r * 512 + f], wv, acc[r]);
    }
    for (int r = 0; r < 16; ++r)
        hg[((bt * 16 + r) * 16 + g) * 128 + t] = acc[r];
}

// ---------------- disc: relu inputs, 256->128 + relu ------------------------
__global__ void k_disc(const float* __restrict__ h1, const float* __restrict__ h2,
                       const float* __restrict__ dw, const float* __restrict__ db,
                       float* __restrict__ dd)
{
    const int bt = blockIdx.x >> 4;
    const int g  = blockIdx.x & 15;
    const int t  = threadIdx.x;            // 128
    __shared__ float fs[16 * 256];
    for (int r = 0; r < 16; ++r) {
        const int rowi = (bt * 16 + r) * 16 + g;
        fs[r * 256 + t]       = fmaxf(h1[rowi * 128 + t], 0.f);  // relu after upper GCN
        fs[r * 256 + 128 + t] = fmaxf(h2[rowi * 128 + t], 0.f);
    }
    __syncthreads();
    const float* w = dw + g * 256 * 128;
    const float bias = db[g * 128 + t];
    float acc[16];
    #pragma unroll
    for (int r = 0; r < 16; ++r) acc[r] = bias;
    for (int f = 0; f < 256; ++f) {
        const float wv = w[f * 128 + t];
        #pragma unroll
        for (int r = 0; r < 16; ++r) acc[r] = fmaf(fs[r * 256 + f], wv, acc[r]);
    }
    for (int r = 0; r < 16; ++r) {
        const int b = bt * 16 + r;
        dd[b * 2048 + g * 128 + t] = fmaxf(acc[r], 0.f);
    }
}

// ---------------- final fc 2048->64 ----------------------------------------
__global__ void k_fc(const float* __restrict__ dd, const float* __restrict__ fcw,
                     const float* __restrict__ fcb, float* __restrict__ out)
{
    const int b0 = blockIdx.x * 4;
    const int t = threadIdx.x;             // 64
    __shared__ float fs[4 * 2048];
    for (int r = 0; r < 4; ++r)
        for (int i = t; i < 2048; i += 64) fs[r * 2048 + i] = dd[(b0 + r) * 2048 + i];
    __syncthreads();
    const float bias = fcb[t];
    float acc[4];
    #pragma unroll
    for (int r = 0; r < 4; ++r) acc[r] = bias;
    for (int f = 0; f < 2048; ++f) {
        const float wv = fcw[f * 64 + t];
        #pragma unroll
        for (int r = 0; r < 4; ++r) acc[r] = fmaf(fs[r * 2048 + f], wv, acc[r]);
    }
    for (int r = 0; r < 4; ++r) out[(b0 + r) * 64 + t] = acc[r];
}

} // namespace

extern "C" void kernel_launch(void* const* d_in, const int* in_sizes, int n_in,
                              void* d_out, int out_size, void* d_ws, size_t ws_size,
                              hipStream_t stream)
{
    const float* x[2]   = {(const float*)d_in[0], (const float*)d_in[1]};
    const int*   ei[2]  = {(const int*)d_in[2], (const int*)d_in[3]};
    const int*   gei[2] = {(const int*)d_in[4], (const int*)d_in[5]};
    const float* conv_w3 = (const float*)d_in[6];
    const float* conv_b3 = (const float*)d_in[7];
    const float* conv_w5 = (const float*)d_in[8];
    const float* conv_b5 = (const float*)d_in[9];
    const float* conv_w7 = (const float*)d_in[10];
    const float* conv_b7 = (const float*)d_in[11];
    const float* tconv_w3 = (const float*)d_in[12];
    const float* tconv_b3 = (const float*)d_in[13];
    const float* tconv_w5 = (const float*)d_in[14];
    const float* tconv_b5 = (const float*)d_in[15];
    const float* tconv_w7 = (const float*)d_in[16];
    const float* tconv_b7 = (const float*)d_in[17];
    const float* ff_w    = (const float*)d_in[18];
    const float* ff_b    = (const float*)d_in[19];
    const float* lower_w = (const float*)d_in[20];
    const float* lower_b = (const float*)d_in[21];
    const float* upper_w = (const float*)d_in[22];
    const float* upper_b = (const float*)d_in[23];
    const float* agg_w   = (const float*)d_in[24];
    const float* agg_b   = (const float*)d_in[25];
    const float* disc_w  = (const float*)d_in[26];
    const float* disc_b  = (const float*)d_in[27];
    const float* fc_w    = (const float*)d_in[28];
    const float* fc_b    = (const float*)d_in[29];

    float* ws = (float*)d_ws;
    // buffer plan (floats):
    // bufA [0, 3145728): feats, then reused as lower-GCN output (gout, 2097152)
    // bufB [3145728, 5242880): h0, then reused as hg(524288)+hgw(524288)
    // bufC [5242880, 7340032): hw (lower transform)
    float* bufA  = ws;
    float* bufB  = ws + 3145728;
    float* bufC  = ws + 5242880;
    float* henc0 = ws + 7340032;
    float* henc1 = henc0 + 524288;
    float* dd    = henc1 + 524288;
    float* dinv  = dd + 524288;      // 16384
    float* dinv2 = dinv + NROWS;     // 4096

    for (int e = 0; e < 2; ++e) {
        float* henc = e ? henc1 : henc0;
        float* feats = bufA;
        float* h0 = bufB;
        float* hw = bufC;

        k_conv_feats<<<NROWS, 192, 0, stream>>>(x[e],
            conv_w3, conv_b3, conv_w5, conv_b5, conv_w7, conv_b7,
            tconv_w3, tconv_b3, tconv_w5, tconv_b5, tconv_w7, tconv_b7, feats);
        k_ff<<<NROWS / 16, 128, 0, stream>>>(feats, ff_w, ff_b, h0);
        k_gemm128<<<NROWS / 16, 128, 0, stream>>>(h0, lower_w, hw);

        k_deg_init<<<NROWS / 256, 256, 0, stream>>>(dinv, NROWS);
        k_deg_count<<<E1 / 256, 256, 0, stream>>>(ei[e] + E1, dinv, E1);
        k_dinv<<<NROWS / 256, 256, 0, stream>>>(dinv, NROWS);

        float* gout = bufA;  // feats dead
        k_msg_init<<<NROWS, 128, 0, stream>>>(hw, dinv, lower_b, gout);
        k_gcn_edges<<<(E1 * 32) / 256, 256, 0, stream>>>(ei[e], hw, dinv, gout, E1);

        float* hg = bufB;    // h0 dead
        k_agg<<<256, 128, 0, stream>>>(gout, agg_w, agg_b, hg);
        float* hgw = bufB + 524288;
        k_gemm128<<<GROWS / 16, 128, 0, stream>>>(hg, upper_w, hgw);

        k_deg_init<<<GROWS / 256, 256, 0, stream>>>(dinv2, GROWS);
        k_deg_count<<<E2 / 256, 256, 0, stream>>>(gei[e] + E2, dinv2, E2);
        k_dinv<<<GROWS / 256, 256, 0, stream>>>(dinv2, GROWS);

        k_msg_init<<<GROWS, 128, 0, stream>>>(hgw, dinv2, upper_b, henc);
        k_gcn_edges<<<(E2 * 32) / 256, 256, 0, stream>>>(gei[e], hgw, dinv2, henc, E2);
    }

    k_disc<<<256, 128, 0, stream>>>(henc0, henc1, disc_w, disc_b, dd);
    k_fc<<<Bn / 4, 64, 0, stream>>>(dd, fc_w, fc_b, (float*)d_out);
}

// Round 2
// 1469.922 us; speedup vs baseline: 1.9427x; 1.9427x over previous
//
#include <hip/hip_runtime.h>
#include <hip/hip_bf16.h>

namespace {

constexpr int Bn      = 256;
constexpr int NNODES  = 64;
constexpr int NGROUPS = 16;
constexpr int L       = 64;
constexpr int C       = 32;
constexpr int GH      = 128;
constexpr int E1      = 262144;
constexpr int E2      = 32768;
constexpr int NROWS   = Bn * NNODES;   // 16384
constexpr int GROWS   = Bn * NGROUPS;  // 4096

// ---------------- conv + max + relu -> feats [NROWS,192] ----------------
// One thread per (row, channel); all 6 branches compile-time unrolled.
// x staged in LDS with zero halo so there are no bounds checks.
template<int K, int LX>
__device__ __forceinline__ float convmax(const float* __restrict__ xin,
                                         const float* __restrict__ wp)
{
    constexpr int PAD = (K - 1) / 2;
    float w[K];
    #pragma unroll
    for (int i = 0; i < K; ++i) w[i] = wp[i];
    float m = -3.0e38f;
    #pragma unroll
    for (int p = 0; p < LX; ++p) {
        float s = 0.f;
        #pragma unroll
        for (int i = 0; i < K; ++i) s = fmaf(w[i], xin[p - PAD + i], s);
        m = fmaxf(m, s);
    }
    return m;
}

__global__ __launch_bounds__(256) void k_conv_feats(
    const float* __restrict__ x,
    const float* __restrict__ w3,  const float* __restrict__ b3,
    const float* __restrict__ w5,  const float* __restrict__ b5,
    const float* __restrict__ w7,  const float* __restrict__ b7,
    const float* __restrict__ tw3, const float* __restrict__ tb3,
    const float* __restrict__ tw5, const float* __restrict__ tb5,
    const float* __restrict__ tw7, const float* __restrict__ tb7,
    float* __restrict__ feats)
{
    // 8 rows per block; xs[r][c][72] with 3-elem zero halo each side.
    __shared__ float xs[8 * 4 * 72];
    const int t = threadIdx.x;             // 256
    const int row0 = blockIdx.x * 8;
    // stage x (zero halo + zero truncated tails: channel c valid length 64-2c)
    for (int idx = t; idx < 8 * 4 * 72; idx += 256) {
        const int r   = idx / 288;
        const int rem = idx - r * 288;
        const int c   = rem / 72;
        const int j   = rem - c * 72;
        const int l   = j - 3;
        float v = 0.f;
        if (l >= 0 && l < 64 - 2 * c)
            v = x[(row0 + r) * 256 + c * 64 + l];
        xs[idx] = v;
    }
    __syncthreads();

    const int r  = t >> 5;                 // 0..7
    const int ch = t & 31;                 // 0..31
    const int row = row0 + r;
    const int n   = row & (NNODES - 1);
    const int wc  = n * C + ch;
    const float* xb0 = &xs[r * 288 + 0 * 72 + 3];
    const float* xb1 = &xs[r * 288 + 1 * 72 + 3];
    const float* xb2 = &xs[r * 288 + 2 * 72 + 3];
    const float* xb3 = &xs[r * 288 + 3 * 72 + 3];

    float* o = feats + row * 192 + ch;
    o[0 * 32] = fmaxf(convmax<3, 64>(xb0, w3  + wc * 3) + b3[wc],  0.f);
    o[1 * 32] = fmaxf(convmax<5, 64>(xb0, w5  + wc * 5) + b5[wc],  0.f);
    o[2 * 32] = fmaxf(convmax<7, 64>(xb0, w7  + wc * 7) + b7[wc],  0.f);
    o[3 * 32] = fmaxf(convmax<3, 62>(xb1, tw3 + wc * 3) + tb3[wc], 0.f);
    o[4 * 32] = fmaxf(convmax<5, 60>(xb2, tw5 + wc * 5) + tb5[wc], 0.f);
    o[5 * 32] = fmaxf(convmax<7, 58>(xb3, tw7 + wc * 7) + tb7[wc], 0.f);
}

// ---------------- per-node FF 192->128 + relu; 16 b-rows per block --------
__global__ void k_ff(const float* __restrict__ feats, const float* __restrict__ ffw,
                     const float* __restrict__ ffb, float* __restrict__ h0)
{
    const int nb = blockIdx.x >> 6;        // b-tile 0..15
    const int n  = blockIdx.x & 63;
    const int t  = threadIdx.x;            // 128
    __shared__ float fs[16 * 192];
    for (int r = 0; r < 16; ++r) {
        const int b = nb * 16 + r;
        for (int i = t; i < 192; i += 128)
            fs[r * 192 + i] = feats[((b << 6) | n) * 192 + i];
    }
    __syncthreads();
    const float* w = ffw + n * 192 * 128;
    const float bias = ffb[n * 128 + t];
    float acc[16];
    #pragma unroll
    for (int r = 0; r < 16; ++r) acc[r] = bias;
    for (int f = 0; f < 192; ++f) {
        const float wv = w[f * 128 + t];
        #pragma unroll
        for (int r = 0; r < 16; ++r) acc[r] = fmaf(fs[r * 192 + f], wv, acc[r]);
    }
    for (int r = 0; r < 16; ++r) {
        const int b = nb * 16 + r;
        h0[((b << 6) | n) * 128 + t] = fmaxf(acc[r], 0.f);
    }
}

// ---------------- shared-weight 128x128 GEMM; 16 rows per block -----------
__global__ void k_gemm128(const float* __restrict__ X, const float* __restrict__ W,
                          float* __restrict__ Y)
{
    const int r0 = blockIdx.x * 16;
    const int t = threadIdx.x;             // 128
    __shared__ float xs[16 * 128];
    for (int r = 0; r < 16; ++r) xs[r * 128 + t] = X[(r0 + r) * 128 + t];
    __syncthreads();
    float acc[16];
    #pragma unroll
    for (int r = 0; r < 16; ++r) acc[r] = 0.f;
    for (int f = 0; f < 128; ++f) {
        const float wv = W[f * 128 + t];
        #pragma unroll
        for (int r = 0; r < 16; ++r) acc[r] = fmaf(xs[r * 128 + f], wv, acc[r]);
    }
    for (int r = 0; r < 16; ++r) Y[(r0 + r) * 128 + t] = acc[r];
}

// ---------------- GCN helpers ---------------------------------------------
__global__ void k_deg_init(float* __restrict__ deg, int n) {
    const int i = blockIdx.x * blockDim.x + threadIdx.x;
    if (i < n) deg[i] = 1.0f;              // self loop
}
__global__ void k_deg_count(const int* __restrict__ dst, float* __restrict__ deg, int E) {
    const int e = blockIdx.x * blockDim.x + threadIdx.x;
    if (e < E) atomicAdd(&deg[dst[e]], 1.0f);
}
__global__ void k_dinv(float* __restrict__ deg, int n) {
    const int i = blockIdx.x * blockDim.x + threadIdx.x;
    if (i < n) deg[i] = rsqrtf(deg[i]);
}
// out[i,:] = hw[i,:]*dinv[i]^2 + bias  (self-loop message + bias)
__global__ void k_msg_init(const float* __restrict__ hw, const float* __restrict__ dinv,
                           const float* __restrict__ bias, float* __restrict__ out)
{
    const int i = blockIdx.x;
    const int t = threadIdx.x;             // 128
    const float di = dinv[i];
    out[i * 128 + t] = fmaf(hw[i * 128 + t], di * di, bias[t]);
}
// scatter: out[dst,:] += hw[src,:] * dinv[src]*dinv[dst]
__global__ void k_gcn_edges(const int* __restrict__ ei, const float* __restrict__ hw,
                            const float* __restrict__ dinv, float* __restrict__ out, int E)
{
    const int gid = blockIdx.x * blockDim.x + threadIdx.x;
    const int e = gid >> 5;                // 32 threads per edge
    if (e >= E) return;
    const int c = (gid & 31) * 4;
    const int s = ei[e];
    const int d = ei[E + e];
    const float norm = dinv[s] * dinv[d];
    const float4 v = *reinterpret_cast<const float4*>(hw + s * 128 + c);
    float* o = out + d * 128 + c;
    atomicAdd(o + 0, v.x * norm);
    atomicAdd(o + 1, v.y * norm);
    atomicAdd(o + 2, v.z * norm);
    atomicAdd(o + 3, v.w * norm);
}

// ---------------- per-group aggregate 512->128 -----------------------------
__global__ void k_agg(const float* __restrict__ h, const float* __restrict__ aggw,
                      const float* __restrict__ aggb, float* __restrict__ hg)
{
    const int bt = blockIdx.x >> 4;        // b-tile 0..15
    const int g  = blockIdx.x & 15;
    const int t  = threadIdx.x;            // 128
    __shared__ float fs[16 * 512];
    for (int r = 0; r < 16; ++r) {
        const int b = bt * 16 + r;
        // group g = nodes 4g..4g+3, contiguous rows of h
        const float* src = h + (b * 64 + g * 4) * 128;
        for (int i = t; i < 512; i += 128) fs[r * 512 + i] = src[i];
    }
    __syncthreads();
    const float* w = aggw + g * 512 * 128;
    const float bias = aggb[g * 128 + t];
    float acc[16];
    #pragma unroll
    for (int r = 0; r < 16; ++r) acc[r] = bias;
    for (int f = 0; f < 512; ++f) {
        const float wv = w[f * 128 + t];
        #pragma unroll
        for (int r = 0; r < 16; ++r) acc[r] = fmaf(fs[r * 512 + f], wv, acc[r]);
    }
    for (int r = 0; r < 16; ++r)
        hg[((bt * 16 + r) * 16 + g) * 128 + t] = acc[r];
}

// ---------------- disc: relu inputs, 256->128 + relu ------------------------
__global__ void k_disc(const float* __restrict__ h1, const float* __restrict__ h2,
                       const float* __restrict__ dw, const float* __restrict__ db,
                       float* __restrict__ dd)
{
    const int bt = blockIdx.x >> 4;
    const int g  = blockIdx.x & 15;
    const int t  = threadIdx.x;            // 128
    __shared__ float fs[16 * 256];
    for (int r = 0; r < 16; ++r) {
        const int rowi = (bt * 16 + r) * 16 + g;
        fs[r * 256 + t]       = fmaxf(h1[rowi * 128 + t], 0.f);  // relu after upper GCN
        fs[r * 256 + 128 + t] = fmaxf(h2[rowi * 128 + t], 0.f);
    }
    __syncthreads();
    const float* w = dw + g * 256 * 128;
    const float bias = db[g * 128 + t];
    float acc[16];
    #pragma unroll
    for (int r = 0; r < 16; ++r) acc[r] = bias;
    for (int f = 0; f < 256; ++f) {
        const float wv = w[f * 128 + t];
        #pragma unroll
        for (int r = 0; r < 16; ++r) acc[r] = fmaf(fs[r * 256 + f], wv, acc[r]);
    }
    for (int r = 0; r < 16; ++r) {
        const int b = bt * 16 + r;
        dd[b * 2048 + g * 128 + t] = fmaxf(acc[r], 0.f);
    }
}

// ---------------- final fc 2048->64 ----------------------------------------
__global__ void k_fc(const float* __restrict__ dd, const float* __restrict__ fcw,
                     const float* __restrict__ fcb, float* __restrict__ out)
{
    const int b0 = blockIdx.x * 4;
    const int t = threadIdx.x;             // 64
    __shared__ float fs[4 * 2048];
    for (int r = 0; r < 4; ++r)
        for (int i = t; i < 2048; i += 64) fs[r * 2048 + i] = dd[(b0 + r) * 2048 + i];
    __syncthreads();
    const float bias = fcb[t];
    float acc[4];
    #pragma unroll
    for (int r = 0; r < 4; ++r) acc[r] = bias;
    for (int f = 0; f < 2048; ++f) {
        const float wv = fcw[f * 64 + t];
        #pragma unroll
        for (int r = 0; r < 4; ++r) acc[r] = fmaf(fs[r * 2048 + f], wv, acc[r]);
    }
    for (int r = 0; r < 4; ++r) out[(b0 + r) * 64 + t] = acc[r];
}

} // namespace

extern "C" void kernel_launch(void* const* d_in, const int* in_sizes, int n_in,
                              void* d_out, int out_size, void* d_ws, size_t ws_size,
                              hipStream_t stream)
{
    const float* x[2]   = {(const float*)d_in[0], (const float*)d_in[1]};
    const int*   ei[2]  = {(const int*)d_in[2], (const int*)d_in[3]};
    const int*   gei[2] = {(const int*)d_in[4], (const int*)d_in[5]};
    const float* conv_w3 = (const float*)d_in[6];
    const float* conv_b3 = (const float*)d_in[7];
    const float* conv_w5 = (const float*)d_in[8];
    const float* conv_b5 = (const float*)d_in[9];
    const float* conv_w7 = (const float*)d_in[10];
    const float* conv_b7 = (const float*)d_in[11];
    const float* tconv_w3 = (const float*)d_in[12];
    const float* tconv_b3 = (const float*)d_in[13];
    const float* tconv_w5 = (const float*)d_in[14];
    const float* tconv_b5 = (const float*)d_in[15];
    const float* tconv_w7 = (const float*)d_in[16];
    const float* tconv_b7 = (const float*)d_in[17];
    const float* ff_w    = (const float*)d_in[18];
    const float* ff_b    = (const float*)d_in[19];
    const float* lower_w = (const float*)d_in[20];
    const float* lower_b = (const float*)d_in[21];
    const float* upper_w = (const float*)d_in[22];
    const float* upper_b = (const float*)d_in[23];
    const float* agg_w   = (const float*)d_in[24];
    const float* agg_b   = (const float*)d_in[25];
    const float* disc_w  = (const float*)d_in[26];
    const float* disc_b  = (const float*)d_in[27];
    const float* fc_w    = (const float*)d_in[28];
    const float* fc_b    = (const float*)d_in[29];

    float* ws = (float*)d_ws;
    float* bufA  = ws;
    float* bufB  = ws + 3145728;
    float* bufC  = ws + 5242880;
    float* henc0 = ws + 7340032;
    float* henc1 = henc0 + 524288;
    float* dd    = henc1 + 524288;
    float* dinv  = dd + 524288;      // 16384
    float* dinv2 = dinv + NROWS;     // 4096

    for (int e = 0; e < 2; ++e) {
        float* henc = e ? henc1 : henc0;
        float* feats = bufA;
        float* h0 = bufB;
        float* hw = bufC;

        k_conv_feats<<<NROWS / 8, 256, 0, stream>>>(x[e],
            conv_w3, conv_b3, conv_w5, conv_b5, conv_w7, conv_b7,
            tconv_w3, tconv_b3, tconv_w5, tconv_b5, tconv_w7, tconv_b7, feats);
        k_ff<<<NROWS / 16, 128, 0, stream>>>(feats, ff_w, ff_b, h0);
        k_gemm128<<<NROWS / 16, 128, 0, stream>>>(h0, lower_w, hw);

        k_deg_init<<<NROWS / 256, 256, 0, stream>>>(dinv, NROWS);
        k_deg_count<<<E1 / 256, 256, 0, stream>>>(ei[e] + E1, dinv, E1);
        k_dinv<<<NROWS / 256, 256, 0, stream>>>(dinv, NROWS);

        float* gout = bufA;  // feats dead
        k_msg_init<<<NROWS, 128, 0, stream>>>(hw, dinv, lower_b, gout);
        k_gcn_edges<<<(E1 * 32) / 256, 256, 0, stream>>>(ei[e], hw, dinv, gout, E1);

        float* hg = bufB;    // h0 dead
        k_agg<<<256, 128, 0, stream>>>(gout, agg_w, agg_b, hg);
        float* hgw = bufB + 524288;
        k_gemm128<<<GROWS / 16, 128, 0, stream>>>(hg, upper_w, hgw);

        k_deg_init<<<GROWS / 256, 256, 0, stream>>>(dinv2, GROWS);
        k_deg_count<<<E2 / 256, 256, 0, stream>>>(gei[e] + E2, dinv2, E2);
        k_dinv<<<GROWS / 256, 256, 0, stream>>>(dinv2, GROWS);

        k_msg_init<<<GROWS, 128, 0, stream>>>(hgw, dinv2, upper_b, henc);
        k_gcn_edges<<<(E2 * 32) / 256, 256, 0, stream>>>(gei[e], hgw, dinv2, henc, E2);
    }

    k_disc<<<256, 128, 0, stream>>>(henc0, henc1, disc_w, disc_b, dd);
    k_fc<<<Bn / 4, 64, 0, stream>>>(dd, fc_w, fc_b, (float*)d_out);
}

// Round 3
// 591.522 us; speedup vs baseline: 4.8277x; 2.4850x over previous
//
#include <hip/hip_runtime.h>
#include <hip/hip_bf16.h>

namespace {

constexpr int Bn      = 256;
constexpr int NNODES  = 64;
constexpr int NGROUPS = 16;
constexpr int L       = 64;
constexpr int C       = 32;
constexpr int GH      = 128;
constexpr int E1      = 262144;
constexpr int E2      = 32768;
constexpr int NROWS   = Bn * NNODES;   // 16384
constexpr int GROWS   = Bn * NGROUPS;  // 4096

// ---------------- conv + max + relu -> feats [NROWS,192] ----------------
template<int K, int LX>
__device__ __forceinline__ float convmax(const float* __restrict__ xin,
                                         const float* __restrict__ wp)
{
    constexpr int PAD = (K - 1) / 2;
    float w[K];
    #pragma unroll
    for (int i = 0; i < K; ++i) w[i] = wp[i];
    float m = -3.0e38f;
    #pragma unroll
    for (int p = 0; p < LX; ++p) {
        float s = 0.f;
        #pragma unroll
        for (int i = 0; i < K; ++i) s = fmaf(w[i], xin[p - PAD + i], s);
        m = fmaxf(m, s);
    }
    return m;
}

__global__ __launch_bounds__(256) void k_conv_feats(
    const float* __restrict__ x,
    const float* __restrict__ w3,  const float* __restrict__ b3,
    const float* __restrict__ w5,  const float* __restrict__ b5,
    const float* __restrict__ w7,  const float* __restrict__ b7,
    const float* __restrict__ tw3, const float* __restrict__ tb3,
    const float* __restrict__ tw5, const float* __restrict__ tb5,
    const float* __restrict__ tw7, const float* __restrict__ tb7,
    float* __restrict__ feats)
{
    __shared__ float xs[8 * 4 * 72];
    const int t = threadIdx.x;             // 256
    const int row0 = blockIdx.x * 8;
    for (int idx = t; idx < 8 * 4 * 72; idx += 256) {
        const int r   = idx / 288;
        const int rem = idx - r * 288;
        const int c   = rem / 72;
        const int j   = rem - c * 72;
        const int l   = j - 3;
        float v = 0.f;
        if (l >= 0 && l < 64 - 2 * c)
            v = x[(row0 + r) * 256 + c * 64 + l];
        xs[idx] = v;
    }
    __syncthreads();

    const int r  = t >> 5;
    const int ch = t & 31;
    const int row = row0 + r;
    const int n   = row & (NNODES - 1);
    const int wc  = n * C + ch;
    const float* xb0 = &xs[r * 288 + 0 * 72 + 3];
    const float* xb1 = &xs[r * 288 + 1 * 72 + 3];
    const float* xb2 = &xs[r * 288 + 2 * 72 + 3];
    const float* xb3 = &xs[r * 288 + 3 * 72 + 3];

    float* o = feats + row * 192 + ch;
    o[0 * 32] = fmaxf(convmax<3, 64>(xb0, w3  + wc * 3) + b3[wc],  0.f);
    o[1 * 32] = fmaxf(convmax<5, 64>(xb0, w5  + wc * 5) + b5[wc],  0.f);
    o[2 * 32] = fmaxf(convmax<7, 64>(xb0, w7  + wc * 7) + b7[wc],  0.f);
    o[3 * 32] = fmaxf(convmax<3, 62>(xb1, tw3 + wc * 3) + tb3[wc], 0.f);
    o[4 * 32] = fmaxf(convmax<5, 60>(xb2, tw5 + wc * 5) + tb5[wc], 0.f);
    o[5 * 32] = fmaxf(convmax<7, 58>(xb3, tw7 + wc * 7) + tb7[wc], 0.f);
}

// ---------------- per-node FF 192->128 + relu; 16 b-rows per block --------
__global__ void k_ff(const float* __restrict__ feats, const float* __restrict__ ffw,
                     const float* __restrict__ ffb, float* __restrict__ h0)
{
    const int nb = blockIdx.x >> 6;
    const int n  = blockIdx.x & 63;
    const int t  = threadIdx.x;            // 128
    __shared__ float fs[16 * 192];
    for (int r = 0; r < 16; ++r) {
        const int b = nb * 16 + r;
        for (int i = t; i < 192; i += 128)
            fs[r * 192 + i] = feats[((b << 6) | n) * 192 + i];
    }
    __syncthreads();
    const float* w = ffw + n * 192 * 128;
    const float bias = ffb[n * 128 + t];
    float acc[16];
    #pragma unroll
    for (int r = 0; r < 16; ++r) acc[r] = bias;
    for (int f = 0; f < 192; ++f) {
        const float wv = w[f * 128 + t];
        #pragma unroll
        for (int r = 0; r < 16; ++r) acc[r] = fmaf(fs[r * 192 + f], wv, acc[r]);
    }
    for (int r = 0; r < 16; ++r) {
        const int b = nb * 16 + r;
        h0[((b << 6) | n) * 128 + t] = fmaxf(acc[r], 0.f);
    }
}

// ---------------- shared-weight 128x128 GEMM; 16 rows per block -----------
__global__ void k_gemm128(const float* __restrict__ X, const float* __restrict__ W,
                          float* __restrict__ Y)
{
    const int r0 = blockIdx.x * 16;
    const int t = threadIdx.x;             // 128
    __shared__ float xs[16 * 128];
    for (int r = 0; r < 16; ++r) xs[r * 128 + t] = X[(r0 + r) * 128 + t];
    __syncthreads();
    float acc[16];
    #pragma unroll
    for (int r = 0; r < 16; ++r) acc[r] = 0.f;
    for (int f = 0; f < 128; ++f) {
        const float wv = W[f * 128 + t];
        #pragma unroll
        for (int r = 0; r < 16; ++r) acc[r] = fmaf(xs[r * 128 + f], wv, acc[r]);
    }
    for (int r = 0; r < 16; ++r) Y[(r0 + r) * 128 + t] = acc[r];
}

// ---------------- CSR build -------------------------------------------------
__global__ void k_zero_i(int* __restrict__ p, int n) {
    const int i = blockIdx.x * blockDim.x + threadIdx.x;
    if (i < n) p[i] = 0;
}
__global__ void k_hist(const int* __restrict__ dst, int* __restrict__ cnt, int E) {
    const int e = blockIdx.x * blockDim.x + threadIdx.x;
    if (e < E) atomicAdd(&cnt[dst[e]], 1);
}
// single-block exclusive scan over n (n/1024 <= 16); also dinv = rsqrt(1+cnt)
__global__ __launch_bounds__(1024) void k_scan(
    const int* __restrict__ cnt, int* __restrict__ offs, int* __restrict__ cur,
    float* __restrict__ dinv, int n)
{
    const int t = threadIdx.x;
    const int chunk = n >> 10;
    __shared__ int part[1024];
    int loc[16];
    int s = 0;
    const int base = t * chunk;
    for (int i = 0; i < chunk; ++i) { loc[i] = cnt[base + i]; s += loc[i]; }
    part[t] = s;
    __syncthreads();
    for (int off = 1; off < 1024; off <<= 1) {
        const int v = (t >= off) ? part[t - off] : 0;
        __syncthreads();
        part[t] += v;
        __syncthreads();
    }
    int run = (t > 0) ? part[t - 1] : 0;
    for (int i = 0; i < chunk; ++i) {
        offs[base + i] = run;
        cur[base + i]  = run;
        run += loc[i];
        dinv[base + i] = rsqrtf(1.0f + (float)loc[i]);
    }
    if (t == 1023) offs[n] = run;
}
__global__ void k_fill(const int* __restrict__ ei, int* __restrict__ cur,
                       int* __restrict__ esrc, int E)
{
    const int e = blockIdx.x * blockDim.x + threadIdx.x;
    if (e >= E) return;
    const int s = ei[e];
    const int d = ei[E + e];
    const int pos = atomicAdd(&cur[d], 1);
    esrc[pos] = s;
}

// ---------------- GCN gather: out[d] = (sum hw[s]*dinv[s] + hw[d]*dinv[d])*dinv[d] + bias
__global__ __launch_bounds__(128) void k_gcn_gather(
    const int* __restrict__ offs, const int* __restrict__ esrc,
    const float* __restrict__ hw, const float* __restrict__ dinv,
    const float* __restrict__ bias, float* __restrict__ out)
{
    const int d = blockIdx.x;
    const int t = threadIdx.x;             // 128
    const int e0 = offs[d], e1 = offs[d + 1];
    const float dd = dinv[d];
    float a0 = hw[d * 128 + t] * dd;
    float a1 = 0.f, a2 = 0.f, a3 = 0.f;
    int j = e0;
    for (; j + 3 < e1; j += 4) {
        const int s0 = esrc[j], s1 = esrc[j + 1], s2 = esrc[j + 2], s3 = esrc[j + 3];
        a0 = fmaf(hw[s0 * 128 + t], dinv[s0], a0);
        a1 = fmaf(hw[s1 * 128 + t], dinv[s1], a1);
        a2 = fmaf(hw[s2 * 128 + t], dinv[s2], a2);
        a3 = fmaf(hw[s3 * 128 + t], dinv[s3], a3);
    }
    for (; j < e1; ++j) {
        const int s = esrc[j];
        a0 = fmaf(hw[s * 128 + t], dinv[s], a0);
    }
    const float acc = (a0 + a1) + (a2 + a3);
    out[d * 128 + t] = fmaf(acc, dd, bias[t]);
}

// ---------------- per-group aggregate 512->128 -----------------------------
__global__ void k_agg(const float* __restrict__ h, const float* __restrict__ aggw,
                      const float* __restrict__ aggb, float* __restrict__ hg)
{
    const int bt = blockIdx.x >> 4;
    const int g  = blockIdx.x & 15;
    const int t  = threadIdx.x;            // 128
    __shared__ float fs[16 * 512];
    for (int r = 0; r < 16; ++r) {
        const int b = bt * 16 + r;
        const float* src = h + (b * 64 + g * 4) * 128;
        for (int i = t; i < 512; i += 128) fs[r * 512 + i] = src[i];
    }
    __syncthreads();
    const float* w = aggw + g * 512 * 128;
    const float bias = aggb[g * 128 + t];
    float acc[16];
    #pragma unroll
    for (int r = 0; r < 16; ++r) acc[r] = bias;
    for (int f = 0; f < 512; ++f) {
        const float wv = w[f * 128 + t];
        #pragma unroll
        for (int r = 0; r < 16; ++r) acc[r] = fmaf(fs[r * 512 + f], wv, acc[r]);
    }
    for (int r = 0; r < 16; ++r)
        hg[((bt * 16 + r) * 16 + g) * 128 + t] = acc[r];
}

// ---------------- disc: relu inputs, 256->128 + relu ------------------------
__global__ void k_disc(const float* __restrict__ h1, const float* __restrict__ h2,
                       const float* __restrict__ dw, const float* __restrict__ db,
                       float* __restrict__ dd)
{
    const int bt = blockIdx.x >> 4;
    const int g  = blockIdx.x & 15;
    const int t  = threadIdx.x;            // 128
    __shared__ float fs[16 * 256];
    for (int r = 0; r < 16; ++r) {
        const int rowi = (bt * 16 + r) * 16 + g;
        fs[r * 256 + t]       = fmaxf(h1[rowi * 128 + t], 0.f);
        fs[r * 256 + 128 + t] = fmaxf(h2[rowi * 128 + t], 0.f);
    }
    __syncthreads();
    const float* w = dw + g * 256 * 128;
    const float bias = db[g * 128 + t];
    float acc[16];
    #pragma unroll
    for (int r = 0; r < 16; ++r) acc[r] = bias;
    for (int f = 0; f < 256; ++f) {
        const float wv = w[f * 128 + t];
        #pragma unroll
        for (int r = 0; r < 16; ++r) acc[r] = fmaf(fs[r * 256 + f], wv, acc[r]);
    }
    for (int r = 0; r < 16; ++r) {
        const int b = bt * 16 + r;
        dd[b * 2048 + g * 128 + t] = fmaxf(acc[r], 0.f);
    }
}

// ---------------- final fc 2048->64 ----------------------------------------
__global__ void k_fc(const float* __restrict__ dd, const float* __restrict__ fcw,
                     const float* __restrict__ fcb, float* __restrict__ out)
{
    const int b0 = blockIdx.x * 4;
    const int t = threadIdx.x;             // 64
    __shared__ float fs[4 * 2048];
    for (int r = 0; r < 4; ++r)
        for (int i = t; i < 2048; i += 64) fs[r * 2048 + i] = dd[(b0 + r) * 2048 + i];
    __syncthreads();
    const float bias = fcb[t];
    float acc[4];
    #pragma unroll
    for (int r = 0; r < 4; ++r) acc[r] = bias;
    for (int f = 0; f < 2048; ++f) {
        const float wv = fcw[f * 64 + t];
        #pragma unroll
        for (int r = 0; r < 4; ++r) acc[r] = fmaf(fs[r * 2048 + f], wv, acc[r]);
    }
    for (int r = 0; r < 4; ++r) out[(b0 + r) * 64 + t] = acc[r];
}

} // namespace

extern "C" void kernel_launch(void* const* d_in, const int* in_sizes, int n_in,
                              void* d_out, int out_size, void* d_ws, size_t ws_size,
                              hipStream_t stream)
{
    const float* x[2]   = {(const float*)d_in[0], (const float*)d_in[1]};
    const int*   ei[2]  = {(const int*)d_in[2], (const int*)d_in[3]};
    const int*   gei[2] = {(const int*)d_in[4], (const int*)d_in[5]};
    const float* conv_w3 = (const float*)d_in[6];
    const float* conv_b3 = (const float*)d_in[7];
    const float* conv_w5 = (const float*)d_in[8];
    const float* conv_b5 = (const float*)d_in[9];
    const float* conv_w7 = (const float*)d_in[10];
    const float* conv_b7 = (const float*)d_in[11];
    const float* tconv_w3 = (const float*)d_in[12];
    const float* tconv_b3 = (const float*)d_in[13];
    const float* tconv_w5 = (const float*)d_in[14];
    const float* tconv_b5 = (const float*)d_in[15];
    const float* tconv_w7 = (const float*)d_in[16];
    const float* tconv_b7 = (const float*)d_in[17];
    const float* ff_w    = (const float*)d_in[18];
    const float* ff_b    = (const float*)d_in[19];
    const float* lower_w = (const float*)d_in[20];
    const float* lower_b = (const float*)d_in[21];
    const float* upper_w = (const float*)d_in[22];
    const float* upper_b = (const float*)d_in[23];
    const float* agg_w   = (const float*)d_in[24];
    const float* agg_b   = (const float*)d_in[25];
    const float* disc_w  = (const float*)d_in[26];
    const float* disc_b  = (const float*)d_in[27];
    const float* fc_w    = (const float*)d_in[28];
    const float* fc_b    = (const float*)d_in[29];

    float* ws = (float*)d_ws;
    float* bufA  = ws;                 // feats (3145728) -> gout (2097152)
    float* bufB  = ws + 3145728;       // h0 (2097152) -> hg+hgw (1048576)
    float* bufC  = ws + 5242880;       // hw (2097152)
    float* henc0 = ws + 7340032;
    float* henc1 = henc0 + 524288;
    float* dd    = henc1 + 524288;
    float* dinv  = dd + 524288;        // 16384
    float* dinv2 = dinv + NROWS;       // 4096
    int* cnt1  = (int*)(dinv2 + GROWS);
    int* offs1 = cnt1 + NROWS;         // 16385
    int* cur1  = offs1 + NROWS + 1;
    int* esrc1 = cur1 + NROWS;         // 262144
    int* cnt2  = esrc1 + E1;
    int* offs2 = cnt2 + GROWS;         // 4097
    int* cur2  = offs2 + GROWS + 1;
    int* esrc2 = cur2 + GROWS;         // 32768

    for (int e = 0; e < 2; ++e) {
        float* henc = e ? henc1 : henc0;
        float* feats = bufA;
        float* h0 = bufB;
        float* hw = bufC;

        // CSR build for node graph
        k_zero_i<<<NROWS / 256, 256, 0, stream>>>(cnt1, NROWS);
        k_hist<<<E1 / 256, 256, 0, stream>>>(ei[e] + E1, cnt1, E1);
        k_scan<<<1, 1024, 0, stream>>>(cnt1, offs1, cur1, dinv, NROWS);
        k_fill<<<E1 / 256, 256, 0, stream>>>(ei[e], cur1, esrc1, E1);

        k_conv_feats<<<NROWS / 8, 256, 0, stream>>>(x[e],
            conv_w3, conv_b3, conv_w5, conv_b5, conv_w7, conv_b7,
            tconv_w3, tconv_b3, tconv_w5, tconv_b5, tconv_w7, tconv_b7, feats);
        k_ff<<<NROWS / 16, 128, 0, stream>>>(feats, ff_w, ff_b, h0);
        k_gemm128<<<NROWS / 16, 128, 0, stream>>>(h0, lower_w, hw);

        float* gout = bufA;  // feats dead
        k_gcn_gather<<<NROWS, 128, 0, stream>>>(offs1, esrc1, hw, dinv, lower_b, gout);

        float* hg = bufB;    // h0 dead
        k_agg<<<256, 128, 0, stream>>>(gout, agg_w, agg_b, hg);
        float* hgw = bufB + 524288;
        k_gemm128<<<GROWS / 16, 128, 0, stream>>>(hg, upper_w, hgw);

        // CSR build for group graph
        k_zero_i<<<GROWS / 256, 256, 0, stream>>>(cnt2, GROWS);
        k_hist<<<E2 / 256, 256, 0, stream>>>(gei[e] + E2, cnt2, E2);
        k_scan<<<1, 1024, 0, stream>>>(cnt2, offs2, cur2, dinv2, GROWS);
        k_fill<<<E2 / 256, 256, 0, stream>>>(gei[e], cur2, esrc2, E2);

        k_gcn_gather<<<GROWS, 128, 0, stream>>>(offs2, esrc2, hgw, dinv2, upper_b, henc);
    }

    k_disc<<<256, 128, 0, stream>>>(henc0, henc1, disc_w, disc_b, dd);
    k_fc<<<Bn / 4, 64, 0, stream>>>(dd, fc_w, fc_b, (float*)d_out);
}

// Round 4
// 528.097 us; speedup vs baseline: 5.4075x; 1.1201x over previous
//
#include <hip/hip_runtime.h>
#include <hip/hip_bf16.h>

namespace {

constexpr int Bn      = 256;
constexpr int NNODES  = 64;
constexpr int NGROUPS = 16;
constexpr int L       = 64;
constexpr int C       = 32;
constexpr int GH      = 128;
constexpr int E1      = 262144;
constexpr int E2      = 32768;
constexpr int NROWS   = Bn * NNODES;   // 16384
constexpr int GROWS   = Bn * NGROUPS;  // 4096

// ---------------- conv + max + relu -> feats [NROWS,192] ----------------
template<int K, int LX>
__device__ __forceinline__ float convmax(const float* __restrict__ xin,
                                         const float* __restrict__ wp)
{
    constexpr int PAD = (K - 1) / 2;
    float w[K];
    #pragma unroll
    for (int i = 0; i < K; ++i) w[i] = wp[i];
    float m = -3.0e38f;
    #pragma unroll
    for (int p = 0; p < LX; ++p) {
        float s = 0.f;
        #pragma unroll
        for (int i = 0; i < K; ++i) s = fmaf(w[i], xin[p - PAD + i], s);
        m = fmaxf(m, s);
    }
    return m;
}

__global__ __launch_bounds__(256) void k_conv_feats(
    const float* __restrict__ x,
    const float* __restrict__ w3,  const float* __restrict__ b3,
    const float* __restrict__ w5,  const float* __restrict__ b5,
    const float* __restrict__ w7,  const float* __restrict__ b7,
    const float* __restrict__ tw3, const float* __restrict__ tb3,
    const float* __restrict__ tw5, const float* __restrict__ tb5,
    const float* __restrict__ tw7, const float* __restrict__ tb7,
    float* __restrict__ feats)
{
    __shared__ float xs[8 * 4 * 72];
    const int t = threadIdx.x;             // 256
    const int row0 = blockIdx.x * 8;
    for (int idx = t; idx < 8 * 4 * 72; idx += 256) {
        const int r   = idx / 288;
        const int rem = idx - r * 288;
        const int c   = rem / 72;
        const int j   = rem - c * 72;
        const int l   = j - 3;
        float v = 0.f;
        if (l >= 0 && l < 64 - 2 * c)
            v = x[(row0 + r) * 256 + c * 64 + l];
        xs[idx] = v;
    }
    __syncthreads();

    const int r  = t >> 5;
    const int ch = t & 31;
    const int row = row0 + r;
    const int n   = row & (NNODES - 1);
    const int wc  = n * C + ch;
    const float* xb0 = &xs[r * 288 + 0 * 72 + 3];
    const float* xb1 = &xs[r * 288 + 1 * 72 + 3];
    const float* xb2 = &xs[r * 288 + 2 * 72 + 3];
    const float* xb3 = &xs[r * 288 + 3 * 72 + 3];

    float* o = feats + row * 192 + ch;
    o[0 * 32] = fmaxf(convmax<3, 64>(xb0, w3  + wc * 3) + b3[wc],  0.f);
    o[1 * 32] = fmaxf(convmax<5, 64>(xb0, w5  + wc * 5) + b5[wc],  0.f);
    o[2 * 32] = fmaxf(convmax<7, 64>(xb0, w7  + wc * 7) + b7[wc],  0.f);
    o[3 * 32] = fmaxf(convmax<3, 62>(xb1, tw3 + wc * 3) + tb3[wc], 0.f);
    o[4 * 32] = fmaxf(convmax<5, 60>(xb2, tw5 + wc * 5) + tb5[wc], 0.f);
    o[5 * 32] = fmaxf(convmax<7, 58>(xb3, tw7 + wc * 7) + tb7[wc], 0.f);
}

// ---------------- per-node FF 192->128 + relu; 16 b-rows per block --------
__global__ void k_ff(const float* __restrict__ feats, const float* __restrict__ ffw,
                     const float* __restrict__ ffb, float* __restrict__ h0)
{
    const int nb = blockIdx.x >> 6;
    const int n  = blockIdx.x & 63;
    const int t  = threadIdx.x;            // 128
    __shared__ float fs[16 * 192];
    for (int r = 0; r < 16; ++r) {
        const int b = nb * 16 + r;
        for (int i = t; i < 192; i += 128)
            fs[r * 192 + i] = feats[((b << 6) | n) * 192 + i];
    }
    __syncthreads();
    const float* w = ffw + n * 192 * 128;
    const float bias = ffb[n * 128 + t];
    float acc[16];
    #pragma unroll
    for (int r = 0; r < 16; ++r) acc[r] = bias;
    for (int f = 0; f < 192; ++f) {
        const float wv = w[f * 128 + t];
        #pragma unroll
        for (int r = 0; r < 16; ++r) acc[r] = fmaf(fs[r * 192 + f], wv, acc[r]);
    }
    for (int r = 0; r < 16; ++r) {
        const int b = nb * 16 + r;
        h0[((b << 6) | n) * 128 + t] = fmaxf(acc[r], 0.f);
    }
}

// ---------------- shared-weight 128x128 GEMM; 16 rows per block -----------
__global__ void k_gemm128(const float* __restrict__ X, const float* __restrict__ W,
                          float* __restrict__ Y)
{
    const int r0 = blockIdx.x * 16;
    const int t = threadIdx.x;             // 128
    __shared__ float xs[16 * 128];
    for (int r = 0; r < 16; ++r) xs[r * 128 + t] = X[(r0 + r) * 128 + t];
    __syncthreads();
    float acc[16];
    #pragma unroll
    for (int r = 0; r < 16; ++r) acc[r] = 0.f;
    for (int f = 0; f < 128; ++f) {
        const float wv = W[f * 128 + t];
        #pragma unroll
        for (int r = 0; r < 16; ++r) acc[r] = fmaf(xs[r * 128 + f], wv, acc[r]);
    }
    for (int r = 0; r < 16; ++r) Y[(r0 + r) * 128 + t] = acc[r];
}

// ---------------- CSR build -------------------------------------------------
__global__ void k_zero_i(int* __restrict__ p, int n) {
    const int i = blockIdx.x * blockDim.x + threadIdx.x;
    if (i < n) p[i] = 0;
}
__global__ void k_hist(const int* __restrict__ dst, int* __restrict__ cnt, int E) {
    const int e = blockIdx.x * blockDim.x + threadIdx.x;
    if (e < E) atomicAdd(&cnt[dst[e]], 1);
}
// single-block exclusive scan over n (n/1024 <= 16); also dinv = rsqrt(1+cnt)
__global__ __launch_bounds__(1024) void k_scan(
    const int* __restrict__ cnt, int* __restrict__ offs, int* __restrict__ cur,
    float* __restrict__ dinv, int n)
{
    const int t = threadIdx.x;
    const int chunk = n >> 10;
    __shared__ int part[1024];
    int loc[16];
    int s = 0;
    const int base = t * chunk;
    for (int i = 0; i < chunk; ++i) { loc[i] = cnt[base + i]; s += loc[i]; }
    part[t] = s;
    __syncthreads();
    for (int off = 1; off < 1024; off <<= 1) {
        const int v = (t >= off) ? part[t - off] : 0;
        __syncthreads();
        part[t] += v;
        __syncthreads();
    }
    int run = (t > 0) ? part[t - 1] : 0;
    for (int i = 0; i < chunk; ++i) {
        offs[base + i] = run;
        cur[base + i]  = run;
        run += loc[i];
        dinv[base + i] = rsqrtf(1.0f + (float)loc[i]);
    }
    if (t == 1023) offs[n] = run;
}
__global__ void k_fill(const int* __restrict__ ei, int* __restrict__ cur,
                       int* __restrict__ esrc, int E)
{
    const int e = blockIdx.x * blockDim.x + threadIdx.x;
    if (e >= E) return;
    const int s = ei[e];
    const int d = ei[E + e];
    const int pos = atomicAdd(&cur[d], 1);
    esrc[pos] = s;
}

// ---------------- GCN gather ------------------------------------------------
__global__ __launch_bounds__(128) void k_gcn_gather(
    const int* __restrict__ offs, const int* __restrict__ esrc,
    const float* __restrict__ hw, const float* __restrict__ dinv,
    const float* __restrict__ bias, float* __restrict__ out)
{
    const int d = blockIdx.x;
    const int t = threadIdx.x;             // 128
    const int e0 = offs[d], e1 = offs[d + 1];
    const float dd = dinv[d];
    float a0 = hw[d * 128 + t] * dd;
    float a1 = 0.f, a2 = 0.f, a3 = 0.f;
    int j = e0;
    for (; j + 3 < e1; j += 4) {
        const int s0 = esrc[j], s1 = esrc[j + 1], s2 = esrc[j + 2], s3 = esrc[j + 3];
        a0 = fmaf(hw[s0 * 128 + t], dinv[s0], a0);
        a1 = fmaf(hw[s1 * 128 + t], dinv[s1], a1);
        a2 = fmaf(hw[s2 * 128 + t], dinv[s2], a2);
        a3 = fmaf(hw[s3 * 128 + t], dinv[s3], a3);
    }
    for (; j < e1; ++j) {
        const int s = esrc[j];
        a0 = fmaf(hw[s * 128 + t], dinv[s], a0);
    }
    const float acc = (a0 + a1) + (a2 + a3);
    out[d * 128 + t] = fmaf(acc, dd, bias[t]);
}

// ---------------- per-group aggregate 512->128 -----------------------------
__global__ void k_agg(const float* __restrict__ h, const float* __restrict__ aggw,
                      const float* __restrict__ aggb, float* __restrict__ hg)
{
    const int bt = blockIdx.x >> 4;
    const int g  = blockIdx.x & 15;
    const int t  = threadIdx.x;            // 128
    __shared__ float fs[16 * 512];
    for (int r = 0; r < 16; ++r) {
        const int b = bt * 16 + r;
        const float* src = h + (b * 64 + g * 4) * 128;
        for (int i = t; i < 512; i += 128) fs[r * 512 + i] = src[i];
    }
    __syncthreads();
    const float* w = aggw + g * 512 * 128;
    const float bias = aggb[g * 128 + t];
    float acc[16];
    #pragma unroll
    for (int r = 0; r < 16; ++r) acc[r] = bias;
    for (int f = 0; f < 512; ++f) {
        const float wv = w[f * 128 + t];
        #pragma unroll
        for (int r = 0; r < 16; ++r) acc[r] = fmaf(fs[r * 512 + f], wv, acc[r]);
    }
    for (int r = 0; r < 16; ++r)
        hg[((bt * 16 + r) * 16 + g) * 128 + t] = acc[r];
}

// ---------------- disc: relu inputs, 256->128 + relu ------------------------
__global__ void k_disc(const float* __restrict__ h1, const float* __restrict__ h2,
                       const float* __restrict__ dw, const float* __restrict__ db,
                       float* __restrict__ dd)
{
    const int bt = blockIdx.x >> 4;
    const int g  = blockIdx.x & 15;
    const int t  = threadIdx.x;            // 128
    __shared__ float fs[16 * 256];
    for (int r = 0; r < 16; ++r) {
        const int rowi = (bt * 16 + r) * 16 + g;
        fs[r * 256 + t]       = fmaxf(h1[rowi * 128 + t], 0.f);
        fs[r * 256 + 128 + t] = fmaxf(h2[rowi * 128 + t], 0.f);
    }
    __syncthreads();
    const float* w = dw + g * 256 * 128;
    const float bias = db[g * 128 + t];
    float acc[16];
    #pragma unroll
    for (int r = 0; r < 16; ++r) acc[r] = bias;
    for (int f = 0; f < 256; ++f) {
        const float wv = w[f * 128 + t];
        #pragma unroll
        for (int r = 0; r < 16; ++r) acc[r] = fmaf(fs[r * 256 + f], wv, acc[r]);
    }
    for (int r = 0; r < 16; ++r) {
        const int b = bt * 16 + r;
        dd[b * 2048 + g * 128 + t] = fmaxf(acc[r], 0.f);
    }
}

// ---------------- final fc 2048->64: one block per batch row ----------------
// 256 threads = 4 waves; wave k handles K-range [k*512,(k+1)*512); lane = out col.
__global__ __launch_bounds__(256) void k_fc(
    const float* __restrict__ dd, const float* __restrict__ fcw,
    const float* __restrict__ fcb, float* __restrict__ out)
{
    const int b = blockIdx.x;
    const int t = threadIdx.x;
    const int o = t & 63;
    const int k = t >> 6;                  // 0..3
    __shared__ float ds[2048];
    __shared__ float red[4][64];
    for (int i = t; i < 2048; i += 256) ds[i] = dd[b * 2048 + i];
    __syncthreads();
    const float* w  = fcw + (k * 512) * 64 + o;
    const float* xr = ds + k * 512;
    float a0 = 0.f, a1 = 0.f, a2 = 0.f, a3 = 0.f;
    #pragma unroll 4
    for (int f = 0; f < 512; f += 4) {
        a0 = fmaf(xr[f + 0], w[(f + 0) * 64], a0);
        a1 = fmaf(xr[f + 1], w[(f + 1) * 64], a1);
        a2 = fmaf(xr[f + 2], w[(f + 2) * 64], a2);
        a3 = fmaf(xr[f + 3], w[(f + 3) * 64], a3);
    }
    red[k][o] = (a0 + a1) + (a2 + a3);
    __syncthreads();
    if (t < 64)
        out[b * 64 + t] = ((red[0][t] + red[1][t]) + (red[2][t] + red[3][t])) + fcb[t];
}

} // namespace

extern "C" void kernel_launch(void* const* d_in, const int* in_sizes, int n_in,
                              void* d_out, int out_size, void* d_ws, size_t ws_size,
                              hipStream_t stream)
{
    const float* x[2]   = {(const float*)d_in[0], (const float*)d_in[1]};
    const int*   ei[2]  = {(const int*)d_in[2], (const int*)d_in[3]};
    const int*   gei[2] = {(const int*)d_in[4], (const int*)d_in[5]};
    const float* conv_w3 = (const float*)d_in[6];
    const float* conv_b3 = (const float*)d_in[7];
    const float* conv_w5 = (const float*)d_in[8];
    const float* conv_b5 = (const float*)d_in[9];
    const float* conv_w7 = (const float*)d_in[10];
    const float* conv_b7 = (const float*)d_in[11];
    const float* tconv_w3 = (const float*)d_in[12];
    const float* tconv_b3 = (const float*)d_in[13];
    const float* tconv_w5 = (const float*)d_in[14];
    const float* tconv_b5 = (const float*)d_in[15];
    const float* tconv_w7 = (const float*)d_in[16];
    const float* tconv_b7 = (const float*)d_in[17];
    const float* ff_w    = (const float*)d_in[18];
    const float* ff_b    = (const float*)d_in[19];
    const float* lower_w = (const float*)d_in[20];
    const float* lower_b = (const float*)d_in[21];
    const float* upper_w = (const float*)d_in[22];
    const float* upper_b = (const float*)d_in[23];
    const float* agg_w   = (const float*)d_in[24];
    const float* agg_b   = (const float*)d_in[25];
    const float* disc_w  = (const float*)d_in[26];
    const float* disc_b  = (const float*)d_in[27];
    const float* fc_w    = (const float*)d_in[28];
    const float* fc_b    = (const float*)d_in[29];

    float* ws = (float*)d_ws;
    float* bufA  = ws;
    float* bufB  = ws + 3145728;
    float* bufC  = ws + 5242880;
    float* henc0 = ws + 7340032;
    float* henc1 = henc0 + 524288;
    float* dd    = henc1 + 524288;
    float* dinv  = dd + 524288;
    float* dinv2 = dinv + NROWS;
    int* cnt1  = (int*)(dinv2 + GROWS);
    int* offs1 = cnt1 + NROWS;
    int* cur1  = offs1 + NROWS + 1;
    int* esrc1 = cur1 + NROWS;
    int* cnt2  = esrc1 + E1;
    int* offs2 = cnt2 + GROWS;
    int* cur2  = offs2 + GROWS + 1;
    int* esrc2 = cur2 + GROWS;

    for (int e = 0; e < 2; ++e) {
        float* henc = e ? henc1 : henc0;
        float* feats = bufA;
        float* h0 = bufB;
        float* hw = bufC;

        k_zero_i<<<NROWS / 256, 256, 0, stream>>>(cnt1, NROWS);
        k_hist<<<E1 / 256, 256, 0, stream>>>(ei[e] + E1, cnt1, E1);
        k_scan<<<1, 1024, 0, stream>>>(cnt1, offs1, cur1, dinv, NROWS);
        k_fill<<<E1 / 256, 256, 0, stream>>>(ei[e], cur1, esrc1, E1);

        k_conv_feats<<<NROWS / 8, 256, 0, stream>>>(x[e],
            conv_w3, conv_b3, conv_w5, conv_b5, conv_w7, conv_b7,
            tconv_w3, tconv_b3, tconv_w5, tconv_b5, tconv_w7, tconv_b7, feats);
        k_ff<<<NROWS / 16, 128, 0, stream>>>(feats, ff_w, ff_b, h0);
        k_gemm128<<<NROWS / 16, 128, 0, stream>>>(h0, lower_w, hw);

        float* gout = bufA;
        k_gcn_gather<<<NROWS, 128, 0, stream>>>(offs1, esrc1, hw, dinv, lower_b, gout);

        float* hg = bufB;
        k_agg<<<256, 128, 0, stream>>>(gout, agg_w, agg_b, hg);
        float* hgw = bufB + 524288;
        k_gemm128<<<GROWS / 16, 128, 0, stream>>>(hg, upper_w, hgw);

        k_zero_i<<<GROWS / 256, 256, 0, stream>>>(cnt2, GROWS);
        k_hist<<<E2 / 256, 256, 0, stream>>>(gei[e] + E2, cnt2, E2);
        k_scan<<<1, 1024, 0, stream>>>(cnt2, offs2, cur2, dinv2, GROWS);
        k_fill<<<E2 / 256, 256, 0, stream>>>(gei[e], cur2, esrc2, E2);

        k_gcn_gather<<<GROWS, 128, 0, stream>>>(offs2, esrc2, hgw, dinv2, upper_b, henc);
    }

    k_disc<<<256, 128, 0, stream>>>(henc0, henc1, disc_w, disc_b, dd);
    k_fc<<<Bn, 256, 0, stream>>>(dd, fc_w, fc_b, (float*)d_out);
}

// Round 5
// 432.795 us; speedup vs baseline: 6.5982x; 1.2202x over previous
//
#include <hip/hip_runtime.h>
#include <hip/hip_bf16.h>

namespace {

constexpr int Bn      = 256;
constexpr int NNODES  = 64;
constexpr int NGROUPS = 16;
constexpr int L       = 64;
constexpr int C       = 32;
constexpr int GH      = 128;
constexpr int E1      = 262144;
constexpr int E2      = 32768;
constexpr int NROWS   = Bn * NNODES;   // 16384
constexpr int GROWS   = Bn * NGROUPS;  // 4096

// ---------------- conv + max + relu -> feats [NROWS,192] ----------------
template<int K, int LX>
__device__ __forceinline__ float convmax(const float* __restrict__ xin,
                                         const float* __restrict__ wp)
{
    constexpr int PAD = (K - 1) / 2;
    float w[K];
    #pragma unroll
    for (int i = 0; i < K; ++i) w[i] = wp[i];
    float m = -3.0e38f;
    #pragma unroll
    for (int p = 0; p < LX; ++p) {
        float s = 0.f;
        #pragma unroll
        for (int i = 0; i < K; ++i) s = fmaf(w[i], xin[p - PAD + i], s);
        m = fmaxf(m, s);
    }
    return m;
}

__global__ __launch_bounds__(256) void k_conv_feats(
    const float* __restrict__ x,
    const float* __restrict__ w3,  const float* __restrict__ b3,
    const float* __restrict__ w5,  const float* __restrict__ b5,
    const float* __restrict__ w7,  const float* __restrict__ b7,
    const float* __restrict__ tw3, const float* __restrict__ tb3,
    const float* __restrict__ tw5, const float* __restrict__ tb5,
    const float* __restrict__ tw7, const float* __restrict__ tb7,
    float* __restrict__ feats)
{
    __shared__ float xs[8 * 4 * 72];
    const int t = threadIdx.x;             // 256
    const int row0 = blockIdx.x * 8;
    for (int idx = t; idx < 8 * 4 * 72; idx += 256) {
        const int r   = idx / 288;
        const int rem = idx - r * 288;
        const int c   = rem / 72;
        const int j   = rem - c * 72;
        const int l   = j - 3;
        float v = 0.f;
        if (l >= 0 && l < 64 - 2 * c)
            v = x[(row0 + r) * 256 + c * 64 + l];
        xs[idx] = v;
    }
    __syncthreads();

    const int r  = t >> 5;
    const int ch = t & 31;
    const int row = row0 + r;
    const int n   = row & (NNODES - 1);
    const int wc  = n * C + ch;
    const float* xb0 = &xs[r * 288 + 0 * 72 + 3];
    const float* xb1 = &xs[r * 288 + 1 * 72 + 3];
    const float* xb2 = &xs[r * 288 + 2 * 72 + 3];
    const float* xb3 = &xs[r * 288 + 3 * 72 + 3];

    float* o = feats + row * 192 + ch;
    o[0 * 32] = fmaxf(convmax<3, 64>(xb0, w3  + wc * 3) + b3[wc],  0.f);
    o[1 * 32] = fmaxf(convmax<5, 64>(xb0, w5  + wc * 5) + b5[wc],  0.f);
    o[2 * 32] = fmaxf(convmax<7, 64>(xb0, w7  + wc * 7) + b7[wc],  0.f);
    o[3 * 32] = fmaxf(convmax<3, 62>(xb1, tw3 + wc * 3) + tb3[wc], 0.f);
    o[4 * 32] = fmaxf(convmax<5, 60>(xb2, tw5 + wc * 5) + tb5[wc], 0.f);
    o[5 * 32] = fmaxf(convmax<7, 58>(xb3, tw7 + wc * 7) + tb7[wc], 0.f);
}

// ---------------- per-node FF 192->128 + relu; 16 b-rows per block --------
__global__ void k_ff(const float* __restrict__ feats, const float* __restrict__ ffw,
                     const float* __restrict__ ffb, float* __restrict__ h0)
{
    const int nb = blockIdx.x >> 6;
    const int n  = blockIdx.x & 63;
    const int t  = threadIdx.x;            // 128
    __shared__ float fs[16 * 192];
    for (int r = 0; r < 16; ++r) {
        const int b = nb * 16 + r;
        for (int i = t; i < 192; i += 128)
            fs[r * 192 + i] = feats[((b << 6) | n) * 192 + i];
    }
    __syncthreads();
    const float* w = ffw + n * 192 * 128;
    const float bias = ffb[n * 128 + t];
    float acc[16];
    #pragma unroll
    for (int r = 0; r < 16; ++r) acc[r] = bias;
    for (int f = 0; f < 192; ++f) {
        const float wv = w[f * 128 + t];
        #pragma unroll
        for (int r = 0; r < 16; ++r) acc[r] = fmaf(fs[r * 192 + f], wv, acc[r]);
    }
    for (int r = 0; r < 16; ++r) {
        const int b = nb * 16 + r;
        h0[((b << 6) | n) * 128 + t] = fmaxf(acc[r], 0.f);
    }
}

// ---------------- shared-weight 128x128 GEMM; 16 rows per block -----------
__global__ void k_gemm128(const float* __restrict__ X, const float* __restrict__ W,
                          float* __restrict__ Y)
{
    const int r0 = blockIdx.x * 16;
    const int t = threadIdx.x;             // 128
    __shared__ float xs[16 * 128];
    for (int r = 0; r < 16; ++r) xs[r * 128 + t] = X[(r0 + r) * 128 + t];
    __syncthreads();
    float acc[16];
    #pragma unroll
    for (int r = 0; r < 16; ++r) acc[r] = 0.f;
    for (int f = 0; f < 128; ++f) {
        const float wv = W[f * 128 + t];
        #pragma unroll
        for (int r = 0; r < 16; ++r) acc[r] = fmaf(xs[r * 128 + f], wv, acc[r]);
    }
    for (int r = 0; r < 16; ++r) Y[(r0 + r) * 128 + t] = acc[r];
}

// ---------------- CSR build -------------------------------------------------
__global__ void k_zero_i(int* __restrict__ p, int n) {
    const int i = blockIdx.x * blockDim.x + threadIdx.x;
    if (i < n) p[i] = 0;
}
__global__ void k_hist(const int* __restrict__ dst, int* __restrict__ cnt, int E) {
    const int e = blockIdx.x * blockDim.x + threadIdx.x;
    if (e < E) atomicAdd(&cnt[dst[e]], 1);
}
// single-block exclusive scan over n (n/1024 <= 16); also dinv = rsqrt(1+cnt)
__global__ __launch_bounds__(1024) void k_scan(
    const int* __restrict__ cnt, int* __restrict__ offs, int* __restrict__ cur,
    float* __restrict__ dinv, int n)
{
    const int t = threadIdx.x;
    const int chunk = n >> 10;
    __shared__ int part[1024];
    int loc[16];
    int s = 0;
    const int base = t * chunk;
    for (int i = 0; i < chunk; ++i) { loc[i] = cnt[base + i]; s += loc[i]; }
    part[t] = s;
    __syncthreads();
    for (int off = 1; off < 1024; off <<= 1) {
        const int v = (t >= off) ? part[t - off] : 0;
        __syncthreads();
        part[t] += v;
        __syncthreads();
    }
    int run = (t > 0) ? part[t - 1] : 0;
    for (int i = 0; i < chunk; ++i) {
        offs[base + i] = run;
        cur[base + i]  = run;
        run += loc[i];
        dinv[base + i] = rsqrtf(1.0f + (float)loc[i]);
    }
    if (t == 1023) offs[n] = run;
}
__global__ void k_fill(const int* __restrict__ ei, int* __restrict__ cur,
                       int* __restrict__ esrc, int E)
{
    const int e = blockIdx.x * blockDim.x + threadIdx.x;
    if (e >= E) return;
    const int s = ei[e];
    const int d = ei[E + e];
    const int pos = atomicAdd(&cur[d], 1);
    esrc[pos] = s;
}

// ---------------- GCN gather ------------------------------------------------
__global__ __launch_bounds__(128) void k_gcn_gather(
    const int* __restrict__ offs, const int* __restrict__ esrc,
    const float* __restrict__ hw, const float* __restrict__ dinv,
    const float* __restrict__ bias, float* __restrict__ out)
{
    const int d = blockIdx.x;
    const int t = threadIdx.x;             // 128
    const int e0 = offs[d], e1 = offs[d + 1];
    const float dd = dinv[d];
    float a0 = hw[d * 128 + t] * dd;
    float a1 = 0.f, a2 = 0.f, a3 = 0.f;
    int j = e0;
    for (; j + 3 < e1; j += 4) {
        const int s0 = esrc[j], s1 = esrc[j + 1], s2 = esrc[j + 2], s3 = esrc[j + 3];
        a0 = fmaf(hw[s0 * 128 + t], dinv[s0], a0);
        a1 = fmaf(hw[s1 * 128 + t], dinv[s1], a1);
        a2 = fmaf(hw[s2 * 128 + t], dinv[s2], a2);
        a3 = fmaf(hw[s3 * 128 + t], dinv[s3], a3);
    }
    for (; j < e1; ++j) {
        const int s = esrc[j];
        a0 = fmaf(hw[s * 128 + t], dinv[s], a0);
    }
    const float acc = (a0 + a1) + (a2 + a3);
    out[d * 128 + t] = fmaf(acc, dd, bias[t]);
}

// ---------------- per-group aggregate 512->128 (v2: 4 rows, K-split 2) ------
// grid = (Bn/4) * 16 ; block = 256 = 4 waves. t: o = t&127 (out col), kk = t>>7.
__global__ __launch_bounds__(256) void k_agg(
    const float* __restrict__ h, const float* __restrict__ aggw,
    const float* __restrict__ aggb, float* __restrict__ hg)
{
    const int bt = blockIdx.x >> 4;        // 0..63 (4 rows each)
    const int g  = blockIdx.x & 15;
    const int t  = threadIdx.x;
    const int o  = t & 127;
    const int kk = t >> 7;                 // 0..1
    __shared__ float fs[4 * 512];
    __shared__ float red[2][4][128];
    // rows 4g..4g+3 of h for batch b are contiguous: 2048 floats per b
    {
        const int b0 = bt * 4;
        float4* dst = (float4*)fs;
        for (int i = t; i < 4 * 128; i += 256) {
            const int r = i >> 7;          // row in tile
            const int q = i & 127;         // float4 idx within row's 512 floats
            dst[i] = *(const float4*)(h + ((size_t)(b0 + r) * 64 + g * 4) * 128 + q * 4);
        }
    }
    __syncthreads();
    const float* w = aggw + (size_t)g * 512 * 128 + (size_t)kk * 256 * 128 + o;
    float a0 = 0.f, a1 = 0.f, a2 = 0.f, a3 = 0.f;
    const float* x0 = fs + 0 * 512 + kk * 256;
    const float* x1 = fs + 1 * 512 + kk * 256;
    const float* x2 = fs + 2 * 512 + kk * 256;
    const float* x3 = fs + 3 * 512 + kk * 256;
    #pragma unroll 8
    for (int f = 0; f < 256; ++f) {
        const float wv = w[f * 128];
        a0 = fmaf(x0[f], wv, a0);
        a1 = fmaf(x1[f], wv, a1);
        a2 = fmaf(x2[f], wv, a2);
        a3 = fmaf(x3[f], wv, a3);
    }
    red[kk][0][o] = a0; red[kk][1][o] = a1; red[kk][2][o] = a2; red[kk][3][o] = a3;
    __syncthreads();
    if (t < 128) {
        const float bias = aggb[g * 128 + t];
        #pragma unroll
        for (int r = 0; r < 4; ++r) {
            const int b = bt * 4 + r;
            hg[((size_t)b * 16 + g) * 128 + t] = red[0][r][t] + red[1][r][t] + bias;
        }
    }
}

// ---------------- disc (v2: 4 rows, K-split 2): relu in, 256->128 + relu ----
// grid = (Bn/4) * 16 ; block = 256.
__global__ __launch_bounds__(256) void k_disc(
    const float* __restrict__ h1, const float* __restrict__ h2,
    const float* __restrict__ dw, const float* __restrict__ db,
    float* __restrict__ dd)
{
    const int bt = blockIdx.x >> 4;        // 0..63
    const int g  = blockIdx.x & 15;
    const int t  = threadIdx.x;
    const int o  = t & 127;
    const int kk = t >> 7;                 // 0..1
    __shared__ float fs[4 * 256];
    __shared__ float red[2][4][128];
    {
        const int half = t >> 7;           // 0: h1, 1: h2
        #pragma unroll
        for (int r = 0; r < 4; ++r) {
            const int rowi = ((bt * 4 + r) * 16 + g);
            const float* src = half ? h2 : h1;
            fs[r * 256 + half * 128 + o] = fmaxf(src[(size_t)rowi * 128 + o], 0.f);
        }
    }
    __syncthreads();
    const float* w = dw + (size_t)g * 256 * 128 + (size_t)kk * 128 * 128 + o;
    float a0 = 0.f, a1 = 0.f, a2 = 0.f, a3 = 0.f;
    const float* x0 = fs + 0 * 256 + kk * 128;
    const float* x1 = fs + 1 * 256 + kk * 128;
    const float* x2 = fs + 2 * 256 + kk * 128;
    const float* x3 = fs + 3 * 256 + kk * 128;
    #pragma unroll 8
    for (int f = 0; f < 128; ++f) {
        const float wv = w[f * 128];
        a0 = fmaf(x0[f], wv, a0);
        a1 = fmaf(x1[f], wv, a1);
        a2 = fmaf(x2[f], wv, a2);
        a3 = fmaf(x3[f], wv, a3);
    }
    red[kk][0][o] = a0; red[kk][1][o] = a1; red[kk][2][o] = a2; red[kk][3][o] = a3;
    __syncthreads();
    if (t < 128) {
        const float bias = db[g * 128 + t];
        #pragma unroll
        for (int r = 0; r < 4; ++r) {
            const int b = bt * 4 + r;
            dd[(size_t)b * 2048 + g * 128 + t] =
                fmaxf(red[0][r][t] + red[1][r][t] + bias, 0.f);
        }
    }
}

// ---------------- final fc 2048->64: one block per batch row ----------------
__global__ __launch_bounds__(256) void k_fc(
    const float* __restrict__ dd, const float* __restrict__ fcw,
    const float* __restrict__ fcb, float* __restrict__ out)
{
    const int b = blockIdx.x;
    const int t = threadIdx.x;
    const int o = t & 63;
    const int k = t >> 6;                  // 0..3
    __shared__ float ds[2048];
    __shared__ float red[4][64];
    for (int i = t; i < 2048; i += 256) ds[i] = dd[b * 2048 + i];
    __syncthreads();
    const float* w  = fcw + (k * 512) * 64 + o;
    const float* xr = ds + k * 512;
    float a0 = 0.f, a1 = 0.f, a2 = 0.f, a3 = 0.f;
    #pragma unroll 4
    for (int f = 0; f < 512; f += 4) {
        a0 = fmaf(xr[f + 0], w[(f + 0) * 64], a0);
        a1 = fmaf(xr[f + 1], w[(f + 1) * 64], a1);
        a2 = fmaf(xr[f + 2], w[(f + 2) * 64], a2);
        a3 = fmaf(xr[f + 3], w[(f + 3) * 64], a3);
    }
    red[k][o] = (a0 + a1) + (a2 + a3);
    __syncthreads();
    if (t < 64)
        out[b * 64 + t] = ((red[0][t] + red[1][t]) + (red[2][t] + red[3][t])) + fcb[t];
}

} // namespace

extern "C" void kernel_launch(void* const* d_in, const int* in_sizes, int n_in,
                              void* d_out, int out_size, void* d_ws, size_t ws_size,
                              hipStream_t stream)
{
    const float* x[2]   = {(const float*)d_in[0], (const float*)d_in[1]};
    const int*   ei[2]  = {(const int*)d_in[2], (const int*)d_in[3]};
    const int*   gei[2] = {(const int*)d_in[4], (const int*)d_in[5]};
    const float* conv_w3 = (const float*)d_in[6];
    const float* conv_b3 = (const float*)d_in[7];
    const float* conv_w5 = (const float*)d_in[8];
    const float* conv_b5 = (const float*)d_in[9];
    const float* conv_w7 = (const float*)d_in[10];
    const float* conv_b7 = (const float*)d_in[11];
    const float* tconv_w3 = (const float*)d_in[12];
    const float* tconv_b3 = (const float*)d_in[13];
    const float* tconv_w5 = (const float*)d_in[14];
    const float* tconv_b5 = (const float*)d_in[15];
    const float* tconv_w7 = (const float*)d_in[16];
    const float* tconv_b7 = (const float*)d_in[17];
    const float* ff_w    = (const float*)d_in[18];
    const float* ff_b    = (const float*)d_in[19];
    const float* lower_w = (const float*)d_in[20];
    const float* lower_b = (const float*)d_in[21];
    const float* upper_w = (const float*)d_in[22];
    const float* upper_b = (const float*)d_in[23];
    const float* agg_w   = (const float*)d_in[24];
    const float* agg_b   = (const float*)d_in[25];
    const float* disc_w  = (const float*)d_in[26];
    const float* disc_b  = (const float*)d_in[27];
    const float* fc_w    = (const float*)d_in[28];
    const float* fc_b    = (const float*)d_in[29];

    float* ws = (float*)d_ws;
    float* bufA  = ws;
    float* bufB  = ws + 3145728;
    float* bufC  = ws + 5242880;
    float* henc0 = ws + 7340032;
    float* henc1 = henc0 + 524288;
    float* dd    = henc1 + 524288;
    float* dinv  = dd + 524288;
    float* dinv2 = dinv + NROWS;
    int* cnt1  = (int*)(dinv2 + GROWS);
    int* offs1 = cnt1 + NROWS;
    int* cur1  = offs1 + NROWS + 1;
    int* esrc1 = cur1 + NROWS;
    int* cnt2  = esrc1 + E1;
    int* offs2 = cnt2 + GROWS;
    int* cur2  = offs2 + GROWS + 1;
    int* esrc2 = cur2 + GROWS;

    for (int e = 0; e < 2; ++e) {
        float* henc = e ? henc1 : henc0;
        float* feats = bufA;
        float* h0 = bufB;
        float* hw = bufC;

        k_zero_i<<<NROWS / 256, 256, 0, stream>>>(cnt1, NROWS);
        k_hist<<<E1 / 256, 256, 0, stream>>>(ei[e] + E1, cnt1, E1);
        k_scan<<<1, 1024, 0, stream>>>(cnt1, offs1, cur1, dinv, NROWS);
        k_fill<<<E1 / 256, 256, 0, stream>>>(ei[e], cur1, esrc1, E1);

        k_conv_feats<<<NROWS / 8, 256, 0, stream>>>(x[e],
            conv_w3, conv_b3, conv_w5, conv_b5, conv_w7, conv_b7,
            tconv_w3, tconv_b3, tconv_w5, tconv_b5, tconv_w7, tconv_b7, feats);
        k_ff<<<NROWS / 16, 128, 0, stream>>>(feats, ff_w, ff_b, h0);
        k_gemm128<<<NROWS / 16, 128, 0, stream>>>(h0, lower_w, hw);

        float* gout = bufA;
        k_gcn_gather<<<NROWS, 128, 0, stream>>>(offs1, esrc1, hw, dinv, lower_b, gout);

        float* hg = bufB;
        k_agg<<<(Bn / 4) * 16, 256, 0, stream>>>(gout, agg_w, agg_b, hg);
        float* hgw = bufB + 524288;
        k_gemm128<<<GROWS / 16, 128, 0, stream>>>(hg, upper_w, hgw);

        k_zero_i<<<GROWS / 256, 256, 0, stream>>>(cnt2, GROWS);
        k_hist<<<E2 / 256, 256, 0, stream>>>(gei[e] + E2, cnt2, E2);
        k_scan<<<1, 1024, 0, stream>>>(cnt2, offs2, cur2, dinv2, GROWS);
        k_fill<<<E2 / 256, 256, 0, stream>>>(gei[e], cur2, esrc2, E2);

        k_gcn_gather<<<GROWS, 128, 0, stream>>>(offs2, esrc2, hgw, dinv2, upper_b, henc);
    }

    k_disc<<<(Bn / 4) * 16, 256, 0, stream>>>(henc0, henc1, disc_w, disc_b, dd);
    k_fc<<<Bn, 256, 0, stream>>>(dd, fc_w, fc_b, (float*)d_out);
}

// Round 6
// 400.743 us; speedup vs baseline: 7.1260x; 1.0800x over previous
//
#include <hip/hip_runtime.h>
#include <hip/hip_bf16.h>

namespace {

constexpr int Bn      = 256;
constexpr int NNODES  = 64;
constexpr int NGROUPS = 16;
constexpr int L       = 64;
constexpr int C       = 32;
constexpr int GH      = 128;
constexpr int E1      = 262144;
constexpr int E2      = 32768;
constexpr int NROWS   = Bn * NNODES;   // 16384
constexpr int GROWS   = Bn * NGROUPS;  // 4096

// ---------------- conv + max + relu -> feats [2*NROWS,192] ----------------
template<int K, int LX>
__device__ __forceinline__ float convmax(const float* __restrict__ xin,
                                         const float* __restrict__ wp)
{
    constexpr int PAD = (K - 1) / 2;
    float w[K];
    #pragma unroll
    for (int i = 0; i < K; ++i) w[i] = wp[i];
    float m = -3.0e38f;
    #pragma unroll
    for (int p = 0; p < LX; ++p) {
        float s = 0.f;
        #pragma unroll
        for (int i = 0; i < K; ++i) s = fmaf(w[i], xin[p - PAD + i], s);
        m = fmaxf(m, s);
    }
    return m;
}

// grid = 2*NROWS/8 ; block 256. Upper half of grid = encoder 1.
__global__ __launch_bounds__(256) void k_conv_feats(
    const float* __restrict__ x1, const float* __restrict__ x2,
    const float* __restrict__ w3,  const float* __restrict__ b3,
    const float* __restrict__ w5,  const float* __restrict__ b5,
    const float* __restrict__ w7,  const float* __restrict__ b7,
    const float* __restrict__ tw3, const float* __restrict__ tb3,
    const float* __restrict__ tw5, const float* __restrict__ tb5,
    const float* __restrict__ tw7, const float* __restrict__ tb7,
    float* __restrict__ feats)
{
    __shared__ float xs[8 * 4 * 72];
    const int t = threadIdx.x;             // 256
    const int eb = blockIdx.x >> 11;       // 0,1 (2048 blocks per encoder)
    const float* __restrict__ x = eb ? x2 : x1;
    const int row0 = (blockIdx.x & 2047) * 8;
    for (int idx = t; idx < 8 * 4 * 72; idx += 256) {
        const int r   = idx / 288;
        const int rem = idx - r * 288;
        const int c   = rem / 72;
        const int j   = rem - c * 72;
        const int l   = j - 3;
        float v = 0.f;
        if (l >= 0 && l < 64 - 2 * c)
            v = x[(size_t)(row0 + r) * 256 + c * 64 + l];
        xs[idx] = v;
    }
    __syncthreads();

    const int r  = t >> 5;
    const int ch = t & 31;
    const int rowl = row0 + r;
    const int n   = rowl & (NNODES - 1);
    const int wc  = n * C + ch;
    const float* xb0 = &xs[r * 288 + 0 * 72 + 3];
    const float* xb1 = &xs[r * 288 + 1 * 72 + 3];
    const float* xb2 = &xs[r * 288 + 2 * 72 + 3];
    const float* xb3 = &xs[r * 288 + 3 * 72 + 3];

    float* o = feats + (size_t)(eb * NROWS + rowl) * 192 + ch;
    o[0 * 32] = fmaxf(convmax<3, 64>(xb0, w3  + wc * 3) + b3[wc],  0.f);
    o[1 * 32] = fmaxf(convmax<5, 64>(xb0, w5  + wc * 5) + b5[wc],  0.f);
    o[2 * 32] = fmaxf(convmax<7, 64>(xb0, w7  + wc * 7) + b7[wc],  0.f);
    o[3 * 32] = fmaxf(convmax<3, 62>(xb1, tw3 + wc * 3) + tb3[wc], 0.f);
    o[4 * 32] = fmaxf(convmax<5, 60>(xb2, tw5 + wc * 5) + tb5[wc], 0.f);
    o[5 * 32] = fmaxf(convmax<7, 58>(xb3, tw7 + wc * 7) + tb7[wc], 0.f);
}

// ---------------- per-node FF 192->128 + relu (v2: K-split 2, unroll 8) -----
// grid = 2*1024 ; block 256. Combined batch 512 (both encoders).
__global__ __launch_bounds__(256) void k_ff(
    const float* __restrict__ feats, const float* __restrict__ ffw,
    const float* __restrict__ ffb, float* __restrict__ h0)
{
    const int nb = blockIdx.x >> 6;        // 0..31 (b-tile over 512)
    const int n  = blockIdx.x & 63;
    const int t  = threadIdx.x;
    const int o  = t & 127;
    const int kk = t >> 7;                 // 0..1
    __shared__ float fs[16 * 192];
    __shared__ float red[2][16][128];
    for (int i = t; i < 16 * 192; i += 256) {
        const int r = i / 192, c = i - r * 192;
        fs[i] = feats[((size_t)(nb * 16 + r) * 64 + n) * 192 + c];
    }
    __syncthreads();
    const float* w = ffw + (size_t)n * 192 * 128 + (kk * 96) * 128 + o;
    const float* xr = fs + kk * 96;
    float acc[16];
    #pragma unroll
    for (int r = 0; r < 16; ++r) acc[r] = 0.f;
    #pragma unroll 8
    for (int f = 0; f < 96; ++f) {
        const float wv = w[f * 128];
        #pragma unroll
        for (int r = 0; r < 16; ++r) acc[r] = fmaf(xr[r * 192 + f], wv, acc[r]);
    }
    #pragma unroll
    for (int r = 0; r < 16; ++r) red[kk][r][o] = acc[r];
    __syncthreads();
    if (t < 128) {
        const float bias = ffb[n * 128 + t];
        #pragma unroll
        for (int r = 0; r < 16; ++r)
            h0[((size_t)(nb * 16 + r) * 64 + n) * 128 + t] =
                fmaxf(red[0][r][t] + red[1][r][t] + bias, 0.f);
    }
}

// ---------------- shared-weight 128x128 GEMM (v2: K-split 2, unroll 8) ------
// grid = rows/16 ; block 256.
__global__ __launch_bounds__(256) void k_gemm128(
    const float* __restrict__ X, const float* __restrict__ W,
    float* __restrict__ Y)
{
    const int r0 = blockIdx.x * 16;
    const int t  = threadIdx.x;
    const int o  = t & 127;
    const int kk = t >> 7;
    __shared__ float xs[16 * 128];
    __shared__ float red[2][16][128];
    for (int i = t; i < 2048; i += 256) xs[i] = X[(size_t)r0 * 128 + i];
    __syncthreads();
    const float* w = W + (kk * 64) * 128 + o;
    const float* xr = xs + kk * 64;
    float acc[16];
    #pragma unroll
    for (int r = 0; r < 16; ++r) acc[r] = 0.f;
    #pragma unroll 8
    for (int f = 0; f < 64; ++f) {
        const float wv = w[f * 128];
        #pragma unroll
        for (int r = 0; r < 16; ++r) acc[r] = fmaf(xr[r * 128 + f], wv, acc[r]);
    }
    #pragma unroll
    for (int r = 0; r < 16; ++r) red[kk][r][o] = acc[r];
    __syncthreads();
    if (t < 128) {
        #pragma unroll
        for (int r = 0; r < 16; ++r)
            Y[(size_t)(r0 + r) * 128 + t] = red[0][r][t] + red[1][r][t];
    }
}

// ---------------- CSR build (both encoders fused; combined arrays) ---------
__global__ void k_zero_i(int* __restrict__ p, int n) {
    const int i = blockIdx.x * blockDim.x + threadIdx.x;
    if (i < n) p[i] = 0;
}
__global__ void k_hist2(const int* __restrict__ eia, const int* __restrict__ eib,
                        int* __restrict__ cnt, int E, int n)
{
    const int gid = blockIdx.x * blockDim.x + threadIdx.x;
    const int eb = gid >= E;
    const int le = gid - (eb ? E : 0);
    if (le >= E) return;
    const int* ei = eb ? eib : eia;
    atomicAdd(&cnt[(eb ? n : 0) + ei[E + le]], 1);
}
// single-block exclusive scan over n (n/1024 <= 32); also dinv = rsqrt(1+cnt)
__global__ __launch_bounds__(1024) void k_scan(
    const int* __restrict__ cnt, int* __restrict__ offs, int* __restrict__ cur,
    float* __restrict__ dinv, int n)
{
    const int t = threadIdx.x;
    const int chunk = n >> 10;
    __shared__ int part[1024];
    int loc[32];
    int s = 0;
    const int base = t * chunk;
    for (int i = 0; i < chunk; ++i) { loc[i] = cnt[base + i]; s += loc[i]; }
    part[t] = s;
    __syncthreads();
    for (int off = 1; off < 1024; off <<= 1) {
        const int v = (t >= off) ? part[t - off] : 0;
        __syncthreads();
        part[t] += v;
        __syncthreads();
    }
    int run = (t > 0) ? part[t - 1] : 0;
    for (int i = 0; i < chunk; ++i) {
        offs[base + i] = run;
        cur[base + i]  = run;
        run += loc[i];
        dinv[base + i] = rsqrtf(1.0f + (float)loc[i]);
    }
    if (t == 1023) offs[n] = run;
}
__global__ void k_fill2(const int* __restrict__ eia, const int* __restrict__ eib,
                        int* __restrict__ cur, int* __restrict__ esrc, int E, int n)
{
    const int gid = blockIdx.x * blockDim.x + threadIdx.x;
    const int eb = gid >= E;
    const int le = gid - (eb ? E : 0);
    if (le >= E) return;
    const int* ei = eb ? eib : eia;
    const int s = ei[le];
    const int d = ei[E + le];
    const int pos = atomicAdd(&cur[(eb ? n : 0) + d], 1);
    esrc[pos] = s;                         // local source id; encoder from row
}

// ---------------- GCN gather (combined 2n rows, local CSR src ids) ---------
__global__ __launch_bounds__(128) void k_gcn_gather(
    const int* __restrict__ offs, const int* __restrict__ esrc,
    const float* __restrict__ hw, const float* __restrict__ dinv,
    const float* __restrict__ bias, float* __restrict__ out, int n)
{
    const int d = blockIdx.x;              // 0..2n-1
    const int t = threadIdx.x;             // 128
    const int sbase = (d >= n) ? n : 0;
    const int e0 = offs[d], e1 = offs[d + 1];
    const float dd = dinv[d];
    float a0 = hw[(size_t)d * 128 + t] * dd;
    float a1 = 0.f, a2 = 0.f, a3 = 0.f;
    int j = e0;
    for (; j + 3 < e1; j += 4) {
        const int s0 = sbase + esrc[j],     s1 = sbase + esrc[j + 1];
        const int s2 = sbase + esrc[j + 2], s3 = sbase + esrc[j + 3];
        a0 = fmaf(hw[(size_t)s0 * 128 + t], dinv[s0], a0);
        a1 = fmaf(hw[(size_t)s1 * 128 + t], dinv[s1], a1);
        a2 = fmaf(hw[(size_t)s2 * 128 + t], dinv[s2], a2);
        a3 = fmaf(hw[(size_t)s3 * 128 + t], dinv[s3], a3);
    }
    for (; j < e1; ++j) {
        const int s = sbase + esrc[j];
        a0 = fmaf(hw[(size_t)s * 128 + t], dinv[s], a0);
    }
    const float acc = (a0 + a1) + (a2 + a3);
    out[(size_t)d * 128 + t] = fmaf(acc, dd, bias[t]);
}

// ---------------- per-group aggregate 512->128 (4 rows, K-split 2) ----------
// grid = 2*(Bn/4)*16 ; block 256. Combined batch 512.
__global__ __launch_bounds__(256) void k_agg(
    const float* __restrict__ h, const float* __restrict__ aggw,
    const float* __restrict__ aggb, float* __restrict__ hg)
{
    const int bt = blockIdx.x >> 4;        // 0..127
    const int g  = blockIdx.x & 15;
    const int t  = threadIdx.x;
    const int o  = t & 127;
    const int kk = t >> 7;
    __shared__ float fs[4 * 512];
    __shared__ float red[2][4][128];
    {
        const int b0 = bt * 4;
        float4* dst = (float4*)fs;
        for (int i = t; i < 4 * 128; i += 256) {
            const int r = i >> 7;
            const int q = i & 127;
            dst[i] = *(const float4*)(h + ((size_t)(b0 + r) * 64 + g * 4) * 128 + q * 4);
        }
    }
    __syncthreads();
    const float* w = aggw + (size_t)g * 512 * 128 + (size_t)kk * 256 * 128 + o;
    float a0 = 0.f, a1 = 0.f, a2 = 0.f, a3 = 0.f;
    const float* x0 = fs + 0 * 512 + kk * 256;
    const float* x1 = fs + 1 * 512 + kk * 256;
    const float* x2 = fs + 2 * 512 + kk * 256;
    const float* x3 = fs + 3 * 512 + kk * 256;
    #pragma unroll 8
    for (int f = 0; f < 256; ++f) {
        const float wv = w[f * 128];
        a0 = fmaf(x0[f], wv, a0);
        a1 = fmaf(x1[f], wv, a1);
        a2 = fmaf(x2[f], wv, a2);
        a3 = fmaf(x3[f], wv, a3);
    }
    red[kk][0][o] = a0; red[kk][1][o] = a1; red[kk][2][o] = a2; red[kk][3][o] = a3;
    __syncthreads();
    if (t < 128) {
        const float bias = aggb[g * 128 + t];
        #pragma unroll
        for (int r = 0; r < 4; ++r) {
            const int b = bt * 4 + r;
            hg[((size_t)b * 16 + g) * 128 + t] = red[0][r][t] + red[1][r][t] + bias;
        }
    }
}

// ---------------- disc (4 rows, K-split 2): relu in, 256->128 + relu --------
__global__ __launch_bounds__(256) void k_disc(
    const float* __restrict__ h1, const float* __restrict__ h2,
    const float* __restrict__ dw, const float* __restrict__ db,
    float* __restrict__ dd)
{
    const int bt = blockIdx.x >> 4;        // 0..63
    const int g  = blockIdx.x & 15;
    const int t  = threadIdx.x;
    const int o  = t & 127;
    const int kk = t >> 7;
    __shared__ float fs[4 * 256];
    __shared__ float red[2][4][128];
    {
        const int half = t >> 7;
        #pragma unroll
        for (int r = 0; r < 4; ++r) {
            const int rowi = ((bt * 4 + r) * 16 + g);
            const float* src = half ? h2 : h1;
            fs[r * 256 + half * 128 + o] = fmaxf(src[(size_t)rowi * 128 + o], 0.f);
        }
    }
    __syncthreads();
    const float* w = dw + (size_t)g * 256 * 128 + (size_t)kk * 128 * 128 + o;
    float a0 = 0.f, a1 = 0.f, a2 = 0.f, a3 = 0.f;
    const float* x0 = fs + 0 * 256 + kk * 128;
    const float* x1 = fs + 1 * 256 + kk * 128;
    const float* x2 = fs + 2 * 256 + kk * 128;
    const float* x3 = fs + 3 * 256 + kk * 128;
    #pragma unroll 8
    for (int f = 0; f < 128; ++f) {
        const float wv = w[f * 128];
        a0 = fmaf(x0[f], wv, a0);
        a1 = fmaf(x1[f], wv, a1);
        a2 = fmaf(x2[f], wv, a2);
        a3 = fmaf(x3[f], wv, a3);
    }
    red[kk][0][o] = a0; red[kk][1][o] = a1; red[kk][2][o] = a2; red[kk][3][o] = a3;
    __syncthreads();
    if (t < 128) {
        const float bias = db[g * 128 + t];
        #pragma unroll
        for (int r = 0; r < 4; ++r) {
            const int b = bt * 4 + r;
            dd[(size_t)b * 2048 + g * 128 + t] =
                fmaxf(red[0][r][t] + red[1][r][t] + bias, 0.f);
        }
    }
}

// ---------------- final fc 2048->64: one block per batch row ----------------
__global__ __launch_bounds__(256) void k_fc(
    const float* __restrict__ dd, const float* __restrict__ fcw,
    const float* __restrict__ fcb, float* __restrict__ out)
{
    const int b = blockIdx.x;
    const int t = threadIdx.x;
    const int o = t & 63;
    const int k = t >> 6;                  // 0..3
    __shared__ float ds[2048];
    __shared__ float red[4][64];
    for (int i = t; i < 2048; i += 256) ds[i] = dd[(size_t)b * 2048 + i];
    __syncthreads();
    const float* w  = fcw + (k * 512) * 64 + o;
    const float* xr = ds + k * 512;
    float a0 = 0.f, a1 = 0.f, a2 = 0.f, a3 = 0.f;
    #pragma unroll 4
    for (int f = 0; f < 512; f += 4) {
        a0 = fmaf(xr[f + 0], w[(f + 0) * 64], a0);
        a1 = fmaf(xr[f + 1], w[(f + 1) * 64], a1);
        a2 = fmaf(xr[f + 2], w[(f + 2) * 64], a2);
        a3 = fmaf(xr[f + 3], w[(f + 3) * 64], a3);
    }
    red[k][o] = (a0 + a1) + (a2 + a3);
    __syncthreads();
    if (t < 64)
        out[(size_t)b * 64 + t] = ((red[0][t] + red[1][t]) + (red[2][t] + red[3][t])) + fcb[t];
}

} // namespace

extern "C" void kernel_launch(void* const* d_in, const int* in_sizes, int n_in,
                              void* d_out, int out_size, void* d_ws, size_t ws_size,
                              hipStream_t stream)
{
    const float* x1 = (const float*)d_in[0];
    const float* x2 = (const float*)d_in[1];
    const int* ei0  = (const int*)d_in[2];
    const int* ei1  = (const int*)d_in[3];
    const int* gei0 = (const int*)d_in[4];
    const int* gei1 = (const int*)d_in[5];
    const float* conv_w3 = (const float*)d_in[6];
    const float* conv_b3 = (const float*)d_in[7];
    const float* conv_w5 = (const float*)d_in[8];
    const float* conv_b5 = (const float*)d_in[9];
    const float* conv_w7 = (const float*)d_in[10];
    const float* conv_b7 = (const float*)d_in[11];
    const float* tconv_w3 = (const float*)d_in[12];
    const float* tconv_b3 = (const float*)d_in[13];
    const float* tconv_w5 = (const float*)d_in[14];
    const float* tconv_b5 = (const float*)d_in[15];
    const float* tconv_w7 = (const float*)d_in[16];
    const float* tconv_b7 = (const float*)d_in[17];
    const float* ff_w    = (const float*)d_in[18];
    const float* ff_b    = (const float*)d_in[19];
    const float* lower_w = (const float*)d_in[20];
    const float* lower_b = (const float*)d_in[21];
    const float* upper_w = (const float*)d_in[22];
    const float* upper_b = (const float*)d_in[23];
    const float* agg_w   = (const float*)d_in[24];
    const float* agg_b   = (const float*)d_in[25];
    const float* disc_w  = (const float*)d_in[26];
    const float* disc_b  = (const float*)d_in[27];
    const float* fc_w    = (const float*)d_in[28];
    const float* fc_b    = (const float*)d_in[29];

    float* ws = (float*)d_ws;
    // combined (both-encoder) buffers, no aliasing
    float* f_feats = ws;                          // 6291456
    float* f_h0    = ws + 6291456;                // 4194304
    float* f_hw    = ws + 10485760;               // 4194304
    float* f_gout  = ws + 14680064;               // 4194304
    float* f_hg    = ws + 18874368;               // 1048576
    float* f_hgw   = ws + 19922944;               // 1048576
    float* f_henc  = ws + 20971520;               // 1048576
    float* f_dd    = ws + 22020096;               // 524288
    float* f_dinv1 = ws + 22544384;               // 32768
    float* f_dinv2 = ws + 22577152;               // 8192
    int* ip    = (int*)(ws + 22585344);
    int* cnt1  = ip;                              // 32768
    int* offs1 = cnt1 + 2 * NROWS;                // 32769
    int* cur1  = offs1 + 2 * NROWS + 1;           // 32768
    int* esrc1 = cur1 + 2 * NROWS;                // 524288
    int* cnt2  = esrc1 + 2 * E1;                  // 8192
    int* offs2 = cnt2 + 2 * GROWS;                // 8193
    int* cur2  = offs2 + 2 * GROWS + 1;           // 8192
    int* esrc2 = cur2 + 2 * GROWS;                // 65536

    // CSR for node graphs (both encoders, combined arrays)
    k_zero_i<<<(2 * NROWS) / 256, 256, 0, stream>>>(cnt1, 2 * NROWS);
    k_hist2<<<(2 * E1) / 256, 256, 0, stream>>>(ei0, ei1, cnt1, E1, NROWS);
    k_scan<<<1, 1024, 0, stream>>>(cnt1, offs1, cur1, f_dinv1, 2 * NROWS);
    k_fill2<<<(2 * E1) / 256, 256, 0, stream>>>(ei0, ei1, cur1, esrc1, E1, NROWS);
    // CSR for group graphs
    k_zero_i<<<(2 * GROWS) / 256, 256, 0, stream>>>(cnt2, 2 * GROWS);
    k_hist2<<<(2 * E2) / 256, 256, 0, stream>>>(gei0, gei1, cnt2, E2, GROWS);
    k_scan<<<1, 1024, 0, stream>>>(cnt2, offs2, cur2, f_dinv2, 2 * GROWS);
    k_fill2<<<(2 * E2) / 256, 256, 0, stream>>>(gei0, gei1, cur2, esrc2, E2, GROWS);

    // encoder pipeline (both encoders per dispatch)
    k_conv_feats<<<2 * NROWS / 8, 256, 0, stream>>>(x1, x2,
        conv_w3, conv_b3, conv_w5, conv_b5, conv_w7, conv_b7,
        tconv_w3, tconv_b3, tconv_w5, tconv_b5, tconv_w7, tconv_b7, f_feats);
    k_ff<<<2 * (NROWS / 16) / 64 * 64, 256, 0, stream>>>(f_feats, ff_w, ff_b, f_h0);
    k_gemm128<<<2 * NROWS / 16, 256, 0, stream>>>(f_h0, lower_w, f_hw);
    k_gcn_gather<<<2 * NROWS, 128, 0, stream>>>(offs1, esrc1, f_hw, f_dinv1,
                                                lower_b, f_gout, NROWS);
    k_agg<<<2 * (Bn / 4) * 16, 256, 0, stream>>>(f_gout, agg_w, agg_b, f_hg);
    k_gemm128<<<2 * GROWS / 16, 256, 0, stream>>>(f_hg, upper_w, f_hgw);
    k_gcn_gather<<<2 * GROWS, 128, 0, stream>>>(offs2, esrc2, f_hgw, f_dinv2,
                                                upper_b, f_henc, GROWS);

    k_disc<<<(Bn / 4) * 16, 256, 0, stream>>>(f_henc, f_henc + (size_t)GROWS * 128,
                                              disc_w, disc_b, f_dd);
    k_fc<<<Bn, 256, 0, stream>>>(f_dd, fc_w, fc_b, (float*)d_out);
}

// Round 7
// 294.187 us; speedup vs baseline: 9.7070x; 1.3622x over previous
//
#include <hip/hip_runtime.h>
#include <hip/hip_bf16.h>

namespace {

constexpr int Bn      = 256;
constexpr int NNODES  = 64;
constexpr int NGROUPS = 16;
constexpr int L       = 64;
constexpr int C       = 32;
constexpr int GH      = 128;
constexpr int E1      = 262144;
constexpr int E2      = 32768;
constexpr int NROWS   = Bn * NNODES;   // 16384
constexpr int GROWS   = Bn * NGROUPS;  // 4096

// ---------------- conv + max + relu -> feats [2*NROWS,192] ----------------
template<int K, int LX>
__device__ __forceinline__ float convmax(const float* __restrict__ xin,
                                         const float* __restrict__ wp)
{
    constexpr int PAD = (K - 1) / 2;
    float w[K];
    #pragma unroll
    for (int i = 0; i < K; ++i) w[i] = wp[i];
    float m = -3.0e38f;
    #pragma unroll
    for (int p = 0; p < LX; ++p) {
        float s = 0.f;
        #pragma unroll
        for (int i = 0; i < K; ++i) s = fmaf(w[i], xin[p - PAD + i], s);
        m = fmaxf(m, s);
    }
    return m;
}

// grid = 2*NROWS/8 ; block 256. Upper half of grid = encoder 1.
__global__ __launch_bounds__(256) void k_conv_feats(
    const float* __restrict__ x1, const float* __restrict__ x2,
    const float* __restrict__ w3,  const float* __restrict__ b3,
    const float* __restrict__ w5,  const float* __restrict__ b5,
    const float* __restrict__ w7,  const float* __restrict__ b7,
    const float* __restrict__ tw3, const float* __restrict__ tb3,
    const float* __restrict__ tw5, const float* __restrict__ tb5,
    const float* __restrict__ tw7, const float* __restrict__ tb7,
    float* __restrict__ feats)
{
    __shared__ float xs[8 * 4 * 72];
    const int t = threadIdx.x;             // 256
    const int eb = blockIdx.x >> 11;       // 0,1
    const float* __restrict__ x = eb ? x2 : x1;
    const int row0 = (blockIdx.x & 2047) * 8;
    for (int idx = t; idx < 8 * 4 * 72; idx += 256) {
        const int r   = idx / 288;
        const int rem = idx - r * 288;
        const int c   = rem / 72;
        const int j   = rem - c * 72;
        const int l   = j - 3;
        float v = 0.f;
        if (l >= 0 && l < 64 - 2 * c)
            v = x[(size_t)(row0 + r) * 256 + c * 64 + l];
        xs[idx] = v;
    }
    __syncthreads();

    const int r  = t >> 5;
    const int ch = t & 31;
    const int rowl = row0 + r;
    const int n   = rowl & (NNODES - 1);
    const int wc  = n * C + ch;
    const float* xb0 = &xs[r * 288 + 0 * 72 + 3];
    const float* xb1 = &xs[r * 288 + 1 * 72 + 3];
    const float* xb2 = &xs[r * 288 + 2 * 72 + 3];
    const float* xb3 = &xs[r * 288 + 3 * 72 + 3];

    float* o = feats + (size_t)(eb * NROWS + rowl) * 192 + ch;
    o[0 * 32] = fmaxf(convmax<3, 64>(xb0, w3  + wc * 3) + b3[wc],  0.f);
    o[1 * 32] = fmaxf(convmax<5, 64>(xb0, w5  + wc * 5) + b5[wc],  0.f);
    o[2 * 32] = fmaxf(convmax<7, 64>(xb0, w7  + wc * 7) + b7[wc],  0.f);
    o[3 * 32] = fmaxf(convmax<3, 62>(xb1, tw3 + wc * 3) + tb3[wc], 0.f);
    o[4 * 32] = fmaxf(convmax<5, 60>(xb2, tw5 + wc * 5) + tb5[wc], 0.f);
    o[5 * 32] = fmaxf(convmax<7, 58>(xb3, tw7 + wc * 7) + tb7[wc], 0.f);
}

// ---------------- per-node FF 192->128 + relu (v3: float4 K-quads) ---------
// grid = 2048 ; block 256: o = t&127 (out col), rh = t>>7 (row half).
__global__ __launch_bounds__(256) void k_ff(
    const float* __restrict__ feats, const float* __restrict__ ffw,
    const float* __restrict__ ffb, float* __restrict__ h0)
{
    const int nb = blockIdx.x >> 6;        // 0..31 (b-tile over 512)
    const int n  = blockIdx.x & 63;
    const int t  = threadIdx.x;
    const int o  = t & 127;
    const int rh = t >> 7;                 // 0..1
    __shared__ float fs[16 * 192];
    // staging: float4, coalesced
    {
        float4* d4 = (float4*)fs;
        for (int i = t; i < 16 * 48; i += 256) {
            const int r = i / 48, c4 = i - r * 48;
            d4[i] = *(const float4*)(feats + ((size_t)(nb * 16 + r) * 64 + n) * 192 + c4 * 4);
        }
    }
    __syncthreads();
    const float* w = ffw + (size_t)n * 192 * 128 + o;
    float acc[8];
    #pragma unroll
    for (int r = 0; r < 8; ++r) acc[r] = 0.f;
    #pragma unroll 2
    for (int f = 0; f < 192; f += 4) {
        const float w0 = w[(f + 0) * 128];
        const float w1 = w[(f + 1) * 128];
        const float w2 = w[(f + 2) * 128];
        const float w3_ = w[(f + 3) * 128];
        #pragma unroll
        for (int r = 0; r < 8; ++r) {
            const float4 xv = *(const float4*)(fs + (rh * 8 + r) * 192 + f);
            acc[r] = fmaf(xv.x, w0, acc[r]);
            acc[r] = fmaf(xv.y, w1, acc[r]);
            acc[r] = fmaf(xv.z, w2, acc[r]);
            acc[r] = fmaf(xv.w, w3_, acc[r]);
        }
    }
    const float bias = ffb[n * 128 + o];
    #pragma unroll
    for (int r = 0; r < 8; ++r) {
        const int row = nb * 16 + rh * 8 + r;
        h0[((size_t)row * 64 + n) * 128 + o] = fmaxf(acc[r] + bias, 0.f);
    }
}

// ---------------- shared-weight 128x128 GEMM (v3: float4 K-quads) ----------
// grid = rows/16 ; block 256.
__global__ __launch_bounds__(256) void k_gemm128(
    const float* __restrict__ X, const float* __restrict__ W,
    float* __restrict__ Y)
{
    const int r0 = blockIdx.x * 16;
    const int t  = threadIdx.x;
    const int o  = t & 127;
    const int rh = t >> 7;
    __shared__ float xs[16 * 128];
    {
        float4* d4 = (float4*)xs;
        const float4* s4 = (const float4*)(X + (size_t)r0 * 128);
        for (int i = t; i < 512; i += 256) d4[i] = s4[i];
    }
    __syncthreads();
    const float* w = W + o;
    float acc[8];
    #pragma unroll
    for (int r = 0; r < 8; ++r) acc[r] = 0.f;
    #pragma unroll 2
    for (int f = 0; f < 128; f += 4) {
        const float w0 = w[(f + 0) * 128];
        const float w1 = w[(f + 1) * 128];
        const float w2 = w[(f + 2) * 128];
        const float w3_ = w[(f + 3) * 128];
        #pragma unroll
        for (int r = 0; r < 8; ++r) {
            const float4 xv = *(const float4*)(xs + (rh * 8 + r) * 128 + f);
            acc[r] = fmaf(xv.x, w0, acc[r]);
            acc[r] = fmaf(xv.y, w1, acc[r]);
            acc[r] = fmaf(xv.z, w2, acc[r]);
            acc[r] = fmaf(xv.w, w3_, acc[r]);
        }
    }
    #pragma unroll
    for (int r = 0; r < 8; ++r)
        Y[(size_t)(r0 + rh * 8 + r) * 128 + o] = acc[r];
}

// ---------------- CSR build (both encoders fused; combined arrays) ---------
__global__ void k_zero_i(int* __restrict__ p, int n) {
    const int i = blockIdx.x * blockDim.x + threadIdx.x;
    if (i < n) p[i] = 0;
}
__global__ void k_hist2(const int* __restrict__ eia, const int* __restrict__ eib,
                        int* __restrict__ cnt, int E, int n)
{
    const int gid = blockIdx.x * blockDim.x + threadIdx.x;
    const int eb = gid >= E;
    const int le = gid - (eb ? E : 0);
    if (le >= E) return;
    const int* ei = eb ? eib : eia;
    atomicAdd(&cnt[(eb ? n : 0) + ei[E + le]], 1);
}
// ---- two-level scan: block sums, then per-block scan+write -----------------
__global__ __launch_bounds__(256) void k_scan_bsum(
    const int* __restrict__ cnt, int* __restrict__ bsum)
{
    const int t = threadIdx.x;
    const int4 v = ((const int4*)cnt)[blockIdx.x * 256 + t];
    int s = v.x + v.y + v.z + v.w;
    #pragma unroll
    for (int off = 32; off > 0; off >>= 1) s += __shfl_down(s, off);
    __shared__ int wsum[4];
    if ((t & 63) == 0) wsum[t >> 6] = s;
    __syncthreads();
    if (t == 0) bsum[blockIdx.x] = wsum[0] + wsum[1] + wsum[2] + wsum[3];
}
__global__ __launch_bounds__(256) void k_scan_final(
    const int* __restrict__ cnt, const int* __restrict__ bsum, int nb,
    int* __restrict__ offs, int* __restrict__ cur, float* __restrict__ dinv, int n)
{
    const int blk = blockIdx.x, t = threadIdx.x;
    int base = 0;
    for (int i = 0; i < blk; ++i) base += bsum[i];
    const int4 v = ((const int4*)cnt)[blk * 256 + t];
    const int s = v.x + v.y + v.z + v.w;
    int sc = s;
    #pragma unroll
    for (int off = 1; off < 64; off <<= 1) {
        const int u = __shfl_up(sc, off);
        if ((t & 63) >= off) sc += u;
    }
    __shared__ int wsum[4];
    if ((t & 63) == 63) wsum[t >> 6] = sc;
    __syncthreads();
    int wbase = 0;
    for (int wv = 0; wv < (t >> 6); ++wv) wbase += wsum[wv];
    int o0 = base + wbase + sc - s;
    const int gi = blk * 1024 + t * 4;
    offs[gi + 0] = o0; cur[gi + 0] = o0; dinv[gi + 0] = rsqrtf(1.f + (float)v.x); o0 += v.x;
    offs[gi + 1] = o0; cur[gi + 1] = o0; dinv[gi + 1] = rsqrtf(1.f + (float)v.y); o0 += v.y;
    offs[gi + 2] = o0; cur[gi + 2] = o0; dinv[gi + 2] = rsqrtf(1.f + (float)v.z); o0 += v.z;
    offs[gi + 3] = o0; cur[gi + 3] = o0; dinv[gi + 3] = rsqrtf(1.f + (float)v.w); o0 += v.w;
    if (blk == nb - 1 && t == 255) offs[n] = o0;
}
__global__ void k_fill2(const int* __restrict__ eia, const int* __restrict__ eib,
                        int* __restrict__ cur, int* __restrict__ esrc, int E, int n)
{
    const int gid = blockIdx.x * blockDim.x + threadIdx.x;
    const int eb = gid >= E;
    const int le = gid - (eb ? E : 0);
    if (le >= E) return;
    const int* ei = eb ? eib : eia;
    const int s = ei[le];
    const int d = ei[E + le];
    const int pos = atomicAdd(&cur[(eb ? n : 0) + d], 1);
    esrc[pos] = s;
}

// ---------------- GCN gather (combined 2n rows, local CSR src ids) ---------
__global__ __launch_bounds__(128) void k_gcn_gather(
    const int* __restrict__ offs, const int* __restrict__ esrc,
    const float* __restrict__ hw, const float* __restrict__ dinv,
    const float* __restrict__ bias, float* __restrict__ out, int n)
{
    const int d = blockIdx.x;
    const int t = threadIdx.x;             // 128
    const int sbase = (d >= n) ? n : 0;
    const int e0 = offs[d], e1 = offs[d + 1];
    const float dd = dinv[d];
    float a0 = hw[(size_t)d * 128 + t] * dd;
    float a1 = 0.f, a2 = 0.f, a3 = 0.f;
    int j = e0;
    for (; j + 3 < e1; j += 4) {
        const int s0 = sbase + esrc[j],     s1 = sbase + esrc[j + 1];
        const int s2 = sbase + esrc[j + 2], s3 = sbase + esrc[j + 3];
        a0 = fmaf(hw[(size_t)s0 * 128 + t], dinv[s0], a0);
        a1 = fmaf(hw[(size_t)s1 * 128 + t], dinv[s1], a1);
        a2 = fmaf(hw[(size_t)s2 * 128 + t], dinv[s2], a2);
        a3 = fmaf(hw[(size_t)s3 * 128 + t], dinv[s3], a3);
    }
    for (; j < e1; ++j) {
        const int s = sbase + esrc[j];
        a0 = fmaf(hw[(size_t)s * 128 + t], dinv[s], a0);
    }
    const float acc = (a0 + a1) + (a2 + a3);
    out[(size_t)d * 128 + t] = fmaf(acc, dd, bias[t]);
}

// ---------------- per-group aggregate 512->128 (4 rows, K-split 2) ----------
__global__ __launch_bounds__(256) void k_agg(
    const float* __restrict__ h, const float* __restrict__ aggw,
    const float* __restrict__ aggb, float* __restrict__ hg)
{
    const int bt = blockIdx.x >> 4;        // 0..127
    const int g  = blockIdx.x & 15;
    const int t  = threadIdx.x;
    const int o  = t & 127;
    const int kk = t >> 7;
    __shared__ float fs[4 * 512];
    __shared__ float red[2][4][128];
    {
        const int b0 = bt * 4;
        float4* dst = (float4*)fs;
        for (int i = t; i < 4 * 128; i += 256) {
            const int r = i >> 7;
            const int q = i & 127;
            dst[i] = *(const float4*)(h + ((size_t)(b0 + r) * 64 + g * 4) * 128 + q * 4);
        }
    }
    __syncthreads();
    const float* w = aggw + (size_t)g * 512 * 128 + (size_t)kk * 256 * 128 + o;
    float a0 = 0.f, a1 = 0.f, a2 = 0.f, a3 = 0.f;
    const float* x0 = fs + 0 * 512 + kk * 256;
    const float* x1 = fs + 1 * 512 + kk * 256;
    const float* x2 = fs + 2 * 512 + kk * 256;
    const float* x3 = fs + 3 * 512 + kk * 256;
    #pragma unroll 8
    for (int f = 0; f < 256; ++f) {
        const float wv = w[f * 128];
        a0 = fmaf(x0[f], wv, a0);
        a1 = fmaf(x1[f], wv, a1);
        a2 = fmaf(x2[f], wv, a2);
        a3 = fmaf(x3[f], wv, a3);
    }
    red[kk][0][o] = a0; red[kk][1][o] = a1; red[kk][2][o] = a2; red[kk][3][o] = a3;
    __syncthreads();
    if (t < 128) {
        const float bias = aggb[g * 128 + t];
        #pragma unroll
        for (int r = 0; r < 4; ++r) {
            const int b = bt * 4 + r;
            hg[((size_t)b * 16 + g) * 128 + t] = red[0][r][t] + red[1][r][t] + bias;
        }
    }
}

// ---------------- disc (4 rows, K-split 2): relu in, 256->128 + relu --------
__global__ __launch_bounds__(256) void k_disc(
    const float* __restrict__ h1, const float* __restrict__ h2,
    const float* __restrict__ dw, const float* __restrict__ db,
    float* __restrict__ dd)
{
    const int bt = blockIdx.x >> 4;        // 0..63
    const int g  = blockIdx.x & 15;
    const int t  = threadIdx.x;
    const int o  = t & 127;
    const int kk = t >> 7;
    __shared__ float fs[4 * 256];
    __shared__ float red[2][4][128];
    {
        const int half = t >> 7;
        #pragma unroll
        for (int r = 0; r < 4; ++r) {
            const int rowi = ((bt * 4 + r) * 16 + g);
            const float* src = half ? h2 : h1;
            fs[r * 256 + half * 128 + o] = fmaxf(src[(size_t)rowi * 128 + o], 0.f);
        }
    }
    __syncthreads();
    const float* w = dw + (size_t)g * 256 * 128 + (size_t)kk * 128 * 128 + o;
    float a0 = 0.f, a1 = 0.f, a2 = 0.f, a3 = 0.f;
    const float* x0 = fs + 0 * 256 + kk * 128;
    const float* x1 = fs + 1 * 256 + kk * 128;
    const float* x2 = fs + 2 * 256 + kk * 128;
    const float* x3 = fs + 3 * 256 + kk * 128;
    #pragma unroll 8
    for (int f = 0; f < 128; ++f) {
        const float wv = w[f * 128];
        a0 = fmaf(x0[f], wv, a0);
        a1 = fmaf(x1[f], wv, a1);
        a2 = fmaf(x2[f], wv, a2);
        a3 = fmaf(x3[f], wv, a3);
    }
    red[kk][0][o] = a0; red[kk][1][o] = a1; red[kk][2][o] = a2; red[kk][3][o] = a3;
    __syncthreads();
    if (t < 128) {
        const float bias = db[g * 128 + t];
        #pragma unroll
        for (int r = 0; r < 4; ++r) {
            const int b = bt * 4 + r;
            dd[(size_t)b * 2048 + g * 128 + t] =
                fmaxf(red[0][r][t] + red[1][r][t] + bias, 0.f);
        }
    }
}

// ---------------- final fc 2048->64: one block per batch row ----------------
__global__ __launch_bounds__(256) void k_fc(
    const float* __restrict__ dd, const float* __restrict__ fcw,
    const float* __restrict__ fcb, float* __restrict__ out)
{
    const int b = blockIdx.x;
    const int t = threadIdx.x;
    const int o = t & 63;
    const int k = t >> 6;                  // 0..3
    __shared__ float ds[2048];
    __shared__ float red[4][64];
    for (int i = t; i < 2048; i += 256) ds[i] = dd[(size_t)b * 2048 + i];
    __syncthreads();
    const float* w  = fcw + (k * 512) * 64 + o;
    const float* xr = ds + k * 512;
    float a0 = 0.f, a1 = 0.f, a2 = 0.f, a3 = 0.f;
    #pragma unroll 4
    for (int f = 0; f < 512; f += 4) {
        a0 = fmaf(xr[f + 0], w[(f + 0) * 64], a0);
        a1 = fmaf(xr[f + 1], w[(f + 1) * 64], a1);
        a2 = fmaf(xr[f + 2], w[(f + 2) * 64], a2);
        a3 = fmaf(xr[f + 3], w[(f + 3) * 64], a3);
    }
    red[k][o] = (a0 + a1) + (a2 + a3);
    __syncthreads();
    if (t < 64)
        out[(size_t)b * 64 + t] = ((red[0][t] + red[1][t]) + (red[2][t] + red[3][t])) + fcb[t];
}

} // namespace

extern "C" void kernel_launch(void* const* d_in, const int* in_sizes, int n_in,
                              void* d_out, int out_size, void* d_ws, size_t ws_size,
                              hipStream_t stream)
{
    const float* x1 = (const float*)d_in[0];
    const float* x2 = (const float*)d_in[1];
    const int* ei0  = (const int*)d_in[2];
    const int* ei1  = (const int*)d_in[3];
    const int* gei0 = (const int*)d_in[4];
    const int* gei1 = (const int*)d_in[5];
    const float* conv_w3 = (const float*)d_in[6];
    const float* conv_b3 = (const float*)d_in[7];
    const float* conv_w5 = (const float*)d_in[8];
    const float* conv_b5 = (const float*)d_in[9];
    const float* conv_w7 = (const float*)d_in[10];
    const float* conv_b7 = (const float*)d_in[11];
    const float* tconv_w3 = (const float*)d_in[12];
    const float* tconv_b3 = (const float*)d_in[13];
    const float* tconv_w5 = (const float*)d_in[14];
    const float* tconv_b5 = (const float*)d_in[15];
    const float* tconv_w7 = (const float*)d_in[16];
    const float* tconv_b7 = (const float*)d_in[17];
    const float* ff_w    = (const float*)d_in[18];
    const float* ff_b    = (const float*)d_in[19];
    const float* lower_w = (const float*)d_in[20];
    const float* lower_b = (const float*)d_in[21];
    const float* upper_w = (const float*)d_in[22];
    const float* upper_b = (const float*)d_in[23];
    const float* agg_w   = (const float*)d_in[24];
    const float* agg_b   = (const float*)d_in[25];
    const float* disc_w  = (const float*)d_in[26];
    const float* disc_b  = (const float*)d_in[27];
    const float* fc_w    = (const float*)d_in[28];
    const float* fc_b    = (const float*)d_in[29];

    float* ws = (float*)d_ws;
    float* f_feats = ws;                          // 6291456
    float* f_h0    = ws + 6291456;                // 4194304
    float* f_hw    = ws + 10485760;               // 4194304
    float* f_gout  = ws + 14680064;               // 4194304
    float* f_hg    = ws + 18874368;               // 1048576
    float* f_hgw   = ws + 19922944;               // 1048576
    float* f_henc  = ws + 20971520;               // 1048576
    float* f_dd    = ws + 22020096;               // 524288
    float* f_dinv1 = ws + 22544384;               // 32768
    float* f_dinv2 = ws + 22577152;               // 8192
    int* ip    = (int*)(ws + 22585344);
    // cnt arrays first (16B-aligned for int4 loads)
    int* cnt1  = ip;                              // 32768
    int* cnt2  = cnt1 + 2 * NROWS;                // 8192
    int* offs1 = cnt2 + 2 * GROWS;                // 32769
    int* cur1  = offs1 + 2 * NROWS + 1;           // 32768
    int* esrc1 = cur1 + 2 * NROWS;                // 524288
    int* offs2 = esrc1 + 2 * E1;                  // 8193
    int* cur2  = offs2 + 2 * GROWS + 1;           // 8192
    int* esrc2 = cur2 + 2 * GROWS;                // 65536
    int* bsum1 = esrc2 + 2 * E2;                  // 32
    int* bsum2 = bsum1 + 32;                      // 8

    // CSR for node graphs
    k_zero_i<<<(2 * NROWS) / 256, 256, 0, stream>>>(cnt1, 2 * NROWS);
    k_hist2<<<(2 * E1) / 256, 256, 0, stream>>>(ei0, ei1, cnt1, E1, NROWS);
    k_scan_bsum<<<32, 256, 0, stream>>>(cnt1, bsum1);
    k_scan_final<<<32, 256, 0, stream>>>(cnt1, bsum1, 32, offs1, cur1, f_dinv1, 2 * NROWS);
    k_fill2<<<(2 * E1) / 256, 256, 0, stream>>>(ei0, ei1, cur1, esrc1, E1, NROWS);
    // CSR for group graphs
    k_zero_i<<<(2 * GROWS) / 256, 256, 0, stream>>>(cnt2, 2 * GROWS);
    k_hist2<<<(2 * E2) / 256, 256, 0, stream>>>(gei0, gei1, cnt2, E2, GROWS);
    k_scan_bsum<<<8, 256, 0, stream>>>(cnt2, bsum2);
    k_scan_final<<<8, 256, 0, stream>>>(cnt2, bsum2, 8, offs2, cur2, f_dinv2, 2 * GROWS);
    k_fill2<<<(2 * E2) / 256, 256, 0, stream>>>(gei0, gei1, cur2, esrc2, E2, GROWS);

    // encoder pipeline (both encoders per dispatch)
    k_conv_feats<<<2 * NROWS / 8, 256, 0, stream>>>(x1, x2,
        conv_w3, conv_b3, conv_w5, conv_b5, conv_w7, conv_b7,
        tconv_w3, tconv_b3, tconv_w5, tconv_b5, tconv_w7, tconv_b7, f_feats);
    k_ff<<<2048, 256, 0, stream>>>(f_feats, ff_w, ff_b, f_h0);
    k_gemm128<<<2 * NROWS / 16, 256, 0, stream>>>(f_h0, lower_w, f_hw);
    k_gcn_gather<<<2 * NROWS, 128, 0, stream>>>(offs1, esrc1, f_hw, f_dinv1,
                                                lower_b, f_gout, NROWS);
    k_agg<<<2 * (Bn / 4) * 16, 256, 0, stream>>>(f_gout, agg_w, agg_b, f_hg);
    k_gemm128<<<2 * GROWS / 16, 256, 0, stream>>>(f_hg, upper_w, f_hgw);
    k_gcn_gather<<<2 * GROWS, 128, 0, stream>>>(offs2, esrc2, f_hgw, f_dinv2,
                                                upper_b, f_henc, GROWS);

    k_disc<<<(Bn / 4) * 16, 256, 0, stream>>>(f_henc, f_henc + (size_t)GROWS * 128,
                                              disc_w, disc_b, f_dd);
    k_fc<<<Bn, 256, 0, stream>>>(f_dd, fc_w, fc_b, (float*)d_out);
}

// Round 8
// 292.616 us; speedup vs baseline: 9.7592x; 1.0054x over previous
//
#include <hip/hip_runtime.h>
#include <hip/hip_bf16.h>

namespace {

constexpr int Bn      = 256;
constexpr int NNODES  = 64;
constexpr int NGROUPS = 16;
constexpr int L       = 64;
constexpr int C       = 32;
constexpr int GH      = 128;
constexpr int E1      = 262144;
constexpr int E2      = 32768;
constexpr int NROWS   = Bn * NNODES;   // 16384
constexpr int GROWS   = Bn * NGROUPS;  // 4096

// ---------------- conv + max + relu -> feats [2*NROWS,192] ----------------
// Chunked register-window convmax: 16 output positions per chunk, window
// loaded once as 6x ds_read_b128 (xin_al is 16B-aligned segment base; data
// starts at +3; tap i of position p reads xw[p + (3-PAD) + i]).
template<int K, int LX>
__device__ __forceinline__ float convmax_w(const float* __restrict__ xin_al,
                                           const float* __restrict__ wp)
{
    constexpr int PAD = (K - 1) / 2;
    constexpr int OFF = 3 - PAD;
    float w[K];
    #pragma unroll
    for (int i = 0; i < K; ++i) w[i] = wp[i];
    float m = -3.0e38f;
    #pragma unroll
    for (int p0 = 0; p0 < LX; p0 += 16) {
        float xw[24];
        #pragma unroll
        for (int q = 0; q < 6; ++q) {
            const float4 v = *(const float4*)(xin_al + p0 + q * 4);
            xw[q * 4 + 0] = v.x; xw[q * 4 + 1] = v.y;
            xw[q * 4 + 2] = v.z; xw[q * 4 + 3] = v.w;
        }
        #pragma unroll
        for (int p = 0; p < 16; ++p) {
            if (p0 + p < LX) {
                float s = 0.f;
                #pragma unroll
                for (int i = 0; i < K; ++i) s = fmaf(w[i], xw[p + OFF + i], s);
                m = fmaxf(m, s);
            }
        }
    }
    return m;
}

// channel-0 branches (K=3,5,7, all LX=64) share one window load.
__device__ __forceinline__ void conv3_ch0(const float* __restrict__ xin_al,
                                          const float* __restrict__ w3p,
                                          const float* __restrict__ w5p,
                                          const float* __restrict__ w7p,
                                          float& m3, float& m5, float& m7)
{
    float w3[3], w5[5], w7[7];
    #pragma unroll
    for (int i = 0; i < 3; ++i) w3[i] = w3p[i];
    #pragma unroll
    for (int i = 0; i < 5; ++i) w5[i] = w5p[i];
    #pragma unroll
    for (int i = 0; i < 7; ++i) w7[i] = w7p[i];
    m3 = m5 = m7 = -3.0e38f;
    #pragma unroll
    for (int p0 = 0; p0 < 64; p0 += 16) {
        float xw[24];
        #pragma unroll
        for (int q = 0; q < 6; ++q) {
            const float4 v = *(const float4*)(xin_al + p0 + q * 4);
            xw[q * 4 + 0] = v.x; xw[q * 4 + 1] = v.y;
            xw[q * 4 + 2] = v.z; xw[q * 4 + 3] = v.w;
        }
        #pragma unroll
        for (int p = 0; p < 16; ++p) {
            float s3 = 0.f, s5 = 0.f, s7 = 0.f;
            #pragma unroll
            for (int i = 0; i < 3; ++i) s3 = fmaf(w3[i], xw[p + 2 + i], s3);
            #pragma unroll
            for (int i = 0; i < 5; ++i) s5 = fmaf(w5[i], xw[p + 1 + i], s5);
            #pragma unroll
            for (int i = 0; i < 7; ++i) s7 = fmaf(w7[i], xw[p + 0 + i], s7);
            m3 = fmaxf(m3, s3);
            m5 = fmaxf(m5, s5);
            m7 = fmaxf(m7, s7);
        }
    }
}

// grid = 2*NROWS/8 ; block 256. Upper half of grid = encoder 1.
__global__ __launch_bounds__(256) void k_conv_feats(
    const float* __restrict__ x1, const float* __restrict__ x2,
    const float* __restrict__ w3,  const float* __restrict__ b3,
    const float* __restrict__ w5,  const float* __restrict__ b5,
    const float* __restrict__ w7,  const float* __restrict__ b7,
    const float* __restrict__ tw3, const float* __restrict__ tb3,
    const float* __restrict__ tw5, const float* __restrict__ tb5,
    const float* __restrict__ tw7, const float* __restrict__ tb7,
    float* __restrict__ feats)
{
    __shared__ float xs[8 * 4 * 72];
    const int t = threadIdx.x;             // 256
    const int eb = blockIdx.x >> 11;       // 0,1
    const float* __restrict__ x = eb ? x2 : x1;
    const int row0 = (blockIdx.x & 2047) * 8;
    for (int idx = t; idx < 8 * 4 * 72; idx += 256) {
        const int r   = idx / 288;
        const int rem = idx - r * 288;
        const int c   = rem / 72;
        const int j   = rem - c * 72;
        const int l   = j - 3;
        float v = 0.f;
        if (l >= 0 && l < 64 - 2 * c)
            v = x[(size_t)(row0 + r) * 256 + c * 64 + l];
        xs[idx] = v;
    }
    __syncthreads();

    const int r  = t >> 5;
    const int ch = t & 31;
    const int rowl = row0 + r;
    const int n   = rowl & (NNODES - 1);
    const int wc  = n * C + ch;
    const float* xb0 = &xs[r * 288 + 0 * 72];   // segment bases (16B aligned)
    const float* xb1 = &xs[r * 288 + 1 * 72];
    const float* xb2 = &xs[r * 288 + 2 * 72];
    const float* xb3 = &xs[r * 288 + 3 * 72];

    float m3, m5, m7;
    conv3_ch0(xb0, w3 + wc * 3, w5 + wc * 5, w7 + wc * 7, m3, m5, m7);

    float* o = feats + (size_t)(eb * NROWS + rowl) * 192 + ch;
    o[0 * 32] = fmaxf(m3 + b3[wc], 0.f);
    o[1 * 32] = fmaxf(m5 + b5[wc], 0.f);
    o[2 * 32] = fmaxf(m7 + b7[wc], 0.f);
    o[3 * 32] = fmaxf(convmax_w<3, 62>(xb1, tw3 + wc * 3) + tb3[wc], 0.f);
    o[4 * 32] = fmaxf(convmax_w<5, 60>(xb2, tw5 + wc * 5) + tb5[wc], 0.f);
    o[5 * 32] = fmaxf(convmax_w<7, 58>(xb3, tw7 + wc * 7) + tb7[wc], 0.f);
}

// ---------------- per-node FF 192->128 + relu (v3: float4 K-quads) ---------
__global__ __launch_bounds__(256) void k_ff(
    const float* __restrict__ feats, const float* __restrict__ ffw,
    const float* __restrict__ ffb, float* __restrict__ h0)
{
    const int nb = blockIdx.x >> 6;        // 0..31 (b-tile over 512)
    const int n  = blockIdx.x & 63;
    const int t  = threadIdx.x;
    const int o  = t & 127;
    const int rh = t >> 7;                 // 0..1
    __shared__ float fs[16 * 192];
    {
        float4* d4 = (float4*)fs;
        for (int i = t; i < 16 * 48; i += 256) {
            const int r = i / 48, c4 = i - r * 48;
            d4[i] = *(const float4*)(feats + ((size_t)(nb * 16 + r) * 64 + n) * 192 + c4 * 4);
        }
    }
    __syncthreads();
    const float* w = ffw + (size_t)n * 192 * 128 + o;
    float acc[8];
    #pragma unroll
    for (int r = 0; r < 8; ++r) acc[r] = 0.f;
    #pragma unroll 2
    for (int f = 0; f < 192; f += 4) {
        const float w0 = w[(f + 0) * 128];
        const float w1 = w[(f + 1) * 128];
        const float w2 = w[(f + 2) * 128];
        const float w3_ = w[(f + 3) * 128];
        #pragma unroll
        for (int r = 0; r < 8; ++r) {
            const float4 xv = *(const float4*)(fs + (rh * 8 + r) * 192 + f);
            acc[r] = fmaf(xv.x, w0, acc[r]);
            acc[r] = fmaf(xv.y, w1, acc[r]);
            acc[r] = fmaf(xv.z, w2, acc[r]);
            acc[r] = fmaf(xv.w, w3_, acc[r]);
        }
    }
    const float bias = ffb[n * 128 + o];
    #pragma unroll
    for (int r = 0; r < 8; ++r) {
        const int row = nb * 16 + rh * 8 + r;
        h0[((size_t)row * 64 + n) * 128 + o] = fmaxf(acc[r] + bias, 0.f);
    }
}

// ---------------- shared-weight 128x128 GEMM (v3: float4 K-quads) ----------
__global__ __launch_bounds__(256) void k_gemm128(
    const float* __restrict__ X, const float* __restrict__ W,
    float* __restrict__ Y)
{
    const int r0 = blockIdx.x * 16;
    const int t  = threadIdx.x;
    const int o  = t & 127;
    const int rh = t >> 7;
    __shared__ float xs[16 * 128];
    {
        float4* d4 = (float4*)xs;
        const float4* s4 = (const float4*)(X + (size_t)r0 * 128);
        for (int i = t; i < 512; i += 256) d4[i] = s4[i];
    }
    __syncthreads();
    const float* w = W + o;
    float acc[8];
    #pragma unroll
    for (int r = 0; r < 8; ++r) acc[r] = 0.f;
    #pragma unroll 2
    for (int f = 0; f < 128; f += 4) {
        const float w0 = w[(f + 0) * 128];
        const float w1 = w[(f + 1) * 128];
        const float w2 = w[(f + 2) * 128];
        const float w3_ = w[(f + 3) * 128];
        #pragma unroll
        for (int r = 0; r < 8; ++r) {
            const float4 xv = *(const float4*)(xs + (rh * 8 + r) * 128 + f);
            acc[r] = fmaf(xv.x, w0, acc[r]);
            acc[r] = fmaf(xv.y, w1, acc[r]);
            acc[r] = fmaf(xv.z, w2, acc[r]);
            acc[r] = fmaf(xv.w, w3_, acc[r]);
        }
    }
    #pragma unroll
    for (int r = 0; r < 8; ++r)
        Y[(size_t)(r0 + rh * 8 + r) * 128 + o] = acc[r];
}

// ---------------- CSR build (both encoders fused; combined arrays) ---------
__global__ void k_zero_i(int* __restrict__ p, int n) {
    const int i = blockIdx.x * blockDim.x + threadIdx.x;
    if (i < n) p[i] = 0;
}
__global__ void k_hist2(const int* __restrict__ eia, const int* __restrict__ eib,
                        int* __restrict__ cnt, int E, int n)
{
    const int gid = blockIdx.x * blockDim.x + threadIdx.x;
    const int eb = gid >= E;
    const int le = gid - (eb ? E : 0);
    if (le >= E) return;
    const int* ei = eb ? eib : eia;
    atomicAdd(&cnt[(eb ? n : 0) + ei[E + le]], 1);
}
// ---- two-level scan -------------------------------------------------------
__global__ __launch_bounds__(256) void k_scan_bsum(
    const int* __restrict__ cnt, int* __restrict__ bsum)
{
    const int t = threadIdx.x;
    const int4 v = ((const int4*)cnt)[blockIdx.x * 256 + t];
    int s = v.x + v.y + v.z + v.w;
    #pragma unroll
    for (int off = 32; off > 0; off >>= 1) s += __shfl_down(s, off);
    __shared__ int wsum[4];
    if ((t & 63) == 0) wsum[t >> 6] = s;
    __syncthreads();
    if (t == 0) bsum[blockIdx.x] = wsum[0] + wsum[1] + wsum[2] + wsum[3];
}
__global__ __launch_bounds__(256) void k_scan_final(
    const int* __restrict__ cnt, const int* __restrict__ bsum, int nb,
    int* __restrict__ offs, int* __restrict__ cur, float* __restrict__ dinv, int n)
{
    const int blk = blockIdx.x, t = threadIdx.x;
    int base = 0;
    for (int i = 0; i < blk; ++i) base += bsum[i];
    const int4 v = ((const int4*)cnt)[blk * 256 + t];
    const int s = v.x + v.y + v.z + v.w;
    int sc = s;
    #pragma unroll
    for (int off = 1; off < 64; off <<= 1) {
        const int u = __shfl_up(sc, off);
        if ((t & 63) >= off) sc += u;
    }
    __shared__ int wsum[4];
    if ((t & 63) == 63) wsum[t >> 6] = sc;
    __syncthreads();
    int wbase = 0;
    for (int wv = 0; wv < (t >> 6); ++wv) wbase += wsum[wv];
    int o0 = base + wbase + sc - s;
    const int gi = blk * 1024 + t * 4;
    offs[gi + 0] = o0; cur[gi + 0] = o0; dinv[gi + 0] = rsqrtf(1.f + (float)v.x); o0 += v.x;
    offs[gi + 1] = o0; cur[gi + 1] = o0; dinv[gi + 1] = rsqrtf(1.f + (float)v.y); o0 += v.y;
    offs[gi + 2] = o0; cur[gi + 2] = o0; dinv[gi + 2] = rsqrtf(1.f + (float)v.z); o0 += v.z;
    offs[gi + 3] = o0; cur[gi + 3] = o0; dinv[gi + 3] = rsqrtf(1.f + (float)v.w); o0 += v.w;
    if (blk == nb - 1 && t == 255) offs[n] = o0;
}
__global__ void k_fill2(const int* __restrict__ eia, const int* __restrict__ eib,
                        int* __restrict__ cur, int* __restrict__ esrc, int E, int n)
{
    const int gid = blockIdx.x * blockDim.x + threadIdx.x;
    const int eb = gid >= E;
    const int le = gid - (eb ? E : 0);
    if (le >= E) return;
    const int* ei = eb ? eib : eia;
    const int s = ei[le];
    const int d = ei[E + le];
    const int pos = atomicAdd(&cur[(eb ? n : 0) + d], 1);
    esrc[pos] = s;
}

// ---------------- GCN gather (combined 2n rows, local CSR src ids) ---------
__global__ __launch_bounds__(128) void k_gcn_gather(
    const int* __restrict__ offs, const int* __restrict__ esrc,
    const float* __restrict__ hw, const float* __restrict__ dinv,
    const float* __restrict__ bias, float* __restrict__ out, int n)
{
    const int d = blockIdx.x;
    const int t = threadIdx.x;             // 128
    const int sbase = (d >= n) ? n : 0;
    const int e0 = offs[d], e1 = offs[d + 1];
    const float dd = dinv[d];
    float a0 = hw[(size_t)d * 128 + t] * dd;
    float a1 = 0.f, a2 = 0.f, a3 = 0.f;
    int j = e0;
    for (; j + 3 < e1; j += 4) {
        const int s0 = sbase + esrc[j],     s1 = sbase + esrc[j + 1];
        const int s2 = sbase + esrc[j + 2], s3 = sbase + esrc[j + 3];
        a0 = fmaf(hw[(size_t)s0 * 128 + t], dinv[s0], a0);
        a1 = fmaf(hw[(size_t)s1 * 128 + t], dinv[s1], a1);
        a2 = fmaf(hw[(size_t)s2 * 128 + t], dinv[s2], a2);
        a3 = fmaf(hw[(size_t)s3 * 128 + t], dinv[s3], a3);
    }
    for (; j < e1; ++j) {
        const int s = sbase + esrc[j];
        a0 = fmaf(hw[(size_t)s * 128 + t], dinv[s], a0);
    }
    const float acc = (a0 + a1) + (a2 + a3);
    out[(size_t)d * 128 + t] = fmaf(acc, dd, bias[t]);
}

// ---------------- per-group aggregate 512->128 (4 rows, K-split 2) ----------
__global__ __launch_bounds__(256) void k_agg(
    const float* __restrict__ h, const float* __restrict__ aggw,
    const float* __restrict__ aggb, float* __restrict__ hg)
{
    const int bt = blockIdx.x >> 4;        // 0..127
    const int g  = blockIdx.x & 15;
    const int t  = threadIdx.x;
    const int o  = t & 127;
    const int kk = t >> 7;
    __shared__ float fs[4 * 512];
    __shared__ float red[2][4][128];
    {
        const int b0 = bt * 4;
        float4* dst = (float4*)fs;
        for (int i = t; i < 4 * 128; i += 256) {
            const int r = i >> 7;
            const int q = i & 127;
            dst[i] = *(const float4*)(h + ((size_t)(b0 + r) * 64 + g * 4) * 128 + q * 4);
        }
    }
    __syncthreads();
    const float* w = aggw + (size_t)g * 512 * 128 + (size_t)kk * 256 * 128 + o;
    float a0 = 0.f, a1 = 0.f, a2 = 0.f, a3 = 0.f;
    const float* x0 = fs + 0 * 512 + kk * 256;
    const float* x1 = fs + 1 * 512 + kk * 256;
    const float* x2 = fs + 2 * 512 + kk * 256;
    const float* x3 = fs + 3 * 512 + kk * 256;
    #pragma unroll 8
    for (int f = 0; f < 256; ++f) {
        const float wv = w[f * 128];
        a0 = fmaf(x0[f], wv, a0);
        a1 = fmaf(x1[f], wv, a1);
        a2 = fmaf(x2[f], wv, a2);
        a3 = fmaf(x3[f], wv, a3);
    }
    red[kk][0][o] = a0; red[kk][1][o] = a1; red[kk][2][o] = a2; red[kk][3][o] = a3;
    __syncthreads();
    if (t < 128) {
        const float bias = aggb[g * 128 + t];
        #pragma unroll
        for (int r = 0; r < 4; ++r) {
            const int b = bt * 4 + r;
            hg[((size_t)b * 16 + g) * 128 + t] = red[0][r][t] + red[1][r][t] + bias;
        }
    }
}

// ---------------- disc (4 rows, K-split 2): relu in, 256->128 + relu --------
__global__ __launch_bounds__(256) void k_disc(
    const float* __restrict__ h1, const float* __restrict__ h2,
    const float* __restrict__ dw, const float* __restrict__ db,
    float* __restrict__ dd)
{
    const int bt = blockIdx.x >> 4;        // 0..63
    const int g  = blockIdx.x & 15;
    const int t  = threadIdx.x;
    const int o  = t & 127;
    const int kk = t >> 7;
    __shared__ float fs[4 * 256];
    __shared__ float red[2][4][128];
    {
        const int half = t >> 7;
        #pragma unroll
        for (int r = 0; r < 4; ++r) {
            const int rowi = ((bt * 4 + r) * 16 + g);
            const float* src = half ? h2 : h1;
            fs[r * 256 + half * 128 + o] = fmaxf(src[(size_t)rowi * 128 + o], 0.f);
        }
    }
    __syncthreads();
    const float* w = dw + (size_t)g * 256 * 128 + (size_t)kk * 128 * 128 + o;
    float a0 = 0.f, a1 = 0.f, a2 = 0.f, a3 = 0.f;
    const float* x0 = fs + 0 * 256 + kk * 128;
    const float* x1 = fs + 1 * 256 + kk * 128;
    const float* x2 = fs + 2 * 256 + kk * 128;
    const float* x3 = fs + 3 * 256 + kk * 128;
    #pragma unroll 8
    for (int f = 0; f < 128; ++f) {
        const float wv = w[f * 128];
        a0 = fmaf(x0[f], wv, a0);
        a1 = fmaf(x1[f], wv, a1);
        a2 = fmaf(x2[f], wv, a2);
        a3 = fmaf(x3[f], wv, a3);
    }
    red[kk][0][o] = a0; red[kk][1][o] = a1; red[kk][2][o] = a2; red[kk][3][o] = a3;
    __syncthreads();
    if (t < 128) {
        const float bias = db[g * 128 + t];
        #pragma unroll
        for (int r = 0; r < 4; ++r) {
            const int b = bt * 4 + r;
            dd[(size_t)b * 2048 + g * 128 + t] =
                fmaxf(red[0][r][t] + red[1][r][t] + bias, 0.f);
        }
    }
}

// ---------------- final fc 2048->64: one block per batch row ----------------
__global__ __launch_bounds__(256) void k_fc(
    const float* __restrict__ dd, const float* __restrict__ fcw,
    const float* __restrict__ fcb, float* __restrict__ out)
{
    const int b = blockIdx.x;
    const int t = threadIdx.x;
    const int o = t & 63;
    const int k = t >> 6;                  // 0..3
    __shared__ float ds[2048];
    __shared__ float red[4][64];
    for (int i = t; i < 2048; i += 256) ds[i] = dd[(size_t)b * 2048 + i];
    __syncthreads();
    const float* w  = fcw + (k * 512) * 64 + o;
    const float* xr = ds + k * 512;
    float a0 = 0.f, a1 = 0.f, a2 = 0.f, a3 = 0.f;
    #pragma unroll 4
    for (int f = 0; f < 512; f += 4) {
        a0 = fmaf(xr[f + 0], w[(f + 0) * 64], a0);
        a1 = fmaf(xr[f + 1], w[(f + 1) * 64], a1);
        a2 = fmaf(xr[f + 2], w[(f + 2) * 64], a2);
        a3 = fmaf(xr[f + 3], w[(f + 3) * 64], a3);
    }
    red[k][o] = (a0 + a1) + (a2 + a3);
    __syncthreads();
    if (t < 64)
        out[(size_t)b * 64 + t] = ((red[0][t] + red[1][t]) + (red[2][t] + red[3][t])) + fcb[t];
}

} // namespace

extern "C" void kernel_launch(void* const* d_in, const int* in_sizes, int n_in,
                              void* d_out, int out_size, void* d_ws, size_t ws_size,
                              hipStream_t stream)
{
    const float* x1 = (const float*)d_in[0];
    const float* x2 = (const float*)d_in[1];
    const int* ei0  = (const int*)d_in[2];
    const int* ei1  = (const int*)d_in[3];
    const int* gei0 = (const int*)d_in[4];
    const int* gei1 = (const int*)d_in[5];
    const float* conv_w3 = (const float*)d_in[6];
    const float* conv_b3 = (const float*)d_in[7];
    const float* conv_w5 = (const float*)d_in[8];
    const float* conv_b5 = (const float*)d_in[9];
    const float* conv_w7 = (const float*)d_in[10];
    const float* conv_b7 = (const float*)d_in[11];
    const float* tconv_w3 = (const float*)d_in[12];
    const float* tconv_b3 = (const float*)d_in[13];
    const float* tconv_w5 = (const float*)d_in[14];
    const float* tconv_b5 = (const float*)d_in[15];
    const float* tconv_w7 = (const float*)d_in[16];
    const float* tconv_b7 = (const float*)d_in[17];
    const float* ff_w    = (const float*)d_in[18];
    const float* ff_b    = (const float*)d_in[19];
    const float* lower_w = (const float*)d_in[20];
    const float* lower_b = (const float*)d_in[21];
    const float* upper_w = (const float*)d_in[22];
    const float* upper_b = (const float*)d_in[23];
    const float* agg_w   = (const float*)d_in[24];
    const float* agg_b   = (const float*)d_in[25];
    const float* disc_w  = (const float*)d_in[26];
    const float* disc_b  = (const float*)d_in[27];
    const float* fc_w    = (const float*)d_in[28];
    const float* fc_b    = (const float*)d_in[29];

    float* ws = (float*)d_ws;
    float* f_feats = ws;                          // 6291456
    float* f_h0    = ws + 6291456;                // 4194304
    float* f_hw    = ws + 10485760;               // 4194304
    float* f_gout  = ws + 14680064;               // 4194304
    float* f_hg    = ws + 18874368;               // 1048576
    float* f_hgw   = ws + 19922944;               // 1048576
    float* f_henc  = ws + 20971520;               // 1048576
    float* f_dd    = ws + 22020096;               // 524288
    float* f_dinv1 = ws + 22544384;               // 32768
    float* f_dinv2 = ws + 22577152;               // 8192
    int* ip    = (int*)(ws + 22585344);
    int* cnt1  = ip;                              // 32768
    int* cnt2  = cnt1 + 2 * NROWS;                // 8192
    int* offs1 = cnt2 + 2 * GROWS;                // 32769
    int* cur1  = offs1 + 2 * NROWS + 1;           // 32768
    int* esrc1 = cur1 + 2 * NROWS;                // 524288
    int* offs2 = esrc1 + 2 * E1;                  // 8193
    int* cur2  = offs2 + 2 * GROWS + 1;           // 8192
    int* esrc2 = cur2 + 2 * GROWS;                // 65536
    int* bsum1 = esrc2 + 2 * E2;                  // 32
    int* bsum2 = bsum1 + 32;                      // 8

    // CSR for node graphs
    k_zero_i<<<(2 * NROWS) / 256, 256, 0, stream>>>(cnt1, 2 * NROWS);
    k_hist2<<<(2 * E1) / 256, 256, 0, stream>>>(ei0, ei1, cnt1, E1, NROWS);
    k_scan_bsum<<<32, 256, 0, stream>>>(cnt1, bsum1);
    k_scan_final<<<32, 256, 0, stream>>>(cnt1, bsum1, 32, offs1, cur1, f_dinv1, 2 * NROWS);
    k_fill2<<<(2 * E1) / 256, 256, 0, stream>>>(ei0, ei1, cur1, esrc1, E1, NROWS);
    // CSR for group graphs
    k_zero_i<<<(2 * GROWS) / 256, 256, 0, stream>>>(cnt2, 2 * GROWS);
    k_hist2<<<(2 * E2) / 256, 256, 0, stream>>>(gei0, gei1, cnt2, E2, GROWS);
    k_scan_bsum<<<8, 256, 0, stream>>>(cnt2, bsum2);
    k_scan_final<<<8, 256, 0, stream>>>(cnt2, bsum2, 8, offs2, cur2, f_dinv2, 2 * GROWS);
    k_fill2<<<(2 * E2) / 256, 256, 0, stream>>>(gei0, gei1, cur2, esrc2, E2, GROWS);

    // encoder pipeline (both encoders per dispatch)
    k_conv_feats<<<2 * NROWS / 8, 256, 0, stream>>>(x1, x2,
        conv_w3, conv_b3, conv_w5, conv_b5, conv_w7, conv_b7,
        tconv_w3, tconv_b3, tconv_w5, tconv_b5, tconv_w7, tconv_b7, f_feats);
    k_ff<<<2048, 256, 0, stream>>>(f_feats, ff_w, ff_b, f_h0);
    k_gemm128<<<2 * NROWS / 16, 256, 0, stream>>>(f_h0, lower_w, f_hw);
    k_gcn_gather<<<2 * NROWS, 128, 0, stream>>>(offs1, esrc1, f_hw, f_dinv1,
                                                lower_b, f_gout, NROWS);
    k_agg<<<2 * (Bn / 4) * 16, 256, 0, stream>>>(f_gout, agg_w, agg_b, f_hg);
    k_gemm128<<<2 * GROWS / 16, 256, 0, stream>>>(f_hg, upper_w, f_hgw);
    k_gcn_gather<<<2 * GROWS, 128, 0, stream>>>(offs2, esrc2, f_hgw, f_dinv2,
                                                upper_b, f_henc, GROWS);

    k_disc<<<(Bn / 4) * 16, 256, 0, stream>>>(f_henc, f_henc + (size_t)GROWS * 128,
                                              disc_w, disc_b, f_dd);
    k_fc<<<Bn, 256, 0, stream>>>(f_dd, fc_w, fc_b, (float*)d_out);
}

// Round 9
// 283.172 us; speedup vs baseline: 10.0846x; 1.0334x over previous
//
#include <hip/hip_runtime.h>
#include <hip/hip_bf16.h>

namespace {

constexpr int Bn      = 256;
constexpr int NNODES  = 64;
constexpr int NGROUPS = 16;
constexpr int L       = 64;
constexpr int C       = 32;
constexpr int GH      = 128;
constexpr int E1      = 262144;
constexpr int E2      = 32768;
constexpr int NROWS   = Bn * NNODES;   // 16384
constexpr int GROWS   = Bn * NGROUPS;  // 4096

// ---------------- conv + max + relu -> feats [2*NROWS,192] ----------------
// 2 channels per thread share one register window; position-pairs feed v_max3.
template<int K, int LX>
__device__ __forceinline__ void convmax2(const float* __restrict__ xin_al,
                                         const float* __restrict__ wpa,
                                         const float* __restrict__ wpb,
                                         float& ma, float& mb)
{
    constexpr int PAD = (K - 1) / 2;
    constexpr int OFF = 3 - PAD;
    float wa[K], wb[K];
    #pragma unroll
    for (int i = 0; i < K; ++i) { wa[i] = wpa[i]; wb[i] = wpb[i]; }
    ma = -3.0e38f; mb = -3.0e38f;
    #pragma unroll
    for (int p0 = 0; p0 < LX; p0 += 16) {
        float xw[24];
        #pragma unroll
        for (int q = 0; q < 6; ++q) {
            const float4 v = *(const float4*)(xin_al + p0 + q * 4);
            xw[q * 4 + 0] = v.x; xw[q * 4 + 1] = v.y;
            xw[q * 4 + 2] = v.z; xw[q * 4 + 3] = v.w;
        }
        #pragma unroll
        for (int p = 0; p < 16; p += 2) {
            if (p0 + p + 1 < LX) {      // LX even -> pairs all-valid or all-invalid
                float sa0 = 0.f, sb0 = 0.f, sa1 = 0.f, sb1 = 0.f;
                #pragma unroll
                for (int i = 0; i < K; ++i) {
                    const float xv0 = xw[p + OFF + i];
                    const float xv1 = xw[p + 1 + OFF + i];
                    sa0 = fmaf(wa[i], xv0, sa0);
                    sb0 = fmaf(wb[i], xv0, sb0);
                    sa1 = fmaf(wa[i], xv1, sa1);
                    sb1 = fmaf(wb[i], xv1, sb1);
                }
                ma = fmaxf(fmaxf(sa0, sa1), ma);   // v_max3
                mb = fmaxf(fmaxf(sb0, sb1), mb);
            }
        }
    }
}

// grid = 2*NROWS/16 ; block 256 = 16 rows x 16 channel-pairs.
__global__ __launch_bounds__(256) void k_conv_feats(
    const float* __restrict__ x1, const float* __restrict__ x2,
    const float* __restrict__ w3,  const float* __restrict__ b3,
    const float* __restrict__ w5,  const float* __restrict__ b5,
    const float* __restrict__ w7,  const float* __restrict__ b7,
    const float* __restrict__ tw3, const float* __restrict__ tb3,
    const float* __restrict__ tw5, const float* __restrict__ tb5,
    const float* __restrict__ tw7, const float* __restrict__ tb7,
    float* __restrict__ feats)
{
    __shared__ float xs[16 * 4 * 72];
    const int t = threadIdx.x;             // 256
    const int eb = blockIdx.x >> 10;       // 0,1
    const float* __restrict__ x = eb ? x2 : x1;
    const int row0 = (blockIdx.x & 1023) * 16;
    for (int idx = t; idx < 16 * 4 * 72; idx += 256) {
        const int r   = idx / 288;
        const int rem = idx - r * 288;
        const int c   = rem / 72;
        const int j   = rem - c * 72;
        const int l   = j - 3;
        float v = 0.f;
        if (l >= 0 && l < 64 - 2 * c)
            v = x[(size_t)(row0 + r) * 256 + c * 64 + l];
        xs[idx] = v;
    }
    __syncthreads();

    const int rr  = t >> 4;                // 0..15
    const int cp  = t & 15;                // 0..15
    const int ch0 = cp * 2;
    const int row = row0 + rr;
    const int n   = row & (NNODES - 1);
    const int wc0 = n * C + ch0;
    const int wc1 = wc0 + 1;
    const float* xb0 = &xs[rr * 288 + 0 * 72];
    const float* xb1 = &xs[rr * 288 + 1 * 72];
    const float* xb2 = &xs[rr * 288 + 2 * 72];
    const float* xb3 = &xs[rr * 288 + 3 * 72];

    float ma, mb;
    float* o = feats + (size_t)(eb * NROWS + row) * 192 + ch0;

    convmax2<3, 64>(xb0, w3 + wc0 * 3, w3 + wc1 * 3, ma, mb);
    *(float2*)(o + 0 * 32) = make_float2(fmaxf(ma + b3[wc0], 0.f), fmaxf(mb + b3[wc1], 0.f));
    convmax2<5, 64>(xb0, w5 + wc0 * 5, w5 + wc1 * 5, ma, mb);
    *(float2*)(o + 1 * 32) = make_float2(fmaxf(ma + b5[wc0], 0.f), fmaxf(mb + b5[wc1], 0.f));
    convmax2<7, 64>(xb0, w7 + wc0 * 7, w7 + wc1 * 7, ma, mb);
    *(float2*)(o + 2 * 32) = make_float2(fmaxf(ma + b7[wc0], 0.f), fmaxf(mb + b7[wc1], 0.f));
    convmax2<3, 62>(xb1, tw3 + wc0 * 3, tw3 + wc1 * 3, ma, mb);
    *(float2*)(o + 3 * 32) = make_float2(fmaxf(ma + tb3[wc0], 0.f), fmaxf(mb + tb3[wc1], 0.f));
    convmax2<5, 60>(xb2, tw5 + wc0 * 5, tw5 + wc1 * 5, ma, mb);
    *(float2*)(o + 4 * 32) = make_float2(fmaxf(ma + tb5[wc0], 0.f), fmaxf(mb + tb5[wc1], 0.f));
    convmax2<7, 58>(xb3, tw7 + wc0 * 7, tw7 + wc1 * 7, ma, mb);
    *(float2*)(o + 5 * 32) = make_float2(fmaxf(ma + tb7[wc0], 0.f), fmaxf(mb + tb7[wc1], 0.f));
}

// ---------------- fused FF(192->128,relu) + lower(128x128) -----------------
// grid = 2048 (nb 0..31, n 0..63); block 256. h0 tile lives in LDS only.
__global__ __launch_bounds__(256) void k_ff_lower(
    const float* __restrict__ feats, const float* __restrict__ ffw,
    const float* __restrict__ ffb, const float* __restrict__ lw,
    float* __restrict__ hw)
{
    const int nb = blockIdx.x >> 6;        // 0..31
    const int n  = blockIdx.x & 63;
    const int t  = threadIdx.x;
    const int o  = t & 127;
    const int rh = t >> 7;                 // 0..1
    __shared__ float fs[16 * 192];
    __shared__ float h0s[16 * 128];
    {
        float4* d4 = (float4*)fs;
        for (int i = t; i < 16 * 48; i += 256) {
            const int r = i / 48, c4 = i - r * 48;
            d4[i] = *(const float4*)(feats + ((size_t)(nb * 16 + r) * 64 + n) * 192 + c4 * 4);
        }
    }
    __syncthreads();
    // phase 1: h0 = relu(feats @ ffw + b)
    {
        const float* w = ffw + (size_t)n * 192 * 128 + o;
        float acc[8];
        #pragma unroll
        for (int r = 0; r < 8; ++r) acc[r] = 0.f;
        #pragma unroll 2
        for (int f = 0; f < 192; f += 4) {
            const float w0 = w[(f + 0) * 128];
            const float w1 = w[(f + 1) * 128];
            const float w2 = w[(f + 2) * 128];
            const float w3_ = w[(f + 3) * 128];
            #pragma unroll
            for (int r = 0; r < 8; ++r) {
                const float4 xv = *(const float4*)(fs + (rh * 8 + r) * 192 + f);
                acc[r] = fmaf(xv.x, w0, acc[r]);
                acc[r] = fmaf(xv.y, w1, acc[r]);
                acc[r] = fmaf(xv.z, w2, acc[r]);
                acc[r] = fmaf(xv.w, w3_, acc[r]);
            }
        }
        const float bias = ffb[n * 128 + o];
        #pragma unroll
        for (int r = 0; r < 8; ++r)
            h0s[(rh * 8 + r) * 128 + o] = fmaxf(acc[r] + bias, 0.f);
    }
    __syncthreads();
    // phase 2: hw = h0 @ lower_w
    {
        const float* w = lw + o;
        float acc[8];
        #pragma unroll
        for (int r = 0; r < 8; ++r) acc[r] = 0.f;
        #pragma unroll 2
        for (int f = 0; f < 128; f += 4) {
            const float w0 = w[(f + 0) * 128];
            const float w1 = w[(f + 1) * 128];
            const float w2 = w[(f + 2) * 128];
            const float w3_ = w[(f + 3) * 128];
            #pragma unroll
            for (int r = 0; r < 8; ++r) {
                const float4 xv = *(const float4*)(h0s + (rh * 8 + r) * 128 + f);
                acc[r] = fmaf(xv.x, w0, acc[r]);
                acc[r] = fmaf(xv.y, w1, acc[r]);
                acc[r] = fmaf(xv.z, w2, acc[r]);
                acc[r] = fmaf(xv.w, w3_, acc[r]);
            }
        }
        #pragma unroll
        for (int r = 0; r < 8; ++r) {
            const int row = nb * 16 + rh * 8 + r;
            hw[((size_t)row * 64 + n) * 128 + o] = acc[r];
        }
    }
}

// ---------------- shared-weight 128x128 GEMM (v3) ---------------------------
__global__ __launch_bounds__(256) void k_gemm128(
    const float* __restrict__ X, const float* __restrict__ W,
    float* __restrict__ Y)
{
    const int r0 = blockIdx.x * 16;
    const int t  = threadIdx.x;
    const int o  = t & 127;
    const int rh = t >> 7;
    __shared__ float xs[16 * 128];
    {
        float4* d4 = (float4*)xs;
        const float4* s4 = (const float4*)(X + (size_t)r0 * 128);
        for (int i = t; i < 512; i += 256) d4[i] = s4[i];
    }
    __syncthreads();
    const float* w = W + o;
    float acc[8];
    #pragma unroll
    for (int r = 0; r < 8; ++r) acc[r] = 0.f;
    #pragma unroll 2
    for (int f = 0; f < 128; f += 4) {
        const float w0 = w[(f + 0) * 128];
        const float w1 = w[(f + 1) * 128];
        const float w2 = w[(f + 2) * 128];
        const float w3_ = w[(f + 3) * 128];
        #pragma unroll
        for (int r = 0; r < 8; ++r) {
            const float4 xv = *(const float4*)(xs + (rh * 8 + r) * 128 + f);
            acc[r] = fmaf(xv.x, w0, acc[r]);
            acc[r] = fmaf(xv.y, w1, acc[r]);
            acc[r] = fmaf(xv.z, w2, acc[r]);
            acc[r] = fmaf(xv.w, w3_, acc[r]);
        }
    }
    #pragma unroll
    for (int r = 0; r < 8; ++r)
        Y[(size_t)(r0 + rh * 8 + r) * 128 + o] = acc[r];
}

// ---------------- CSR build: both graphs (node+group), both encoders -------
__global__ void k_zero_i(int* __restrict__ p, int n) {
    const int i = blockIdx.x * blockDim.x + threadIdx.x;
    if (i < n) p[i] = 0;
}
__global__ void k_hist_all(const int* __restrict__ ei0, const int* __restrict__ ei1,
                           const int* __restrict__ gei0, const int* __restrict__ gei1,
                           int* __restrict__ cnt1, int* __restrict__ cnt2)
{
    const int gid = blockIdx.x * blockDim.x + threadIdx.x;
    if (gid < 2 * E1) {
        const int eb = gid >= E1;
        const int le = gid - (eb ? E1 : 0);
        const int* ei = eb ? ei1 : ei0;
        atomicAdd(&cnt1[(eb ? NROWS : 0) + ei[E1 + le]], 1);
    } else {
        const int g2 = gid - 2 * E1;
        const int eb = g2 >= E2;
        const int le = g2 - (eb ? E2 : 0);
        const int* ei = eb ? gei1 : gei0;
        atomicAdd(&cnt2[(eb ? GROWS : 0) + ei[E2 + le]], 1);
    }
}
__global__ __launch_bounds__(256) void k_scan_bsum_all(
    const int* __restrict__ cnt1, const int* __restrict__ cnt2,
    int* __restrict__ bsum1, int* __restrict__ bsum2)
{
    const int blk = blockIdx.x, t = threadIdx.x;
    const int* cnt; int* bsum; int lblk;
    if (blk < 32) { cnt = cnt1; bsum = bsum1; lblk = blk; }
    else          { cnt = cnt2; bsum = bsum2; lblk = blk - 32; }
    const int4 v = ((const int4*)cnt)[lblk * 256 + t];
    int s = v.x + v.y + v.z + v.w;
    #pragma unroll
    for (int off = 32; off > 0; off >>= 1) s += __shfl_down(s, off);
    __shared__ int wsum[4];
    if ((t & 63) == 0) wsum[t >> 6] = s;
    __syncthreads();
    if (t == 0) bsum[lblk] = wsum[0] + wsum[1] + wsum[2] + wsum[3];
}
__global__ __launch_bounds__(256) void k_scan_final_all(
    const int* __restrict__ cnt1, const int* __restrict__ bsum1,
    int* __restrict__ offs1, int* __restrict__ cur1, float* __restrict__ dinv1,
    const int* __restrict__ cnt2, const int* __restrict__ bsum2,
    int* __restrict__ offs2, int* __restrict__ cur2, float* __restrict__ dinv2)
{
    const int blk = blockIdx.x, t = threadIdx.x;
    const int* cnt; const int* bsum; int* offs; int* cur; float* dinv;
    int n, nb, lblk;
    if (blk < 32) { cnt = cnt1; bsum = bsum1; offs = offs1; cur = cur1; dinv = dinv1;
                    n = 2 * NROWS; nb = 32; lblk = blk; }
    else          { cnt = cnt2; bsum = bsum2; offs = offs2; cur = cur2; dinv = dinv2;
                    n = 2 * GROWS; nb = 8; lblk = blk - 32; }
    int base = 0;
    for (int i = 0; i < lblk; ++i) base += bsum[i];
    const int4 v = ((const int4*)cnt)[lblk * 256 + t];
    const int s = v.x + v.y + v.z + v.w;
    int sc = s;
    #pragma unroll
    for (int off = 1; off < 64; off <<= 1) {
        const int u = __shfl_up(sc, off);
        if ((t & 63) >= off) sc += u;
    }
    __shared__ int wsum[4];
    if ((t & 63) == 63) wsum[t >> 6] = sc;
    __syncthreads();
    int wbase = 0;
    for (int wv = 0; wv < (t >> 6); ++wv) wbase += wsum[wv];
    int o0 = base + wbase + sc - s;
    const int gi = lblk * 1024 + t * 4;
    offs[gi + 0] = o0; cur[gi + 0] = o0; dinv[gi + 0] = rsqrtf(1.f + (float)v.x); o0 += v.x;
    offs[gi + 1] = o0; cur[gi + 1] = o0; dinv[gi + 1] = rsqrtf(1.f + (float)v.y); o0 += v.y;
    offs[gi + 2] = o0; cur[gi + 2] = o0; dinv[gi + 2] = rsqrtf(1.f + (float)v.z); o0 += v.z;
    offs[gi + 3] = o0; cur[gi + 3] = o0; dinv[gi + 3] = rsqrtf(1.f + (float)v.w); o0 += v.w;
    if (lblk == nb - 1 && t == 255) offs[n] = o0;
}
__global__ void k_fill_all(const int* __restrict__ ei0, const int* __restrict__ ei1,
                           const int* __restrict__ gei0, const int* __restrict__ gei1,
                           int* __restrict__ cur1, int* __restrict__ esrc1,
                           int* __restrict__ cur2, int* __restrict__ esrc2)
{
    const int gid = blockIdx.x * blockDim.x + threadIdx.x;
    if (gid < 2 * E1) {
        const int eb = gid >= E1;
        const int le = gid - (eb ? E1 : 0);
        const int* ei = eb ? ei1 : ei0;
        const int s = ei[le];
        const int d = ei[E1 + le];
        const int pos = atomicAdd(&cur1[(eb ? NROWS : 0) + d], 1);
        esrc1[pos] = s;
    } else {
        const int g2 = gid - 2 * E1;
        const int eb = g2 >= E2;
        const int le = g2 - (eb ? E2 : 0);
        const int* ei = eb ? gei1 : gei0;
        const int s = ei[le];
        const int d = ei[E2 + le];
        const int pos = atomicAdd(&cur2[(eb ? GROWS : 0) + d], 1);
        esrc2[pos] = s;
    }
}

// ---------------- GCN gather (combined 2n rows, local CSR src ids) ---------
__global__ __launch_bounds__(128) void k_gcn_gather(
    const int* __restrict__ offs, const int* __restrict__ esrc,
    const float* __restrict__ hw, const float* __restrict__ dinv,
    const float* __restrict__ bias, float* __restrict__ out, int n)
{
    const int d = blockIdx.x;
    const int t = threadIdx.x;             // 128
    const int sbase = (d >= n) ? n : 0;
    const int e0 = offs[d], e1 = offs[d + 1];
    const float dd = dinv[d];
    float a0 = hw[(size_t)d * 128 + t] * dd;
    float a1 = 0.f, a2 = 0.f, a3 = 0.f;
    int j = e0;
    for (; j + 3 < e1; j += 4) {
        const int s0 = sbase + esrc[j],     s1 = sbase + esrc[j + 1];
        const int s2 = sbase + esrc[j + 2], s3 = sbase + esrc[j + 3];
        a0 = fmaf(hw[(size_t)s0 * 128 + t], dinv[s0], a0);
        a1 = fmaf(hw[(size_t)s1 * 128 + t], dinv[s1], a1);
        a2 = fmaf(hw[(size_t)s2 * 128 + t], dinv[s2], a2);
        a3 = fmaf(hw[(size_t)s3 * 128 + t], dinv[s3], a3);
    }
    for (; j < e1; ++j) {
        const int s = sbase + esrc[j];
        a0 = fmaf(hw[(size_t)s * 128 + t], dinv[s], a0);
    }
    const float acc = (a0 + a1) + (a2 + a3);
    out[(size_t)d * 128 + t] = fmaf(acc, dd, bias[t]);
}

// ---------------- per-group aggregate 512->128 (4 rows, K-split 2) ----------
__global__ __launch_bounds__(256) void k_agg(
    const float* __restrict__ h, const float* __restrict__ aggw,
    const float* __restrict__ aggb, float* __restrict__ hg)
{
    const int bt = blockIdx.x >> 4;        // 0..127
    const int g  = blockIdx.x & 15;
    const int t  = threadIdx.x;
    const int o  = t & 127;
    const int kk = t >> 7;
    __shared__ float fs[4 * 512];
    __shared__ float red[2][4][128];
    {
        const int b0 = bt * 4;
        float4* dst = (float4*)fs;
        for (int i = t; i < 4 * 128; i += 256) {
            const int r = i >> 7;
            const int q = i & 127;
            dst[i] = *(const float4*)(h + ((size_t)(b0 + r) * 64 + g * 4) * 128 + q * 4);
        }
    }
    __syncthreads();
    const float* w = aggw + (size_t)g * 512 * 128 + (size_t)kk * 256 * 128 + o;
    float a0 = 0.f, a1 = 0.f, a2 = 0.f, a3 = 0.f;
    const float* x0 = fs + 0 * 512 + kk * 256;
    const float* x1 = fs + 1 * 512 + kk * 256;
    const float* x2 = fs + 2 * 512 + kk * 256;
    const float* x3 = fs + 3 * 512 + kk * 256;
    #pragma unroll 8
    for (int f = 0; f < 256; ++f) {
        const float wv = w[f * 128];
        a0 = fmaf(x0[f], wv, a0);
        a1 = fmaf(x1[f], wv, a1);
        a2 = fmaf(x2[f], wv, a2);
        a3 = fmaf(x3[f], wv, a3);
    }
    red[kk][0][o] = a0; red[kk][1][o] = a1; red[kk][2][o] = a2; red[kk][3][o] = a3;
    __syncthreads();
    if (t < 128) {
        const float bias = aggb[g * 128 + t];
        #pragma unroll
        for (int r = 0; r < 4; ++r) {
            const int b = bt * 4 + r;
            hg[((size_t)b * 16 + g) * 128 + t] = red[0][r][t] + red[1][r][t] + bias;
        }
    }
}

// ---------------- disc (4 rows, K-split 2): relu in, 256->128 + relu --------
__global__ __launch_bounds__(256) void k_disc(
    const float* __restrict__ h1, const float* __restrict__ h2,
    const float* __restrict__ dw, const float* __restrict__ db,
    float* __restrict__ dd)
{
    const int bt = blockIdx.x >> 4;        // 0..63
    const int g  = blockIdx.x & 15;
    const int t  = threadIdx.x;
    const int o  = t & 127;
    const int kk = t >> 7;
    __shared__ float fs[4 * 256];
    __shared__ float red[2][4][128];
    {
        const int half = t >> 7;
        #pragma unroll
        for (int r = 0; r < 4; ++r) {
            const int rowi = ((bt * 4 + r) * 16 + g);
            const float* src = half ? h2 : h1;
            fs[r * 256 + half * 128 + o] = fmaxf(src[(size_t)rowi * 128 + o], 0.f);
        }
    }
    __syncthreads();
    const float* w = dw + (size_t)g * 256 * 128 + (size_t)kk * 128 * 128 + o;
    float a0 = 0.f, a1 = 0.f, a2 = 0.f, a3 = 0.f;
    const float* x0 = fs + 0 * 256 + kk * 128;
    const float* x1 = fs + 1 * 256 + kk * 128;
    const float* x2 = fs + 2 * 256 + kk * 128;
    const float* x3 = fs + 3 * 256 + kk * 128;
    #pragma unroll 8
    for (int f = 0; f < 128; ++f) {
        const float wv = w[f * 128];
        a0 = fmaf(x0[f], wv, a0);
        a1 = fmaf(x1[f], wv, a1);
        a2 = fmaf(x2[f], wv, a2);
        a3 = fmaf(x3[f], wv, a3);
    }
    red[kk][0][o] = a0; red[kk][1][o] = a1; red[kk][2][o] = a2; red[kk][3][o] = a3;
    __syncthreads();
    if (t < 128) {
        const float bias = db[g * 128 + t];
        #pragma unroll
        for (int r = 0; r < 4; ++r) {
            const int b = bt * 4 + r;
            dd[(size_t)b * 2048 + g * 128 + t] =
                fmaxf(red[0][r][t] + red[1][r][t] + bias, 0.f);
        }
    }
}

// ---------------- final fc 2048->64: one block per batch row ----------------
__global__ __launch_bounds__(256) void k_fc(
    const float* __restrict__ dd, const float* __restrict__ fcw,
    const float* __restrict__ fcb, float* __restrict__ out)
{
    const int b = blockIdx.x;
    const int t = threadIdx.x;
    const int o = t & 63;
    const int k = t >> 6;                  // 0..3
    __shared__ float ds[2048];
    __shared__ float red[4][64];
    for (int i = t; i < 2048; i += 256) ds[i] = dd[(size_t)b * 2048 + i];
    __syncthreads();
    const float* w  = fcw + (k * 512) * 64 + o;
    const float* xr = ds + k * 512;
    float a0 = 0.f, a1 = 0.f, a2 = 0.f, a3 = 0.f;
    #pragma unroll 4
    for (int f = 0; f < 512; f += 4) {
        a0 = fmaf(xr[f + 0], w[(f + 0) * 64], a0);
        a1 = fmaf(xr[f + 1], w[(f + 1) * 64], a1);
        a2 = fmaf(xr[f + 2], w[(f + 2) * 64], a2);
        a3 = fmaf(xr[f + 3], w[(f + 3) * 64], a3);
    }
    red[k][o] = (a0 + a1) + (a2 + a3);
    __syncthreads();
    if (t < 64)
        out[(size_t)b * 64 + t] = ((red[0][t] + red[1][t]) + (red[2][t] + red[3][t])) + fcb[t];
}

} // namespace

extern "C" void kernel_launch(void* const* d_in, const int* in_sizes, int n_in,
                              void* d_out, int out_size, void* d_ws, size_t ws_size,
                              hipStream_t stream)
{
    const float* x1 = (const float*)d_in[0];
    const float* x2 = (const float*)d_in[1];
    const int* ei0  = (const int*)d_in[2];
    const int* ei1  = (const int*)d_in[3];
    const int* gei0 = (const int*)d_in[4];
    const int* gei1 = (const int*)d_in[5];
    const float* conv_w3 = (const float*)d_in[6];
    const float* conv_b3 = (const float*)d_in[7];
    const float* conv_w5 = (const float*)d_in[8];
    const float* conv_b5 = (const float*)d_in[9];
    const float* conv_w7 = (const float*)d_in[10];
    const float* conv_b7 = (const float*)d_in[11];
    const float* tconv_w3 = (const float*)d_in[12];
    const float* tconv_b3 = (const float*)d_in[13];
    const float* tconv_w5 = (const float*)d_in[14];
    const float* tconv_b5 = (const float*)d_in[15];
    const float* tconv_w7 = (const float*)d_in[16];
    const float* tconv_b7 = (const float*)d_in[17];
    const float* ff_w    = (const float*)d_in[18];
    const float* ff_b    = (const float*)d_in[19];
    const float* lower_w = (const float*)d_in[20];
    const float* lower_b = (const float*)d_in[21];
    const float* upper_w = (const float*)d_in[22];
    const float* upper_b = (const float*)d_in[23];
    const float* agg_w   = (const float*)d_in[24];
    const float* agg_b   = (const float*)d_in[25];
    const float* disc_w  = (const float*)d_in[26];
    const float* disc_b  = (const float*)d_in[27];
    const float* fc_w    = (const float*)d_in[28];
    const float* fc_b    = (const float*)d_in[29];

    float* ws = (float*)d_ws;
    float* f_feats = ws;                          // 6291456
    float* f_hw    = ws + 10485760;               // 4194304
    float* f_gout  = ws + 14680064;               // 4194304
    float* f_hg    = ws + 18874368;               // 1048576
    float* f_hgw   = ws + 19922944;               // 1048576
    float* f_henc  = ws + 20971520;               // 1048576
    float* f_dd    = ws + 22020096;               // 524288
    float* f_dinv1 = ws + 22544384;               // 32768
    float* f_dinv2 = ws + 22577152;               // 8192
    int* ip    = (int*)(ws + 22585344);
    int* cnt1  = ip;                              // 32768
    int* cnt2  = cnt1 + 2 * NROWS;                // 8192 (contiguous with cnt1)
    int* offs1 = cnt2 + 2 * GROWS;                // 32769
    int* cur1  = offs1 + 2 * NROWS + 1;           // 32768
    int* esrc1 = cur1 + 2 * NROWS;                // 524288
    int* offs2 = esrc1 + 2 * E1;                  // 8193
    int* cur2  = offs2 + 2 * GROWS + 1;           // 8192
    int* esrc2 = cur2 + 2 * GROWS;                // 65536
    int* bsum1 = esrc2 + 2 * E2;                  // 32
    int* bsum2 = bsum1 + 32;                      // 8

    // CSR build, both graphs in 5 launches
    k_zero_i<<<(2 * NROWS + 2 * GROWS) / 256, 256, 0, stream>>>(cnt1, 2 * NROWS + 2 * GROWS);
    k_hist_all<<<(2 * E1 + 2 * E2) / 256, 256, 0, stream>>>(ei0, ei1, gei0, gei1, cnt1, cnt2);
    k_scan_bsum_all<<<40, 256, 0, stream>>>(cnt1, cnt2, bsum1, bsum2);
    k_scan_final_all<<<40, 256, 0, stream>>>(cnt1, bsum1, offs1, cur1, f_dinv1,
                                             cnt2, bsum2, offs2, cur2, f_dinv2);
    k_fill_all<<<(2 * E1 + 2 * E2) / 256, 256, 0, stream>>>(ei0, ei1, gei0, gei1,
                                                            cur1, esrc1, cur2, esrc2);

    // encoder pipeline (both encoders per dispatch)
    k_conv_feats<<<2 * NROWS / 16, 256, 0, stream>>>(x1, x2,
        conv_w3, conv_b3, conv_w5, conv_b5, conv_w7, conv_b7,
        tconv_w3, tconv_b3, tconv_w5, tconv_b5, tconv_w7, tconv_b7, f_feats);
    k_ff_lower<<<2048, 256, 0, stream>>>(f_feats, ff_w, ff_b, lower_w, f_hw);
    k_gcn_gather<<<2 * NROWS, 128, 0, stream>>>(offs1, esrc1, f_hw, f_dinv1,
                                                lower_b, f_gout, NROWS);
    k_agg<<<2 * (Bn / 4) * 16, 256, 0, stream>>>(f_gout, agg_w, agg_b, f_hg);
    k_gemm128<<<2 * GROWS / 16, 256, 0, stream>>>(f_hg, upper_w, f_hgw);
    k_gcn_gather<<<2 * GROWS, 128, 0, stream>>>(offs2, esrc2, f_hgw, f_dinv2,
                                                upper_b, f_henc, GROWS);

    k_disc<<<(Bn / 4) * 16, 256, 0, stream>>>(f_henc, f_henc + (size_t)GROWS * 128,
                                              disc_w, disc_b, f_dd);
    k_fc<<<Bn, 256, 0, stream>>>(f_dd, fc_w, fc_b, (float*)d_out);
}

// Round 10
// 283.056 us; speedup vs baseline: 10.0888x; 1.0004x over previous
//
#include <hip/hip_runtime.h>
#include <hip/hip_bf16.h>

namespace {

constexpr int Bn      = 256;
constexpr int NNODES  = 64;
constexpr int NGROUPS = 16;
constexpr int L       = 64;
constexpr int C       = 32;
constexpr int GH      = 128;
constexpr int E1      = 262144;
constexpr int E2      = 32768;
constexpr int NROWS   = Bn * NNODES;   // 16384
constexpr int GROWS   = Bn * NGROUPS;  // 4096
constexpr int XROW    = 296;           // LDS row stride (288 data + 8 pad; 296%32=8)

// ---------------- conv + max + relu -> feats [2*NROWS,192] ----------------
// 2 channels per thread share one register window; position-pairs feed v_max3.
template<int K, int LX>
__device__ __forceinline__ void convmax2(const float* __restrict__ xin_al,
                                         const float* __restrict__ wpa,
                                         const float* __restrict__ wpb,
                                         float& ma, float& mb)
{
    constexpr int PAD = (K - 1) / 2;
    constexpr int OFF = 3 - PAD;
    float wa[K], wb[K];
    #pragma unroll
    for (int i = 0; i < K; ++i) { wa[i] = wpa[i]; wb[i] = wpb[i]; }
    ma = -3.0e38f; mb = -3.0e38f;
    #pragma unroll
    for (int p0 = 0; p0 < LX; p0 += 16) {
        float xw[24];
        #pragma unroll
        for (int q = 0; q < 6; ++q) {
            const float4 v = *(const float4*)(xin_al + p0 + q * 4);
            xw[q * 4 + 0] = v.x; xw[q * 4 + 1] = v.y;
            xw[q * 4 + 2] = v.z; xw[q * 4 + 3] = v.w;
        }
        #pragma unroll
        for (int p = 0; p < 16; p += 2) {
            if (p0 + p + 1 < LX) {
                float sa0 = 0.f, sb0 = 0.f, sa1 = 0.f, sb1 = 0.f;
                #pragma unroll
                for (int i = 0; i < K; ++i) {
                    const float xv0 = xw[p + OFF + i];
                    const float xv1 = xw[p + 1 + OFF + i];
                    sa0 = fmaf(wa[i], xv0, sa0);
                    sb0 = fmaf(wb[i], xv0, sb0);
                    sa1 = fmaf(wa[i], xv1, sa1);
                    sb1 = fmaf(wb[i], xv1, sb1);
                }
                ma = fmaxf(fmaxf(sa0, sa1), ma);   // v_max3
                mb = fmaxf(fmaxf(sb0, sb1), mb);
            }
        }
    }
}

// ch-0 branches: K=3,5,7 (LX=64) x 2 channels share ONE window load.
__device__ __forceinline__ void conv6_ch0(
    const float* __restrict__ xin_al,
    const float* __restrict__ w3a, const float* __restrict__ w3b,
    const float* __restrict__ w5a, const float* __restrict__ w5b,
    const float* __restrict__ w7a, const float* __restrict__ w7b,
    float& m3a, float& m3b, float& m5a, float& m5b, float& m7a, float& m7b)
{
    float a3[3], b3[3], a5[5], b5[5], a7[7], b7[7];
    #pragma unroll
    for (int i = 0; i < 3; ++i) { a3[i] = w3a[i]; b3[i] = w3b[i]; }
    #pragma unroll
    for (int i = 0; i < 5; ++i) { a5[i] = w5a[i]; b5[i] = w5b[i]; }
    #pragma unroll
    for (int i = 0; i < 7; ++i) { a7[i] = w7a[i]; b7[i] = w7b[i]; }
    m3a = m3b = m5a = m5b = m7a = m7b = -3.0e38f;
    #pragma unroll
    for (int p0 = 0; p0 < 64; p0 += 16) {
        float xw[24];
        #pragma unroll
        for (int q = 0; q < 6; ++q) {
            const float4 v = *(const float4*)(xin_al + p0 + q * 4);
            xw[q * 4 + 0] = v.x; xw[q * 4 + 1] = v.y;
            xw[q * 4 + 2] = v.z; xw[q * 4 + 3] = v.w;
        }
        #pragma unroll
        for (int p = 0; p < 16; p += 2) {
            float s3a0 = 0.f, s3b0 = 0.f, s3a1 = 0.f, s3b1 = 0.f;
            #pragma unroll
            for (int i = 0; i < 3; ++i) {
                const float xv0 = xw[p + 2 + i], xv1 = xw[p + 3 + i];
                s3a0 = fmaf(a3[i], xv0, s3a0); s3b0 = fmaf(b3[i], xv0, s3b0);
                s3a1 = fmaf(a3[i], xv1, s3a1); s3b1 = fmaf(b3[i], xv1, s3b1);
            }
            m3a = fmaxf(fmaxf(s3a0, s3a1), m3a);
            m3b = fmaxf(fmaxf(s3b0, s3b1), m3b);
            float s5a0 = 0.f, s5b0 = 0.f, s5a1 = 0.f, s5b1 = 0.f;
            #pragma unroll
            for (int i = 0; i < 5; ++i) {
                const float xv0 = xw[p + 1 + i], xv1 = xw[p + 2 + i];
                s5a0 = fmaf(a5[i], xv0, s5a0); s5b0 = fmaf(b5[i], xv0, s5b0);
                s5a1 = fmaf(a5[i], xv1, s5a1); s5b1 = fmaf(b5[i], xv1, s5b1);
            }
            m5a = fmaxf(fmaxf(s5a0, s5a1), m5a);
            m5b = fmaxf(fmaxf(s5b0, s5b1), m5b);
            float s7a0 = 0.f, s7b0 = 0.f, s7a1 = 0.f, s7b1 = 0.f;
            #pragma unroll
            for (int i = 0; i < 7; ++i) {
                const float xv0 = xw[p + 0 + i], xv1 = xw[p + 1 + i];
                s7a0 = fmaf(a7[i], xv0, s7a0); s7b0 = fmaf(b7[i], xv0, s7b0);
                s7a1 = fmaf(a7[i], xv1, s7a1); s7b1 = fmaf(b7[i], xv1, s7b1);
            }
            m7a = fmaxf(fmaxf(s7a0, s7a1), m7a);
            m7b = fmaxf(fmaxf(s7b0, s7b1), m7b);
        }
    }
}

// grid = 2*NROWS/16 ; block 256 = 16 rows x 16 channel-pairs.
__global__ __launch_bounds__(256) void k_conv_feats(
    const float* __restrict__ x1, const float* __restrict__ x2,
    const float* __restrict__ w3,  const float* __restrict__ b3,
    const float* __restrict__ w5,  const float* __restrict__ b5,
    const float* __restrict__ w7,  const float* __restrict__ b7,
    const float* __restrict__ tw3, const float* __restrict__ tb3,
    const float* __restrict__ tw5, const float* __restrict__ tb5,
    const float* __restrict__ tw7, const float* __restrict__ tb7,
    float* __restrict__ feats)
{
    __shared__ float xs[16 * XROW];
    const int t = threadIdx.x;             // 256
    const int eb = blockIdx.x >> 10;       // 0,1
    const float* __restrict__ x = eb ? x2 : x1;
    const int row0 = (blockIdx.x & 1023) * 16;
    for (int idx = t; idx < 16 * 4 * 72; idx += 256) {
        const int r   = idx / 288;
        const int rem = idx - r * 288;
        const int c   = rem / 72;
        const int j   = rem - c * 72;
        const int l   = j - 3;
        float v = 0.f;
        if (l >= 0 && l < 64 - 2 * c)
            v = x[(size_t)(row0 + r) * 256 + c * 64 + l];
        xs[r * XROW + c * 72 + j] = v;
    }
    __syncthreads();

    const int rr  = t >> 4;                // 0..15
    const int cp  = t & 15;                // 0..15
    const int ch0 = cp * 2;
    const int row = row0 + rr;
    const int n   = row & (NNODES - 1);
    const int wc0 = n * C + ch0;
    const int wc1 = wc0 + 1;
    const float* xb0 = &xs[rr * XROW + 0 * 72];
    const float* xb1 = &xs[rr * XROW + 1 * 72];
    const float* xb2 = &xs[rr * XROW + 2 * 72];
    const float* xb3 = &xs[rr * XROW + 3 * 72];

    float* o = feats + (size_t)(eb * NROWS + row) * 192 + ch0;

    float m3a, m3b, m5a, m5b, m7a, m7b;
    conv6_ch0(xb0, w3 + wc0 * 3, w3 + wc1 * 3, w5 + wc0 * 5, w5 + wc1 * 5,
              w7 + wc0 * 7, w7 + wc1 * 7, m3a, m3b, m5a, m5b, m7a, m7b);
    *(float2*)(o + 0 * 32) = make_float2(fmaxf(m3a + b3[wc0], 0.f), fmaxf(m3b + b3[wc1], 0.f));
    *(float2*)(o + 1 * 32) = make_float2(fmaxf(m5a + b5[wc0], 0.f), fmaxf(m5b + b5[wc1], 0.f));
    *(float2*)(o + 2 * 32) = make_float2(fmaxf(m7a + b7[wc0], 0.f), fmaxf(m7b + b7[wc1], 0.f));

    float ma, mb;
    convmax2<3, 62>(xb1, tw3 + wc0 * 3, tw3 + wc1 * 3, ma, mb);
    *(float2*)(o + 3 * 32) = make_float2(fmaxf(ma + tb3[wc0], 0.f), fmaxf(mb + tb3[wc1], 0.f));
    convmax2<5, 60>(xb2, tw5 + wc0 * 5, tw5 + wc1 * 5, ma, mb);
    *(float2*)(o + 4 * 32) = make_float2(fmaxf(ma + tb5[wc0], 0.f), fmaxf(mb + tb5[wc1], 0.f));
    convmax2<7, 58>(xb3, tw7 + wc0 * 7, tw7 + wc1 * 7, ma, mb);
    *(float2*)(o + 5 * 32) = make_float2(fmaxf(ma + tb7[wc0], 0.f), fmaxf(mb + tb7[wc1], 0.f));
}

// ---------------- fused FF(192->128,relu) + lower(128x128) -----------------
__global__ __launch_bounds__(256) void k_ff_lower(
    const float* __restrict__ feats, const float* __restrict__ ffw,
    const float* __restrict__ ffb, const float* __restrict__ lw,
    float* __restrict__ hw)
{
    const int nb = blockIdx.x >> 6;        // 0..31
    const int n  = blockIdx.x & 63;
    const int t  = threadIdx.x;
    const int o  = t & 127;
    const int rh = t >> 7;                 // 0..1
    __shared__ float fs[16 * 192];
    __shared__ float h0s[16 * 128];
    {
        float4* d4 = (float4*)fs;
        for (int i = t; i < 16 * 48; i += 256) {
            const int r = i / 48, c4 = i - r * 48;
            d4[i] = *(const float4*)(feats + ((size_t)(nb * 16 + r) * 64 + n) * 192 + c4 * 4);
        }
    }
    __syncthreads();
    {
        const float* w = ffw + (size_t)n * 192 * 128 + o;
        float acc[8];
        #pragma unroll
        for (int r = 0; r < 8; ++r) acc[r] = 0.f;
        #pragma unroll 2
        for (int f = 0; f < 192; f += 4) {
            const float w0 = w[(f + 0) * 128];
            const float w1 = w[(f + 1) * 128];
            const float w2 = w[(f + 2) * 128];
            const float w3_ = w[(f + 3) * 128];
            #pragma unroll
            for (int r = 0; r < 8; ++r) {
                const float4 xv = *(const float4*)(fs + (rh * 8 + r) * 192 + f);
                acc[r] = fmaf(xv.x, w0, acc[r]);
                acc[r] = fmaf(xv.y, w1, acc[r]);
                acc[r] = fmaf(xv.z, w2, acc[r]);
                acc[r] = fmaf(xv.w, w3_, acc[r]);
            }
        }
        const float bias = ffb[n * 128 + o];
        #pragma unroll
        for (int r = 0; r < 8; ++r)
            h0s[(rh * 8 + r) * 128 + o] = fmaxf(acc[r] + bias, 0.f);
    }
    __syncthreads();
    {
        const float* w = lw + o;
        float acc[8];
        #pragma unroll
        for (int r = 0; r < 8; ++r) acc[r] = 0.f;
        #pragma unroll 2
        for (int f = 0; f < 128; f += 4) {
            const float w0 = w[(f + 0) * 128];
            const float w1 = w[(f + 1) * 128];
            const float w2 = w[(f + 2) * 128];
            const float w3_ = w[(f + 3) * 128];
            #pragma unroll
            for (int r = 0; r < 8; ++r) {
                const float4 xv = *(const float4*)(h0s + (rh * 8 + r) * 128 + f);
                acc[r] = fmaf(xv.x, w0, acc[r]);
                acc[r] = fmaf(xv.y, w1, acc[r]);
                acc[r] = fmaf(xv.z, w2, acc[r]);
                acc[r] = fmaf(xv.w, w3_, acc[r]);
            }
        }
        #pragma unroll
        for (int r = 0; r < 8; ++r) {
            const int row = nb * 16 + rh * 8 + r;
            hw[((size_t)row * 64 + n) * 128 + o] = acc[r];
        }
    }
}

// ---------------- shared-weight 128x128 GEMM (v3) ---------------------------
__global__ __launch_bounds__(256) void k_gemm128(
    const float* __restrict__ X, const float* __restrict__ W,
    float* __restrict__ Y)
{
    const int r0 = blockIdx.x * 16;
    const int t  = threadIdx.x;
    const int o  = t & 127;
    const int rh = t >> 7;
    __shared__ float xs[16 * 128];
    {
        float4* d4 = (float4*)xs;
        const float4* s4 = (const float4*)(X + (size_t)r0 * 128);
        for (int i = t; i < 512; i += 256) d4[i] = s4[i];
    }
    __syncthreads();
    const float* w = W + o;
    float acc[8];
    #pragma unroll
    for (int r = 0; r < 8; ++r) acc[r] = 0.f;
    #pragma unroll 2
    for (int f = 0; f < 128; f += 4) {
        const float w0 = w[(f + 0) * 128];
        const float w1 = w[(f + 1) * 128];
        const float w2 = w[(f + 2) * 128];
        const float w3_ = w[(f + 3) * 128];
        #pragma unroll
        for (int r = 0; r < 8; ++r) {
            const float4 xv = *(const float4*)(xs + (rh * 8 + r) * 128 + f);
            acc[r] = fmaf(xv.x, w0, acc[r]);
            acc[r] = fmaf(xv.y, w1, acc[r]);
            acc[r] = fmaf(xv.z, w2, acc[r]);
            acc[r] = fmaf(xv.w, w3_, acc[r]);
        }
    }
    #pragma unroll
    for (int r = 0; r < 8; ++r)
        Y[(size_t)(r0 + rh * 8 + r) * 128 + o] = acc[r];
}

// ---------------- CSR build: both graphs (node+group), both encoders -------
__global__ void k_zero_i(int* __restrict__ p, int n) {
    const int i = blockIdx.x * blockDim.x + threadIdx.x;
    if (i < n) p[i] = 0;
}
__global__ void k_hist_all(const int* __restrict__ ei0, const int* __restrict__ ei1,
                           const int* __restrict__ gei0, const int* __restrict__ gei1,
                           int* __restrict__ cnt1, int* __restrict__ cnt2)
{
    const int gid = blockIdx.x * blockDim.x + threadIdx.x;
    if (gid < 2 * E1) {
        const int eb = gid >= E1;
        const int le = gid - (eb ? E1 : 0);
        const int* ei = eb ? ei1 : ei0;
        atomicAdd(&cnt1[(eb ? NROWS : 0) + ei[E1 + le]], 1);
    } else {
        const int g2 = gid - 2 * E1;
        const int eb = g2 >= E2;
        const int le = g2 - (eb ? E2 : 0);
        const int* ei = eb ? gei1 : gei0;
        atomicAdd(&cnt2[(eb ? GROWS : 0) + ei[E2 + le]], 1);
    }
}
__global__ __launch_bounds__(256) void k_scan_bsum_all(
    const int* __restrict__ cnt1, const int* __restrict__ cnt2,
    int* __restrict__ bsum1, int* __restrict__ bsum2)
{
    const int blk = blockIdx.x, t = threadIdx.x;
    const int* cnt; int* bsum; int lblk;
    if (blk < 32) { cnt = cnt1; bsum = bsum1; lblk = blk; }
    else          { cnt = cnt2; bsum = bsum2; lblk = blk - 32; }
    const int4 v = ((const int4*)cnt)[lblk * 256 + t];
    int s = v.x + v.y + v.z + v.w;
    #pragma unroll
    for (int off = 32; off > 0; off >>= 1) s += __shfl_down(s, off);
    __shared__ int wsum[4];
    if ((t & 63) == 0) wsum[t >> 6] = s;
    __syncthreads();
    if (t == 0) bsum[lblk] = wsum[0] + wsum[1] + wsum[2] + wsum[3];
}
__global__ __launch_bounds__(256) void k_scan_final_all(
    const int* __restrict__ cnt1, const int* __restrict__ bsum1,
    int* __restrict__ offs1, int* __restrict__ cur1, float* __restrict__ dinv1,
    const int* __restrict__ cnt2, const int* __restrict__ bsum2,
    int* __restrict__ offs2, int* __restrict__ cur2, float* __restrict__ dinv2)
{
    const int blk = blockIdx.x, t = threadIdx.x;
    const int* cnt; const int* bsum; int* offs; int* cur; float* dinv;
    int n, nb, lblk;
    if (blk < 32) { cnt = cnt1; bsum = bsum1; offs = offs1; cur = cur1; dinv = dinv1;
                    n = 2 * NROWS; nb = 32; lblk = blk; }
    else          { cnt = cnt2; bsum = bsum2; offs = offs2; cur = cur2; dinv = dinv2;
                    n = 2 * GROWS; nb = 8; lblk = blk - 32; }
    int base = 0;
    for (int i = 0; i < lblk; ++i) base += bsum[i];
    const int4 v = ((const int4*)cnt)[lblk * 256 + t];
    const int s = v.x + v.y + v.z + v.w;
    int sc = s;
    #pragma unroll
    for (int off = 1; off < 64; off <<= 1) {
        const int u = __shfl_up(sc, off);
        if ((t & 63) >= off) sc += u;
    }
    __shared__ int wsum[4];
    if ((t & 63) == 63) wsum[t >> 6] = sc;
    __syncthreads();
    int wbase = 0;
    for (int wv = 0; wv < (t >> 6); ++wv) wbase += wsum[wv];
    int o0 = base + wbase + sc - s;
    const int gi = lblk * 1024 + t * 4;
    offs[gi + 0] = o0; cur[gi + 0] = o0; dinv[gi + 0] = rsqrtf(1.f + (float)v.x); o0 += v.x;
    offs[gi + 1] = o0; cur[gi + 1] = o0; dinv[gi + 1] = rsqrtf(1.f + (float)v.y); o0 += v.y;
    offs[gi + 2] = o0; cur[gi + 2] = o0; dinv[gi + 2] = rsqrtf(1.f + (float)v.z); o0 += v.z;
    offs[gi + 3] = o0; cur[gi + 3] = o0; dinv[gi + 3] = rsqrtf(1.f + (float)v.w); o0 += v.w;
    if (lblk == nb - 1 && t == 255) offs[n] = o0;
}
__global__ void k_fill_all(const int* __restrict__ ei0, const int* __restrict__ ei1,
                           const int* __restrict__ gei0, const int* __restrict__ gei1,
                           int* __restrict__ cur1, int* __restrict__ esrc1,
                           int* __restrict__ cur2, int* __restrict__ esrc2)
{
    const int gid = blockIdx.x * blockDim.x + threadIdx.x;
    if (gid < 2 * E1) {
        const int eb = gid >= E1;
        const int le = gid - (eb ? E1 : 0);
        const int* ei = eb ? ei1 : ei0;
        const int s = ei[le];
        const int d = ei[E1 + le];
        const int pos = atomicAdd(&cur1[(eb ? NROWS : 0) + d], 1);
        esrc1[pos] = s;
    } else {
        const int g2 = gid - 2 * E1;
        const int eb = g2 >= E2;
        const int le = g2 - (eb ? E2 : 0);
        const int* ei = eb ? gei1 : gei0;
        const int s = ei[le];
        const int d = ei[E2 + le];
        const int pos = atomicAdd(&cur2[(eb ? GROWS : 0) + d], 1);
        esrc2[pos] = s;
    }
}

// ---------------- GCN gather (combined 2n rows, local CSR src ids) ---------
__global__ __launch_bounds__(128) void k_gcn_gather(
    const int* __restrict__ offs, const int* __restrict__ esrc,
    const float* __restrict__ hw, const float* __restrict__ dinv,
    const float* __restrict__ bias, float* __restrict__ out, int n)
{
    const int d = blockIdx.x;
    const int t = threadIdx.x;             // 128
    const int sbase = (d >= n) ? n : 0;
    const int e0 = offs[d], e1 = offs[d + 1];
    const float dd = dinv[d];
    float a0 = hw[(size_t)d * 128 + t] * dd;
    float a1 = 0.f, a2 = 0.f, a3 = 0.f;
    int j = e0;
    for (; j + 3 < e1; j += 4) {
        const int s0 = sbase + esrc[j],     s1 = sbase + esrc[j + 1];
        const int s2 = sbase + esrc[j + 2], s3 = sbase + esrc[j + 3];
        a0 = fmaf(hw[(size_t)s0 * 128 + t], dinv[s0], a0);
        a1 = fmaf(hw[(size_t)s1 * 128 + t], dinv[s1], a1);
        a2 = fmaf(hw[(size_t)s2 * 128 + t], dinv[s2], a2);
        a3 = fmaf(hw[(size_t)s3 * 128 + t], dinv[s3], a3);
    }
    for (; j < e1; ++j) {
        const int s = sbase + esrc[j];
        a0 = fmaf(hw[(size_t)s * 128 + t], dinv[s], a0);
    }
    const float acc = (a0 + a1) + (a2 + a3);
    out[(size_t)d * 128 + t] = fmaf(acc, dd, bias[t]);
}

// ---------------- per-group aggregate 512->128 (4 rows, K-split 2) ----------
__global__ __launch_bounds__(256) void k_agg(
    const float* __restrict__ h, const float* __restrict__ aggw,
    const float* __restrict__ aggb, float* __restrict__ hg)
{
    const int bt = blockIdx.x >> 4;        // 0..127
    const int g  = blockIdx.x & 15;
    const int t  = threadIdx.x;
    const int o  = t & 127;
    const int kk = t >> 7;
    __shared__ float fs[4 * 512];
    __shared__ float red[2][4][128];
    {
        const int b0 = bt * 4;
        float4* dst = (float4*)fs;
        for (int i = t; i < 4 * 128; i += 256) {
            const int r = i >> 7;
            const int q = i & 127;
            dst[i] = *(const float4*)(h + ((size_t)(b0 + r) * 64 + g * 4) * 128 + q * 4);
        }
    }
    __syncthreads();
    const float* w = aggw + (size_t)g * 512 * 128 + (size_t)kk * 256 * 128 + o;
    float a0 = 0.f, a1 = 0.f, a2 = 0.f, a3 = 0.f;
    const float* x0 = fs + 0 * 512 + kk * 256;
    const float* x1 = fs + 1 * 512 + kk * 256;
    const float* x2 = fs + 2 * 512 + kk * 256;
    const float* x3 = fs + 3 * 512 + kk * 256;
    #pragma unroll 8
    for (int f = 0; f < 256; ++f) {
        const float wv = w[f * 128];
        a0 = fmaf(x0[f], wv, a0);
        a1 = fmaf(x1[f], wv, a1);
        a2 = fmaf(x2[f], wv, a2);
        a3 = fmaf(x3[f], wv, a3);
    }
    red[kk][0][o] = a0; red[kk][1][o] = a1; red[kk][2][o] = a2; red[kk][3][o] = a3;
    __syncthreads();
    if (t < 128) {
        const float bias = aggb[g * 128 + t];
        #pragma unroll
        for (int r = 0; r < 4; ++r) {
            const int b = bt * 4 + r;
            hg[((size_t)b * 16 + g) * 128 + t] = red[0][r][t] + red[1][r][t] + bias;
        }
    }
}

// ---------------- disc (4 rows, K-split 2): relu in, 256->128 + relu --------
__global__ __launch_bounds__(256) void k_disc(
    const float* __restrict__ h1, const float* __restrict__ h2,
    const float* __restrict__ dw, const float* __restrict__ db,
    float* __restrict__ dd)
{
    const int bt = blockIdx.x >> 4;        // 0..63
    const int g  = blockIdx.x & 15;
    const int t  = threadIdx.x;
    const int o  = t & 127;
    const int kk = t >> 7;
    __shared__ float fs[4 * 256];
    __shared__ float red[2][4][128];
    {
        const int half = t >> 7;
        #pragma unroll
        for (int r = 0; r < 4; ++r) {
            const int rowi = ((bt * 4 + r) * 16 + g);
            const float* src = half ? h2 : h1;
            fs[r * 256 + half * 128 + o] = fmaxf(src[(size_t)rowi * 128 + o], 0.f);
        }
    }
    __syncthreads();
    const float* w = dw + (size_t)g * 256 * 128 + (size_t)kk * 128 * 128 + o;
    float a0 = 0.f, a1 = 0.f, a2 = 0.f, a3 = 0.f;
    const float* x0 = fs + 0 * 256 + kk * 128;
    const float* x1 = fs + 1 * 256 + kk * 128;
    const float* x2 = fs + 2 * 256 + kk * 128;
    const float* x3 = fs + 3 * 256 + kk * 128;
    #pragma unroll 8
    for (int f = 0; f < 128; ++f) {
        const float wv = w[f * 128];
        a0 = fmaf(x0[f], wv, a0);
        a1 = fmaf(x1[f], wv, a1);
        a2 = fmaf(x2[f], wv, a2);
        a3 = fmaf(x3[f], wv, a3);
    }
    red[kk][0][o] = a0; red[kk][1][o] = a1; red[kk][2][o] = a2; red[kk][3][o] = a3;
    __syncthreads();
    if (t < 128) {
        const float bias = db[g * 128 + t];
        #pragma unroll
        for (int r = 0; r < 4; ++r) {
            const int b = bt * 4 + r;
            dd[(size_t)b * 2048 + g * 128 + t] =
                fmaxf(red[0][r][t] + red[1][r][t] + bias, 0.f);
        }
    }
}

// ---------------- final fc 2048->64: one block per batch row ----------------
__global__ __launch_bounds__(256) void k_fc(
    const float* __restrict__ dd, const float* __restrict__ fcw,
    const float* __restrict__ fcb, float* __restrict__ out)
{
    const int b = blockIdx.x;
    const int t = threadIdx.x;
    const int o = t & 63;
    const int k = t >> 6;                  // 0..3
    __shared__ float ds[2048];
    __shared__ float red[4][64];
    for (int i = t; i < 2048; i += 256) ds[i] = dd[(size_t)b * 2048 + i];
    __syncthreads();
    const float* w  = fcw + (k * 512) * 64 + o;
    const float* xr = ds + k * 512;
    float a0 = 0.f, a1 = 0.f, a2 = 0.f, a3 = 0.f;
    #pragma unroll 4
    for (int f = 0; f < 512; f += 4) {
        a0 = fmaf(xr[f + 0], w[(f + 0) * 64], a0);
        a1 = fmaf(xr[f + 1], w[(f + 1) * 64], a1);
        a2 = fmaf(xr[f + 2], w[(f + 2) * 64], a2);
        a3 = fmaf(xr[f + 3], w[(f + 3) * 64], a3);
    }
    red[k][o] = (a0 + a1) + (a2 + a3);
    __syncthreads();
    if (t < 64)
        out[(size_t)b * 64 + t] = ((red[0][t] + red[1][t]) + (red[2][t] + red[3][t])) + fcb[t];
}

} // namespace

extern "C" void kernel_launch(void* const* d_in, const int* in_sizes, int n_in,
                              void* d_out, int out_size, void* d_ws, size_t ws_size,
                              hipStream_t stream)
{
    const float* x1 = (const float*)d_in[0];
    const float* x2 = (const float*)d_in[1];
    const int* ei0  = (const int*)d_in[2];
    const int* ei1  = (const int*)d_in[3];
    const int* gei0 = (const int*)d_in[4];
    const int* gei1 = (const int*)d_in[5];
    const float* conv_w3 = (const float*)d_in[6];
    const float* conv_b3 = (const float*)d_in[7];
    const float* conv_w5 = (const float*)d_in[8];
    const float* conv_b5 = (const float*)d_in[9];
    const float* conv_w7 = (const float*)d_in[10];
    const float* conv_b7 = (const float*)d_in[11];
    const float* tconv_w3 = (const float*)d_in[12];
    const float* tconv_b3 = (const float*)d_in[13];
    const float* tconv_w5 = (const float*)d_in[14];
    const float* tconv_b5 = (const float*)d_in[15];
    const float* tconv_w7 = (const float*)d_in[16];
    const float* tconv_b7 = (const float*)d_in[17];
    const float* ff_w    = (const float*)d_in[18];
    const float* ff_b    = (const float*)d_in[19];
    const float* lower_w = (const float*)d_in[20];
    const float* lower_b = (const float*)d_in[21];
    const float* upper_w = (const float*)d_in[22];
    const float* upper_b = (const float*)d_in[23];
    const float* agg_w   = (const float*)d_in[24];
    const float* agg_b   = (const float*)d_in[25];
    const float* disc_w  = (const float*)d_in[26];
    const float* disc_b  = (const float*)d_in[27];
    const float* fc_w    = (const float*)d_in[28];
    const float* fc_b    = (const float*)d_in[29];

    float* ws = (float*)d_ws;
    float* f_feats = ws;                          // 6291456
    float* f_hw    = ws + 10485760;               // 4194304
    float* f_gout  = ws + 14680064;               // 4194304
    float* f_hg    = ws + 18874368;               // 1048576
    float* f_hgw   = ws + 19922944;               // 1048576
    float* f_henc  = ws + 20971520;               // 1048576
    float* f_dd    = ws + 22020096;               // 524288
    float* f_dinv1 = ws + 22544384;               // 32768
    float* f_dinv2 = ws + 22577152;               // 8192
    int* ip    = (int*)(ws + 22585344);
    int* cnt1  = ip;                              // 32768
    int* cnt2  = cnt1 + 2 * NROWS;                // 8192
    int* offs1 = cnt2 + 2 * GROWS;                // 32769
    int* cur1  = offs1 + 2 * NROWS + 1;           // 32768
    int* esrc1 = cur1 + 2 * NROWS;                // 524288
    int* offs2 = esrc1 + 2 * E1;                  // 8193
    int* cur2  = offs2 + 2 * GROWS + 1;           // 8192
    int* esrc2 = cur2 + 2 * GROWS;                // 65536
    int* bsum1 = esrc2 + 2 * E2;                  // 32
    int* bsum2 = bsum1 + 32;                      // 8

    // CSR build, both graphs in 5 launches
    k_zero_i<<<(2 * NROWS + 2 * GROWS) / 256, 256, 0, stream>>>(cnt1, 2 * NROWS + 2 * GROWS);
    k_hist_all<<<(2 * E1 + 2 * E2) / 256, 256, 0, stream>>>(ei0, ei1, gei0, gei1, cnt1, cnt2);
    k_scan_bsum_all<<<40, 256, 0, stream>>>(cnt1, cnt2, bsum1, bsum2);
    k_scan_final_all<<<40, 256, 0, stream>>>(cnt1, bsum1, offs1, cur1, f_dinv1,
                                             cnt2, bsum2, offs2, cur2, f_dinv2);
    k_fill_all<<<(2 * E1 + 2 * E2) / 256, 256, 0, stream>>>(ei0, ei1, gei0, gei1,
                                                            cur1, esrc1, cur2, esrc2);

    // encoder pipeline (both encoders per dispatch)
    k_conv_feats<<<2 * NROWS / 16, 256, 0, stream>>>(x1, x2,
        conv_w3, conv_b3, conv_w5, conv_b5, conv_w7, conv_b7,
        tconv_w3, tconv_b3, tconv_w5, tconv_b5, tconv_w7, tconv_b7, f_feats);
    k_ff_lower<<<2048, 256, 0, stream>>>(f_feats, ff_w, ff_b, lower_w, f_hw);
    k_gcn_gather<<<2 * NROWS, 128, 0, stream>>>(offs1, esrc1, f_hw, f_dinv1,
                                                lower_b, f_gout, NROWS);
    k_agg<<<2 * (Bn / 4) * 16, 256, 0, stream>>>(f_gout, agg_w, agg_b, f_hg);
    k_gemm128<<<2 * GROWS / 16, 256, 0, stream>>>(f_hg, upper_w, f_hgw);
    k_gcn_gather<<<2 * GROWS, 128, 0, stream>>>(offs2, esrc2, f_hgw, f_dinv2,
                                                upper_b, f_henc, GROWS);

    k_disc<<<(Bn / 4) * 16, 256, 0, stream>>>(f_henc, f_henc + (size_t)GROWS * 128,
                                              disc_w, disc_b, f_dd);
    k_fc<<<Bn, 256, 0, stream>>>(f_dd, fc_w, fc_b, (float*)d_out);
}

// Round 11
// 282.869 us; speedup vs baseline: 10.0954x; 1.0007x over previous
//
#include <hip/hip_runtime.h>
#include <hip/hip_bf16.h>

namespace {

constexpr int Bn      = 256;
constexpr int NNODES  = 64;
constexpr int NGROUPS = 16;
constexpr int L       = 64;
constexpr int C       = 32;
constexpr int GH      = 128;
constexpr int E1      = 262144;
constexpr int E2      = 32768;
constexpr int NROWS   = Bn * NNODES;   // 16384
constexpr int GROWS   = Bn * NGROUPS;  // 4096
constexpr int XROW    = 296;           // LDS row stride (288 data + 8 pad; 296%32=8)

// ---------------- conv + max + relu -> feats [2*NROWS,192] ----------------
// 2 channels per thread share one register window; position-pairs feed v_max3.
template<int K, int LX>
__device__ __forceinline__ void convmax2(const float* __restrict__ xin_al,
                                         const float* __restrict__ wpa,
                                         const float* __restrict__ wpb,
                                         float& ma, float& mb)
{
    constexpr int PAD = (K - 1) / 2;
    constexpr int OFF = 3 - PAD;
    float wa[K], wb[K];
    #pragma unroll
    for (int i = 0; i < K; ++i) { wa[i] = wpa[i]; wb[i] = wpb[i]; }
    ma = -3.0e38f; mb = -3.0e38f;
    #pragma unroll
    for (int p0 = 0; p0 < LX; p0 += 16) {
        float xw[24];
        #pragma unroll
        for (int q = 0; q < 6; ++q) {
            const float4 v = *(const float4*)(xin_al + p0 + q * 4);
            xw[q * 4 + 0] = v.x; xw[q * 4 + 1] = v.y;
            xw[q * 4 + 2] = v.z; xw[q * 4 + 3] = v.w;
        }
        #pragma unroll
        for (int p = 0; p < 16; p += 2) {
            if (p0 + p + 1 < LX) {
                float sa0 = 0.f, sb0 = 0.f, sa1 = 0.f, sb1 = 0.f;
                #pragma unroll
                for (int i = 0; i < K; ++i) {
                    const float xv0 = xw[p + OFF + i];
                    const float xv1 = xw[p + 1 + OFF + i];
                    sa0 = fmaf(wa[i], xv0, sa0);
                    sb0 = fmaf(wb[i], xv0, sb0);
                    sa1 = fmaf(wa[i], xv1, sa1);
                    sb1 = fmaf(wb[i], xv1, sb1);
                }
                ma = fmaxf(fmaxf(sa0, sa1), ma);   // v_max3
                mb = fmaxf(fmaxf(sb0, sb1), mb);
            }
        }
    }
}

// ch-0 branches: K=3,5,7 (LX=64) x 2 channels share ONE window load.
__device__ __forceinline__ void conv6_ch0(
    const float* __restrict__ xin_al,
    const float* __restrict__ w3a, const float* __restrict__ w3b,
    const float* __restrict__ w5a, const float* __restrict__ w5b,
    const float* __restrict__ w7a, const float* __restrict__ w7b,
    float& m3a, float& m3b, float& m5a, float& m5b, float& m7a, float& m7b)
{
    float a3[3], b3[3], a5[5], b5[5], a7[7], b7[7];
    #pragma unroll
    for (int i = 0; i < 3; ++i) { a3[i] = w3a[i]; b3[i] = w3b[i]; }
    #pragma unroll
    for (int i = 0; i < 5; ++i) { a5[i] = w5a[i]; b5[i] = w5b[i]; }
    #pragma unroll
    for (int i = 0; i < 7; ++i) { a7[i] = w7a[i]; b7[i] = w7b[i]; }
    m3a = m3b = m5a = m5b = m7a = m7b = -3.0e38f;
    #pragma unroll
    for (int p0 = 0; p0 < 64; p0 += 16) {
        float xw[24];
        #pragma unroll
        for (int q = 0; q < 6; ++q) {
            const float4 v = *(const float4*)(xin_al + p0 + q * 4);
            xw[q * 4 + 0] = v.x; xw[q * 4 + 1] = v.y;
            xw[q * 4 + 2] = v.z; xw[q * 4 + 3] = v.w;
        }
        #pragma unroll
        for (int p = 0; p < 16; p += 2) {
            float s3a0 = 0.f, s3b0 = 0.f, s3a1 = 0.f, s3b1 = 0.f;
            #pragma unroll
            for (int i = 0; i < 3; ++i) {
                const float xv0 = xw[p + 2 + i], xv1 = xw[p + 3 + i];
                s3a0 = fmaf(a3[i], xv0, s3a0); s3b0 = fmaf(b3[i], xv0, s3b0);
                s3a1 = fmaf(a3[i], xv1, s3a1); s3b1 = fmaf(b3[i], xv1, s3b1);
            }
            m3a = fmaxf(fmaxf(s3a0, s3a1), m3a);
            m3b = fmaxf(fmaxf(s3b0, s3b1), m3b);
            float s5a0 = 0.f, s5b0 = 0.f, s5a1 = 0.f, s5b1 = 0.f;
            #pragma unroll
            for (int i = 0; i < 5; ++i) {
                const float xv0 = xw[p + 1 + i], xv1 = xw[p + 2 + i];
                s5a0 = fmaf(a5[i], xv0, s5a0); s5b0 = fmaf(b5[i], xv0, s5b0);
                s5a1 = fmaf(a5[i], xv1, s5a1); s5b1 = fmaf(b5[i], xv1, s5b1);
            }
            m5a = fmaxf(fmaxf(s5a0, s5a1), m5a);
            m5b = fmaxf(fmaxf(s5b0, s5b1), m5b);
            float s7a0 = 0.f, s7b0 = 0.f, s7a1 = 0.f, s7b1 = 0.f;
            #pragma unroll
            for (int i = 0; i < 7; ++i) {
                const float xv0 = xw[p + 0 + i], xv1 = xw[p + 1 + i];
                s7a0 = fmaf(a7[i], xv0, s7a0); s7b0 = fmaf(b7[i], xv0, s7b0);
                s7a1 = fmaf(a7[i], xv1, s7a1); s7b1 = fmaf(b7[i], xv1, s7b1);
            }
            m7a = fmaxf(fmaxf(s7a0, s7a1), m7a);
            m7b = fmaxf(fmaxf(s7b0, s7b1), m7b);
        }
    }
}

// grid = 2*NROWS/16 ; block 256 = 16 rows x 16 channel-pairs.
// __launch_bounds__(256, 2): min 2 waves/EU -> VGPR ceiling 128, so the
// window + weights + accumulators stay in registers (at 36 VGPR the compiler
// re-rolled the loops; ~2.2x instruction bloat).
__global__ __launch_bounds__(256, 2) void k_conv_feats(
    const float* __restrict__ x1, const float* __restrict__ x2,
    const float* __restrict__ w3,  const float* __restrict__ b3,
    const float* __restrict__ w5,  const float* __restrict__ b5,
    const float* __restrict__ w7,  const float* __restrict__ b7,
    const float* __restrict__ tw3, const float* __restrict__ tb3,
    const float* __restrict__ tw5, const float* __restrict__ tb5,
    const float* __restrict__ tw7, const float* __restrict__ tb7,
    float* __restrict__ feats)
{
    __shared__ float xs[16 * XROW];
    const int t = threadIdx.x;             // 256
    const int eb = blockIdx.x >> 10;       // 0,1
    const float* __restrict__ x = eb ? x2 : x1;
    const int row0 = (blockIdx.x & 1023) * 16;
    for (int idx = t; idx < 16 * 4 * 72; idx += 256) {
        const int r   = idx / 288;
        const int rem = idx - r * 288;
        const int c   = rem / 72;
        const int j   = rem - c * 72;
        const int l   = j - 3;
        float v = 0.f;
        if (l >= 0 && l < 64 - 2 * c)
            v = x[(size_t)(row0 + r) * 256 + c * 64 + l];
        xs[r * XROW + c * 72 + j] = v;
    }
    __syncthreads();

    const int rr  = t >> 4;                // 0..15
    const int cp  = t & 15;                // 0..15
    const int ch0 = cp * 2;
    const int row = row0 + rr;
    const int n   = row & (NNODES - 1);
    const int wc0 = n * C + ch0;
    const int wc1 = wc0 + 1;
    const float* xb0 = &xs[rr * XROW + 0 * 72];
    const float* xb1 = &xs[rr * XROW + 1 * 72];
    const float* xb2 = &xs[rr * XROW + 2 * 72];
    const float* xb3 = &xs[rr * XROW + 3 * 72];

    float* o = feats + (size_t)(eb * NROWS + row) * 192 + ch0;

    float m3a, m3b, m5a, m5b, m7a, m7b;
    conv6_ch0(xb0, w3 + wc0 * 3, w3 + wc1 * 3, w5 + wc0 * 5, w5 + wc1 * 5,
              w7 + wc0 * 7, w7 + wc1 * 7, m3a, m3b, m5a, m5b, m7a, m7b);
    *(float2*)(o + 0 * 32) = make_float2(fmaxf(m3a + b3[wc0], 0.f), fmaxf(m3b + b3[wc1], 0.f));
    *(float2*)(o + 1 * 32) = make_float2(fmaxf(m5a + b5[wc0], 0.f), fmaxf(m5b + b5[wc1], 0.f));
    *(float2*)(o + 2 * 32) = make_float2(fmaxf(m7a + b7[wc0], 0.f), fmaxf(m7b + b7[wc1], 0.f));

    float ma, mb;
    convmax2<3, 62>(xb1, tw3 + wc0 * 3, tw3 + wc1 * 3, ma, mb);
    *(float2*)(o + 3 * 32) = make_float2(fmaxf(ma + tb3[wc0], 0.f), fmaxf(mb + tb3[wc1], 0.f));
    convmax2<5, 60>(xb2, tw5 + wc0 * 5, tw5 + wc1 * 5, ma, mb);
    *(float2*)(o + 4 * 32) = make_float2(fmaxf(ma + tb5[wc0], 0.f), fmaxf(mb + tb5[wc1], 0.f));
    convmax2<7, 58>(xb3, tw7 + wc0 * 7, tw7 + wc1 * 7, ma, mb);
    *(float2*)(o + 5 * 32) = make_float2(fmaxf(ma + tb7[wc0], 0.f), fmaxf(mb + tb7[wc1], 0.f));
}

// ---------------- fused FF(192->128,relu) + lower(128x128) -----------------
__global__ __launch_bounds__(256) void k_ff_lower(
    const float* __restrict__ feats, const float* __restrict__ ffw,
    const float* __restrict__ ffb, const float* __restrict__ lw,
    float* __restrict__ hw)
{
    const int nb = blockIdx.x >> 6;        // 0..31
    const int n  = blockIdx.x & 63;
    const int t  = threadIdx.x;
    const int o  = t & 127;
    const int rh = t >> 7;                 // 0..1
    __shared__ float fs[16 * 192];
    __shared__ float h0s[16 * 128];
    {
        float4* d4 = (float4*)fs;
        for (int i = t; i < 16 * 48; i += 256) {
            const int r = i / 48, c4 = i - r * 48;
            d4[i] = *(const float4*)(feats + ((size_t)(nb * 16 + r) * 64 + n) * 192 + c4 * 4);
        }
    }
    __syncthreads();
    {
        const float* w = ffw + (size_t)n * 192 * 128 + o;
        float acc[8];
        #pragma unroll
        for (int r = 0; r < 8; ++r) acc[r] = 0.f;
        #pragma unroll 2
        for (int f = 0; f < 192; f += 4) {
            const float w0 = w[(f + 0) * 128];
            const float w1 = w[(f + 1) * 128];
            const float w2 = w[(f + 2) * 128];
            const float w3_ = w[(f + 3) * 128];
            #pragma unroll
            for (int r = 0; r < 8; ++r) {
                const float4 xv = *(const float4*)(fs + (rh * 8 + r) * 192 + f);
                acc[r] = fmaf(xv.x, w0, acc[r]);
                acc[r] = fmaf(xv.y, w1, acc[r]);
                acc[r] = fmaf(xv.z, w2, acc[r]);
                acc[r] = fmaf(xv.w, w3_, acc[r]);
            }
        }
        const float bias = ffb[n * 128 + o];
        #pragma unroll
        for (int r = 0; r < 8; ++r)
            h0s[(rh * 8 + r) * 128 + o] = fmaxf(acc[r] + bias, 0.f);
    }
    __syncthreads();
    {
        const float* w = lw + o;
        float acc[8];
        #pragma unroll
        for (int r = 0; r < 8; ++r) acc[r] = 0.f;
        #pragma unroll 2
        for (int f = 0; f < 128; f += 4) {
            const float w0 = w[(f + 0) * 128];
            const float w1 = w[(f + 1) * 128];
            const float w2 = w[(f + 2) * 128];
            const float w3_ = w[(f + 3) * 128];
            #pragma unroll
            for (int r = 0; r < 8; ++r) {
                const float4 xv = *(const float4*)(h0s + (rh * 8 + r) * 128 + f);
                acc[r] = fmaf(xv.x, w0, acc[r]);
                acc[r] = fmaf(xv.y, w1, acc[r]);
                acc[r] = fmaf(xv.z, w2, acc[r]);
                acc[r] = fmaf(xv.w, w3_, acc[r]);
            }
        }
        #pragma unroll
        for (int r = 0; r < 8; ++r) {
            const int row = nb * 16 + rh * 8 + r;
            hw[((size_t)row * 64 + n) * 128 + o] = acc[r];
        }
    }
}

// ---------------- shared-weight 128x128 GEMM (v3) ---------------------------
__global__ __launch_bounds__(256) void k_gemm128(
    const float* __restrict__ X, const float* __restrict__ W,
    float* __restrict__ Y)
{
    const int r0 = blockIdx.x * 16;
    const int t  = threadIdx.x;
    const int o  = t & 127;
    const int rh = t >> 7;
    __shared__ float xs[16 * 128];
    {
        float4* d4 = (float4*)xs;
        const float4* s4 = (const float4*)(X + (size_t)r0 * 128);
        for (int i = t; i < 512; i += 256) d4[i] = s4[i];
    }
    __syncthreads();
    const float* w = W + o;
    float acc[8];
    #pragma unroll
    for (int r = 0; r < 8; ++r) acc[r] = 0.f;
    #pragma unroll 2
    for (int f = 0; f < 128; f += 4) {
        const float w0 = w[(f + 0) * 128];
        const float w1 = w[(f + 1) * 128];
        const float w2 = w[(f + 2) * 128];
        const float w3_ = w[(f + 3) * 128];
        #pragma unroll
        for (int r = 0; r < 8; ++r) {
            const float4 xv = *(const float4*)(xs + (rh * 8 + r) * 128 + f);
            acc[r] = fmaf(xv.x, w0, acc[r]);
            acc[r] = fmaf(xv.y, w1, acc[r]);
            acc[r] = fmaf(xv.z, w2, acc[r]);
            acc[r] = fmaf(xv.w, w3_, acc[r]);
        }
    }
    #pragma unroll
    for (int r = 0; r < 8; ++r)
        Y[(size_t)(r0 + rh * 8 + r) * 128 + o] = acc[r];
}

// ---------------- CSR build: both graphs (node+group), both encoders -------
__global__ void k_zero_i(int* __restrict__ p, int n) {
    const int i = blockIdx.x * blockDim.x + threadIdx.x;
    if (i < n) p[i] = 0;
}
__global__ void k_hist_all(const int* __restrict__ ei0, const int* __restrict__ ei1,
                           const int* __restrict__ gei0, const int* __restrict__ gei1,
                           int* __restrict__ cnt1, int* __restrict__ cnt2)
{
    const int gid = blockIdx.x * blockDim.x + threadIdx.x;
    if (gid < 2 * E1) {
        const int eb = gid >= E1;
        const int le = gid - (eb ? E1 : 0);
        const int* ei = eb ? ei1 : ei0;
        atomicAdd(&cnt1[(eb ? NROWS : 0) + ei[E1 + le]], 1);
    } else {
        const int g2 = gid - 2 * E1;
        const int eb = g2 >= E2;
        const int le = g2 - (eb ? E2 : 0);
        const int* ei = eb ? gei1 : gei0;
        atomicAdd(&cnt2[(eb ? GROWS : 0) + ei[E2 + le]], 1);
    }
}
__global__ __launch_bounds__(256) void k_scan_bsum_all(
    const int* __restrict__ cnt1, const int* __restrict__ cnt2,
    int* __restrict__ bsum1, int* __restrict__ bsum2)
{
    const int blk = blockIdx.x, t = threadIdx.x;
    const int* cnt; int* bsum; int lblk;
    if (blk < 32) { cnt = cnt1; bsum = bsum1; lblk = blk; }
    else          { cnt = cnt2; bsum = bsum2; lblk = blk - 32; }
    const int4 v = ((const int4*)cnt)[lblk * 256 + t];
    int s = v.x + v.y + v.z + v.w;
    #pragma unroll
    for (int off = 32; off > 0; off >>= 1) s += __shfl_down(s, off);
    __shared__ int wsum[4];
    if ((t & 63) == 0) wsum[t >> 6] = s;
    __syncthreads();
    if (t == 0) bsum[lblk] = wsum[0] + wsum[1] + wsum[2] + wsum[3];
}
__global__ __launch_bounds__(256) void k_scan_final_all(
    const int* __restrict__ cnt1, const int* __restrict__ bsum1,
    int* __restrict__ offs1, int* __restrict__ cur1, float* __restrict__ dinv1,
    const int* __restrict__ cnt2, const int* __restrict__ bsum2,
    int* __restrict__ offs2, int* __restrict__ cur2, float* __restrict__ dinv2)
{
    const int blk = blockIdx.x, t = threadIdx.x;
    const int* cnt; const int* bsum; int* offs; int* cur; float* dinv;
    int n, nb, lblk;
    if (blk < 32) { cnt = cnt1; bsum = bsum1; offs = offs1; cur = cur1; dinv = dinv1;
                    n = 2 * NROWS; nb = 32; lblk = blk; }
    else          { cnt = cnt2; bsum = bsum2; offs = offs2; cur = cur2; dinv = dinv2;
                    n = 2 * GROWS; nb = 8; lblk = blk - 32; }
    int base = 0;
    for (int i = 0; i < lblk; ++i) base += bsum[i];
    const int4 v = ((const int4*)cnt)[lblk * 256 + t];
    const int s = v.x + v.y + v.z + v.w;
    int sc = s;
    #pragma unroll
    for (int off = 1; off < 64; off <<= 1) {
        const int u = __shfl_up(sc, off);
        if ((t & 63) >= off) sc += u;
    }
    __shared__ int wsum[4];
    if ((t & 63) == 63) wsum[t >> 6] = sc;
    __syncthreads();
    int wbase = 0;
    for (int wv = 0; wv < (t >> 6); ++wv) wbase += wsum[wv];
    int o0 = base + wbase + sc - s;
    const int gi = lblk * 1024 + t * 4;
    offs[gi + 0] = o0; cur[gi + 0] = o0; dinv[gi + 0] = rsqrtf(1.f + (float)v.x); o0 += v.x;
    offs[gi + 1] = o0; cur[gi + 1] = o0; dinv[gi + 1] = rsqrtf(1.f + (float)v.y); o0 += v.y;
    offs[gi + 2] = o0; cur[gi + 2] = o0; dinv[gi + 2] = rsqrtf(1.f + (float)v.z); o0 += v.z;
    offs[gi + 3] = o0; cur[gi + 3] = o0; dinv[gi + 3] = rsqrtf(1.f + (float)v.w); o0 += v.w;
    if (lblk == nb - 1 && t == 255) offs[n] = o0;
}
__global__ void k_fill_all(const int* __restrict__ ei0, const int* __restrict__ ei1,
                           const int* __restrict__ gei0, const int* __restrict__ gei1,
                           int* __restrict__ cur1, int* __restrict__ esrc1,
                           int* __restrict__ cur2, int* __restrict__ esrc2)
{
    const int gid = blockIdx.x * blockDim.x + threadIdx.x;
    if (gid < 2 * E1) {
        const int eb = gid >= E1;
        const int le = gid - (eb ? E1 : 0);
        const int* ei = eb ? ei1 : ei0;
        const int s = ei[le];
        const int d = ei[E1 + le];
        const int pos = atomicAdd(&cur1[(eb ? NROWS : 0) + d], 1);
        esrc1[pos] = s;
    } else {
        const int g2 = gid - 2 * E1;
        const int eb = g2 >= E2;
        const int le = g2 - (eb ? E2 : 0);
        const int* ei = eb ? gei1 : gei0;
        const int s = ei[le];
        const int d = ei[E2 + le];
        const int pos = atomicAdd(&cur2[(eb ? GROWS : 0) + d], 1);
        esrc2[pos] = s;
    }
}

// ---------------- GCN gather (combined 2n rows, local CSR src ids) ---------
__global__ __launch_bounds__(128) void k_gcn_gather(
    const int* __restrict__ offs, const int* __restrict__ esrc,
    const float* __restrict__ hw, const float* __restrict__ dinv,
    const float* __restrict__ bias, float* __restrict__ out, int n)
{
    const int d = blockIdx.x;
    const int t = threadIdx.x;             // 128
    const int sbase = (d >= n) ? n : 0;
    const int e0 = offs[d], e1 = offs[d + 1];
    const float dd = dinv[d];
    float a0 = hw[(size_t)d * 128 + t] * dd;
    float a1 = 0.f, a2 = 0.f, a3 = 0.f;
    int j = e0;
    for (; j + 3 < e1; j += 4) {
        const int s0 = sbase + esrc[j],     s1 = sbase + esrc[j + 1];
        const int s2 = sbase + esrc[j + 2], s3 = sbase + esrc[j + 3];
        a0 = fmaf(hw[(size_t)s0 * 128 + t], dinv[s0], a0);
        a1 = fmaf(hw[(size_t)s1 * 128 + t], dinv[s1], a1);
        a2 = fmaf(hw[(size_t)s2 * 128 + t], dinv[s2], a2);
        a3 = fmaf(hw[(size_t)s3 * 128 + t], dinv[s3], a3);
    }
    for (; j < e1; ++j) {
        const int s = sbase + esrc[j];
        a0 = fmaf(hw[(size_t)s * 128 + t], dinv[s], a0);
    }
    const float acc = (a0 + a1) + (a2 + a3);
    out[(size_t)d * 128 + t] = fmaf(acc, dd, bias[t]);
}

// ---------------- per-group aggregate 512->128 (4 rows, K-split 2) ----------
__global__ __launch_bounds__(256) void k_agg(
    const float* __restrict__ h, const float* __restrict__ aggw,
    const float* __restrict__ aggb, float* __restrict__ hg)
{
    const int bt = blockIdx.x >> 4;        // 0..127
    const int g  = blockIdx.x & 15;
    const int t  = threadIdx.x;
    const int o  = t & 127;
    const int kk = t >> 7;
    __shared__ float fs[4 * 512];
    __shared__ float red[2][4][128];
    {
        const int b0 = bt * 4;
        float4* dst = (float4*)fs;
        for (int i = t; i < 4 * 128; i += 256) {
            const int r = i >> 7;
            const int q = i & 127;
            dst[i] = *(const float4*)(h + ((size_t)(b0 + r) * 64 + g * 4) * 128 + q * 4);
        }
    }
    __syncthreads();
    const float* w = aggw + (size_t)g * 512 * 128 + (size_t)kk * 256 * 128 + o;
    float a0 = 0.f, a1 = 0.f, a2 = 0.f, a3 = 0.f;
    const float* x0 = fs + 0 * 512 + kk * 256;
    const float* x1 = fs + 1 * 512 + kk * 256;
    const float* x2 = fs + 2 * 512 + kk * 256;
    const float* x3 = fs + 3 * 512 + kk * 256;
    #pragma unroll 8
    for (int f = 0; f < 256; ++f) {
        const float wv = w[f * 128];
        a0 = fmaf(x0[f], wv, a0);
        a1 = fmaf(x1[f], wv, a1);
        a2 = fmaf(x2[f], wv, a2);
        a3 = fmaf(x3[f], wv, a3);
    }
    red[kk][0][o] = a0; red[kk][1][o] = a1; red[kk][2][o] = a2; red[kk][3][o] = a3;
    __syncthreads();
    if (t < 128) {
        const float bias = aggb[g * 128 + t];
        #pragma unroll
        for (int r = 0; r < 4; ++r) {
            const int b = bt * 4 + r;
            hg[((size_t)b * 16 + g) * 128 + t] = red[0][r][t] + red[1][r][t] + bias;
        }
    }
}

// ---------------- disc (4 rows, K-split 2): relu in, 256->128 + relu --------
__global__ __launch_bounds__(256) void k_disc(
    const float* __restrict__ h1, const float* __restrict__ h2,
    const float* __restrict__ dw, const float* __restrict__ db,
    float* __restrict__ dd)
{
    const int bt = blockIdx.x >> 4;        // 0..63
    const int g  = blockIdx.x & 15;
    const int t  = threadIdx.x;
    const int o  = t & 127;
    const int kk = t >> 7;
    __shared__ float fs[4 * 256];
    __shared__ float red[2][4][128];
    {
        const int half = t >> 7;
        #pragma unroll
        for (int r = 0; r < 4; ++r) {
            const int rowi = ((bt * 4 + r) * 16 + g);
            const float* src = half ? h2 : h1;
            fs[r * 256 + half * 128 + o] = fmaxf(src[(size_t)rowi * 128 + o], 0.f);
        }
    }
    __syncthreads();
    const float* w = dw + (size_t)g * 256 * 128 + (size_t)kk * 128 * 128 + o;
    float a0 = 0.f, a1 = 0.f, a2 = 0.f, a3 = 0.f;
    const float* x0 = fs + 0 * 256 + kk * 128;
    const float* x1 = fs + 1 * 256 + kk * 128;
    const float* x2 = fs + 2 * 256 + kk * 128;
    const float* x3 = fs + 3 * 256 + kk * 128;
    #pragma unroll 8
    for (int f = 0; f < 128; ++f) {
        const float wv = w[f * 128];
        a0 = fmaf(x0[f], wv, a0);
        a1 = fmaf(x1[f], wv, a1);
        a2 = fmaf(x2[f], wv, a2);
        a3 = fmaf(x3[f], wv, a3);
    }
    red[kk][0][o] = a0; red[kk][1][o] = a1; red[kk][2][o] = a2; red[kk][3][o] = a3;
    __syncthreads();
    if (t < 128) {
        const float bias = db[g * 128 + t];
        #pragma unroll
        for (int r = 0; r < 4; ++r) {
            const int b = bt * 4 + r;
            dd[(size_t)b * 2048 + g * 128 + t] =
                fmaxf(red[0][r][t] + red[1][r][t] + bias, 0.f);
        }
    }
}

// ---------------- final fc 2048->64: one block per batch row ----------------
__global__ __launch_bounds__(256) void k_fc(
    const float* __restrict__ dd, const float* __restrict__ fcw,
    const float* __restrict__ fcb, float* __restrict__ out)
{
    const int b = blockIdx.x;
    const int t = threadIdx.x;
    const int o = t & 63;
    const int k = t >> 6;                  // 0..3
    __shared__ float ds[2048];
    __shared__ float red[4][64];
    for (int i = t; i < 2048; i += 256) ds[i] = dd[(size_t)b * 2048 + i];
    __syncthreads();
    const float* w  = fcw + (k * 512) * 64 + o;
    const float* xr = ds + k * 512;
    float a0 = 0.f, a1 = 0.f, a2 = 0.f, a3 = 0.f;
    #pragma unroll 4
    for (int f = 0; f < 512; f += 4) {
        a0 = fmaf(xr[f + 0], w[(f + 0) * 64], a0);
        a1 = fmaf(xr[f + 1], w[(f + 1) * 64], a1);
        a2 = fmaf(xr[f + 2], w[(f + 2) * 64], a2);
        a3 = fmaf(xr[f + 3], w[(f + 3) * 64], a3);
    }
    red[k][o] = (a0 + a1) + (a2 + a3);
    __syncthreads();
    if (t < 64)
        out[(size_t)b * 64 + t] = ((red[0][t] + red[1][t]) + (red[2][t] + red[3][t])) + fcb[t];
}

} // namespace

extern "C" void kernel_launch(void* const* d_in, const int* in_sizes, int n_in,
                              void* d_out, int out_size, void* d_ws, size_t ws_size,
                              hipStream_t stream)
{
    const float* x1 = (const float*)d_in[0];
    const float* x2 = (const float*)d_in[1];
    const int* ei0  = (const int*)d_in[2];
    const int* ei1  = (const int*)d_in[3];
    const int* gei0 = (const int*)d_in[4];
    const int* gei1 = (const int*)d_in[5];
    const float* conv_w3 = (const float*)d_in[6];
    const float* conv_b3 = (const float*)d_in[7];
    const float* conv_w5 = (const float*)d_in[8];
    const float* conv_b5 = (const float*)d_in[9];
    const float* conv_w7 = (const float*)d_in[10];
    const float* conv_b7 = (const float*)d_in[11];
    const float* tconv_w3 = (const float*)d_in[12];
    const float* tconv_b3 = (const float*)d_in[13];
    const float* tconv_w5 = (const float*)d_in[14];
    const float* tconv_b5 = (const float*)d_in[15];
    const float* tconv_w7 = (const float*)d_in[16];
    const float* tconv_b7 = (const float*)d_in[17];
    const float* ff_w    = (const float*)d_in[18];
    const float* ff_b    = (const float*)d_in[19];
    const float* lower_w = (const float*)d_in[20];
    const float* lower_b = (const float*)d_in[21];
    const float* upper_w = (const float*)d_in[22];
    const float* upper_b = (const float*)d_in[23];
    const float* agg_w   = (const float*)d_in[24];
    const float* agg_b   = (const float*)d_in[25];
    const float* disc_w  = (const float*)d_in[26];
    const float* disc_b  = (const float*)d_in[27];
    const float* fc_w    = (const float*)d_in[28];
    const float* fc_b    = (const float*)d_in[29];

    float* ws = (float*)d_ws;
    float* f_feats = ws;                          // 6291456
    float* f_hw    = ws + 10485760;               // 4194304
    float* f_gout  = ws + 14680064;               // 4194304
    float* f_hg    = ws + 18874368;               // 1048576
    float* f_hgw   = ws + 19922944;               // 1048576
    float* f_henc  = ws + 20971520;               // 1048576
    float* f_dd    = ws + 22020096;               // 524288
    float* f_dinv1 = ws + 22544384;               // 32768
    float* f_dinv2 = ws + 22577152;               // 8192
    int* ip    = (int*)(ws + 22585344);
    int* cnt1  = ip;                              // 32768
    int* cnt2  = cnt1 + 2 * NROWS;                // 8192
    int* offs1 = cnt2 + 2 * GROWS;                // 32769
    int* cur1  = offs1 + 2 * NROWS + 1;           // 32768
    int* esrc1 = cur1 + 2 * NROWS;                // 524288
    int* offs2 = esrc1 + 2 * E1;                  // 8193
    int* cur2  = offs2 + 2 * GROWS + 1;           // 8192
    int* esrc2 = cur2 + 2 * GROWS;                // 65536
    int* bsum1 = esrc2 + 2 * E2;                  // 32
    int* bsum2 = bsum1 + 32;                      // 8

    // CSR build, both graphs in 5 launches
    k_zero_i<<<(2 * NROWS + 2 * GROWS) / 256, 256, 0, stream>>>(cnt1, 2 * NROWS + 2 * GROWS);
    k_hist_all<<<(2 * E1 + 2 * E2) / 256, 256, 0, stream>>>(ei0, ei1, gei0, gei1, cnt1, cnt2);
    k_scan_bsum_all<<<40, 256, 0, stream>>>(cnt1, cnt2, bsum1, bsum2);
    k_scan_final_all<<<40, 256, 0, stream>>>(cnt1, bsum1, offs1, cur1, f_dinv1,
                                             cnt2, bsum2, offs2, cur2, f_dinv2);
    k_fill_all<<<(2 * E1 + 2 * E2) / 256, 256, 0, stream>>>(ei0, ei1, gei0, gei1,
                                                            cur1, esrc1, cur2, esrc2);

    // encoder pipeline (both encoders per dispatch)
    k_conv_feats<<<2 * NROWS / 16, 256, 0, stream>>>(x1, x2,
        conv_w3, conv_b3, conv_w5, conv_b5, conv_w7, conv_b7,
        tconv_w3, tconv_b3, tconv_w5, tconv_b5, tconv_w7, tconv_b7, f_feats);
    k_ff_lower<<<2048, 256, 0, stream>>>(f_feats, ff_w, ff_b, lower_w, f_hw);
    k_gcn_gather<<<2 * NROWS, 128, 0, stream>>>(offs1, esrc1, f_hw, f_dinv1,
                                                lower_b, f_gout, NROWS);
    k_agg<<<2 * (Bn / 4) * 16, 256, 0, stream>>>(f_gout, agg_w, agg_b, f_hg);
    k_gemm128<<<2 * GROWS / 16, 256, 0, stream>>>(f_hg, upper_w, f_hgw);
    k_gcn_gather<<<2 * GROWS, 128, 0, stream>>>(offs2, esrc2, f_hgw, f_dinv2,
                                                upper_b, f_henc, GROWS);

    k_disc<<<(Bn / 4) * 16, 256, 0, stream>>>(f_henc, f_henc + (size_t)GROWS * 128,
                                              disc_w, disc_b, f_dd);
    k_fc<<<Bn, 256, 0, stream>>>(f_dd, fc_w, fc_b, (float*)d_out);
}